// Round 12
// baseline (1229.438 us; speedup 1.0000x reference)
//
#include <hip/hip_runtime.h>
#include <hip/hip_bf16.h>

#define S_LEN 1024
#define HID 7168
#define NH 128
#define DQ 1536
#define DKV 512
#define DH 128
#define DR 64

typedef __attribute__((ext_vector_type(8))) short bf16x8;
typedef __attribute__((ext_vector_type(4))) float f32x4;
typedef __attribute__((ext_vector_type(4))) float fl4;
typedef __attribute__((ext_vector_type(4))) unsigned short us4;
typedef __attribute__((ext_vector_type(8))) unsigned short us8;
typedef __attribute__((ext_vector_type(4))) unsigned int u32x4;

static __device__ __forceinline__ unsigned short f2bf(float f) {
  union { float f; unsigned int u; } v; v.f = f;
  unsigned int u = v.u;
  return (unsigned short)((u + 0x7fffu + ((u >> 16) & 1u)) >> 16);
}
static __device__ __forceinline__ float bf2f(unsigned short u) {
  union { unsigned int u; float f; } v; v.u = ((unsigned int)u) << 16;
  return v.f;
}
static __device__ __forceinline__ unsigned int cvtpk2(float lo, float hi) {
  unsigned int r;
  asm("v_cvt_pk_bf16_f32 %0, %1, %2" : "=v"(r) : "v"(lo), "v"(hi));
  return r;
}

// ---------------- fp32 -> bf16 conversion -------------------------------------
__global__ __launch_bounds__(256) void cvt_bf16_kernel(
    const float* __restrict__ in, unsigned short* __restrict__ out, int n8) {
  int i = blockIdx.x * 256 + threadIdx.x;
  int stride = gridDim.x * 256;
  for (; i < n8; i += stride) {
    fl4 a = ((const fl4*)in)[2 * i];
    fl4 b = ((const fl4*)in)[2 * i + 1];
    us8 u = { f2bf(a[0]), f2bf(a[1]), f2bf(a[2]), f2bf(a[3]),
              f2bf(b[0]), f2bf(b[1]), f2bf(b[2]), f2bf(b[3]) };
    ((us8*)out)[i] = u;
  }
}

// ---------------- bf16 GEMM (m97 structure + T14 W-prefetch) ------------------
// OUTMODE 1: C = bf16((A@W^T + bias) * alpha), grid.z==1
// OUTMODE 2: fp32 partials per K-slice at Cv + z*zstride (split-K), no bias
// WFP32 1: W read as fp32, prefetched to regs one K-step ahead, cvt in staging.
// grid.x may be PADDED to a multiple of 8 (XCD colocation of m-groups).
template <int OUTMODE, int WFP32>
__global__ __launch_bounds__(256) void gemm_k(
    const unsigned short* __restrict__ A, int lda,
    const unsigned short* __restrict__ Wb16,
    const float* __restrict__ Wfa, const float* __restrict__ Wfb, int nsplit,
    int ldw,
    const float* __restrict__ bias,
    void* __restrict__ Cv, int ldc, size_t zstride,
    int Ncl, int ksl, float alpha)
{
  const int n0 = blockIdx.x * 128;
  if (n0 >= Ncl) return;                 // padded-grid early exit (block-uniform)

  __shared__ unsigned short As[128 * 64];
  __shared__ unsigned short Ws[128 * 64];
  const int t = threadIdx.x;
  const int l = t & 63, w = t >> 6;
  const int r15 = l & 15, g = l >> 4;
  const int wm = (w >> 1) * 64, wn = (w & 1) * 64;
  const int m0 = blockIdx.y * 128;
  const int kbase = blockIdx.z * ksl;
  const int srow = l >> 3;
  const int scol = (l & 7) * 8;

  f32x4 acc[4][4];
#pragma unroll
  for (int i = 0; i < 4; ++i)
#pragma unroll
    for (int j = 0; j < 4; ++j) acc[i][j] = (f32x4){0.f, 0.f, 0.f, 0.f};

  const unsigned short* Ab = A + (size_t)m0 * lda;
  const unsigned short* Wb = nullptr;
  const float* Wf = nullptr;
  if constexpr (WFP32) {
    Wf = (n0 < nsplit) ? Wfa + (size_t)n0 * ldw : Wfb + (size_t)(n0 - nsplit) * ldw;
  } else {
    Wb = Wb16 + (size_t)n0 * ldw;
  }

  fl4 wx[4], wy[4];
  auto issueW = [&](int k0) {
#pragma unroll
    for (int i = 0; i < 4; ++i) {
      int c = t + 256 * i;
      const float* src = Wf + (size_t)(c >> 3) * ldw + k0 + (c & 7) * 8;
      wx[i] = *(const fl4*)src;
      wy[i] = *(const fl4*)(src + 4);
    }
  };

  if constexpr (WFP32) issueW(kbase);
  const int kend = kbase + ksl;

  for (int k0 = kbase; k0 < kend; k0 += 64) {
    __syncthreads();
#pragma unroll
    for (int i = 0; i < 4; ++i) {
      int chunk = w * 4 + i;
      int row = chunk * 8 + srow;
      __builtin_amdgcn_global_load_lds(
          (const __attribute__((address_space(1))) void*)(Ab + (size_t)row * lda + k0 + scol),
          (__attribute__((address_space(3))) void*)(As + chunk * 512), 16, 0, 0);
      if constexpr (!WFP32) {
        __builtin_amdgcn_global_load_lds(
            (const __attribute__((address_space(1))) void*)(Wb + (size_t)row * ldw + k0 + scol),
            (__attribute__((address_space(3))) void*)(Ws + chunk * 512), 16, 0, 0);
      }
    }
    if constexpr (WFP32) {
#pragma unroll
      for (int i = 0; i < 4; ++i) {
        int c = t + 256 * i;
        u32x4 p = { cvtpk2(wx[i][0], wx[i][1]), cvtpk2(wx[i][2], wx[i][3]),
                    cvtpk2(wy[i][0], wy[i][1]), cvtpk2(wy[i][2], wy[i][3]) };
        ((u32x4*)Ws)[c] = p;
      }
    }
    __syncthreads();
    if constexpr (WFP32) {
      if (k0 + 64 < kend) issueW(k0 + 64);   // T14: next W loads fly over MFMA
    }
#pragma unroll
    for (int kk = 0; kk < 2; ++kk) {
      bf16x8 a[4], b[4];
#pragma unroll
      for (int mt = 0; mt < 4; ++mt)
        a[mt] = *reinterpret_cast<const bf16x8*>(&As[(wm + mt * 16 + r15) * 64 + kk * 32 + 8 * g]);
#pragma unroll
      for (int nt = 0; nt < 4; ++nt)
        b[nt] = *reinterpret_cast<const bf16x8*>(&Ws[(wn + nt * 16 + r15) * 64 + kk * 32 + 8 * g]);
#pragma unroll
      for (int mt = 0; mt < 4; ++mt)
#pragma unroll
        for (int nt = 0; nt < 4; ++nt)
          acc[mt][nt] = __builtin_amdgcn_mfma_f32_16x16x32_bf16(a[mt], b[nt], acc[mt][nt], 0, 0, 0);
    }
  }

  if constexpr (OUTMODE == 1) {
    float bv[4];
#pragma unroll
    for (int nt = 0; nt < 4; ++nt) {
      int col = n0 + wn + nt * 16 + r15;
      bv[nt] = (col < Ncl) ? bias[col] : 0.f;
    }
#pragma unroll
    for (int mt = 0; mt < 4; ++mt)
#pragma unroll
      for (int nt = 0; nt < 4; ++nt) {
        int col = n0 + wn + nt * 16 + r15;
        if (col < Ncl) {
#pragma unroll
          for (int r = 0; r < 4; ++r) {
            int row = m0 + wm + mt * 16 + g * 4 + r;
            ((unsigned short*)Cv)[(size_t)row * ldc + col] =
                f2bf((acc[mt][nt][r] + bv[nt]) * alpha);
          }
        }
      }
  } else {
    float* Cp = (float*)Cv + blockIdx.z * zstride;
#pragma unroll
    for (int mt = 0; mt < 4; ++mt)
#pragma unroll
      for (int nt = 0; nt < 4; ++nt) {
        int col = n0 + wn + nt * 16 + r15;
        if (col < Ncl) {
#pragma unroll
          for (int r = 0; r < 4; ++r) {
            int row = m0 + wm + mt * 16 + g * 4 + r;
            Cp[(size_t)row * ldc + col] = acc[mt][nt][r];
          }
        }
      }
  }
}

// ---------------- split-K reductions ------------------------------------------
__global__ __launch_bounds__(256) void reduce_f32_kernel(
    const float* __restrict__ pbuf, const float* __restrict__ bias,
    float* __restrict__ out, int ldo, int rowlen4, int nz, size_t zstride, int total4)
{
  int idx = blockIdx.x * 256 + threadIdx.x;
  if (idx >= total4) return;
  int r = idx / rowlen4, c4 = idx % rowlen4;
  fl4 acc = *(const fl4*)(bias + c4 * 4);
  for (int z = 0; z < nz; ++z)
    acc += *(const fl4*)(pbuf + z * zstride + (size_t)idx * 4);
  *(fl4*)(out + (size_t)r * ldo + c4 * 4) = acc;
}

__global__ __launch_bounds__(256) void reduce_bf16_kernel(
    const float* __restrict__ pbuf, const float* __restrict__ bias,
    unsigned short* __restrict__ out, int ldo, int rowlen4, int nz, size_t zstride, int total4)
{
  int idx = blockIdx.x * 256 + threadIdx.x;
  if (idx >= total4) return;
  int r = idx / rowlen4, c4 = idx % rowlen4;
  fl4 acc = *(const fl4*)(bias + c4 * 4);
  for (int z = 0; z < nz; ++z)
    acc += *(const fl4*)(pbuf + z * zstride + (size_t)idx * 4);
  us4 u = { f2bf(acc[0]), f2bf(acc[1]), f2bf(acc[2]), f2bf(acc[3]) };
  *(us4*)(out + (size_t)r * ldo + c4 * 4) = u;
}

// ---------------- rope tables + table-based rope ------------------------------
__global__ __launch_bounds__(256) void rope_table_kernel(float* __restrict__ ctab,
                                                         float* __restrict__ stab) {
  int idx = blockIdx.x * 256 + threadIdx.x;
  if (idx >= S_LEN * 32) return;
  int j = idx & 31, s = idx >> 5;
  float invf = expf(-0.28782313662425574f * (float)j);
  float ang = (float)s * invf;
  ctab[idx] = cosf(ang);
  stab[idx] = sinf(ang);
}

__global__ void rope_bf16_kernel(unsigned short* __restrict__ x, int nh, int lda, int total,
                                 const float* __restrict__ ctab,
                                 const float* __restrict__ stab) {
  int idx = blockIdx.x * 256 + threadIdx.x;
  if (idx >= total) return;
  int j = idx & 31;
  int rest = idx >> 5;
  int hh = rest % nh;
  int s = rest / nh;
  float c = ctab[s * 32 + j], sn = stab[s * 32 + j];
  size_t base = (size_t)s * lda + hh * 64;
  float x1 = bf2f(x[base + j]), x2 = bf2f(x[base + j + 32]);
  x[base + j]      = f2bf(x1 * c - x2 * sn);
  x[base + j + 32] = f2bf(x2 * c + x1 * sn);
}

// ---------------- V transpose -------------------------------------------------
__global__ __launch_bounds__(256) void vtrans_kernel(
    const unsigned short* __restrict__ kvb, unsigned short* __restrict__ vt) {
  __shared__ unsigned short tl[64][72];
  const int s0 = blockIdx.x * 64;
  const int c0 = blockIdx.y * 64;
  const int t = threadIdx.x;
  const int rr = t >> 3, cc = (t & 7) * 8;
  const int hbase = (c0 >> 7) * 256 + 128 + (c0 & 127);
#pragma unroll
  for (int i = 0; i < 2; ++i) {
    int r = rr + i * 32;
    *reinterpret_cast<bf16x8*>(&tl[r][cc]) =
        *reinterpret_cast<const bf16x8*>(kvb + (size_t)(s0 + r) * 32768 + hbase + cc);
  }
  __syncthreads();
#pragma unroll
  for (int i = 0; i < 2; ++i) {
    int vc = rr + i * 32;
    unsigned short tmp[8];
#pragma unroll
    for (int j = 0; j < 8; ++j) tmp[j] = tl[cc + j][vc];
    *reinterpret_cast<bf16x8*>(&vt[(size_t)(c0 + vc) * 1024 + s0 + cc]) =
        *reinterpret_cast<bf16x8*>(tmp);
  }
}

// ---------------- flash attention ---------------------------------------------
__global__ __launch_bounds__(256) void mla_attn_kernel(
    const unsigned short* __restrict__ qcat,
    const unsigned short* __restrict__ kvb,
    const unsigned short* __restrict__ kr,
    const unsigned short* __restrict__ vt,
    unsigned short* __restrict__ obuf)
{
  __shared__ unsigned short Klds[64][200];
  __shared__ unsigned short Vlds[128][72];
  __shared__ unsigned short Plds[4][16][72];

  const int t = threadIdx.x;
  const int l = t & 63, w = t >> 6;
  const int r15 = l & 15, g = l >> 4;
  const int bid = blockIdx.x;
  const int orig = (bid & 7) * 256 + (bid >> 3);
  const int h = orig >> 4;
  const int q0 = (orig & 15) * 64;

  bf16x8 qf[6];
  const unsigned short* qrow = qcat + (size_t)(q0 + w * 16 + r15) * 24576;
#pragma unroll
  for (int kk = 0; kk < 4; ++kk)
    qf[kk] = *reinterpret_cast<const bf16x8*>(qrow + h * 128 + kk * 32 + 8 * g);
#pragma unroll
  for (int kk = 4; kk < 6; ++kk)
    qf[kk] = *reinterpret_cast<const bf16x8*>(qrow + 16384 + h * 64 + (kk - 4) * 32 + 8 * g);

  bf16x8 kreg[6], vreg[4];
  auto loadKV = [&](int kk0) {
#pragma unroll
    for (int i = 0; i < 6; ++i) {
      int c = t + 256 * i, row = c / 24, cb = c % 24;
      const unsigned short* src = (cb < 16)
          ? kvb + (size_t)(kk0 + row) * 32768 + h * 256 + cb * 8
          : kr + (size_t)(kk0 + row) * 2112 + (cb - 16) * 8;
      kreg[i] = *reinterpret_cast<const bf16x8*>(src);
    }
#pragma unroll
    for (int i = 0; i < 4; ++i) {
      int c = t + 256 * i, d = c >> 3, kb = c & 7;
      vreg[i] = *reinterpret_cast<const bf16x8*>(vt + ((size_t)h * 128 + d) * 1024 + kk0 + kb * 8);
    }
  };

  float m_r[4], l_r[4];
  f32x4 oacc[8];
#pragma unroll
  for (int r = 0; r < 4; ++r) { m_r[r] = -1e30f; l_r[r] = 0.f; }
#pragma unroll
  for (int d = 0; d < 8; ++d) oacc[d] = (f32x4){0.f, 0.f, 0.f, 0.f};

  loadKV(0);

  for (int kt = 0; kt < 16; ++kt) {
    __syncthreads();
#pragma unroll
    for (int i = 0; i < 6; ++i) {
      int c = t + 256 * i, row = c / 24, cb = c % 24;
      *reinterpret_cast<bf16x8*>(&Klds[row][cb * 8]) = kreg[i];
    }
#pragma unroll
    for (int i = 0; i < 4; ++i) {
      int c = t + 256 * i, d = c >> 3, kb = c & 7;
      *reinterpret_cast<bf16x8*>(&Vlds[d][kb * 8]) = vreg[i];
    }
    __syncthreads();
    if (kt < 15) loadKV((kt + 1) * 64);

    f32x4 sacc[4];
#pragma unroll
    for (int nt = 0; nt < 4; ++nt) sacc[nt] = (f32x4){0.f, 0.f, 0.f, 0.f};
    __builtin_amdgcn_s_setprio(1);
#pragma unroll
    for (int nt = 0; nt < 4; ++nt)
#pragma unroll
      for (int kk = 0; kk < 6; ++kk) {
        bf16x8 b = *reinterpret_cast<const bf16x8*>(&Klds[nt * 16 + r15][kk * 32 + 8 * g]);
        sacc[nt] = __builtin_amdgcn_mfma_f32_16x16x32_bf16(qf[kk], b, sacc[nt], 0, 0, 0);
      }
    __builtin_amdgcn_s_setprio(0);

    float sc[4], rsum[4];
#pragma unroll
    for (int r = 0; r < 4; ++r) {
      float mx = fmaxf(fmaxf(sacc[0][r], sacc[1][r]), fmaxf(sacc[2][r], sacc[3][r]));
      mx = fmaxf(mx, __shfl_xor(mx, 1));
      mx = fmaxf(mx, __shfl_xor(mx, 2));
      mx = fmaxf(mx, __shfl_xor(mx, 4));
      mx = fmaxf(mx, __shfl_xor(mx, 8));
      float mn = fmaxf(m_r[r], mx);
      sc[r] = __expf(m_r[r] - mn);
      m_r[r] = mn;
      rsum[r] = 0.f;
    }
#pragma unroll
    for (int nt = 0; nt < 4; ++nt)
#pragma unroll
      for (int r = 0; r < 4; ++r) {
        float p = __expf(sacc[nt][r] - m_r[r]);
        rsum[r] += p;
        Plds[w][g * 4 + r][nt * 16 + r15] = f2bf(p);
      }
#pragma unroll
    for (int r = 0; r < 4; ++r) {
      float s = rsum[r];
      s += __shfl_xor(s, 1);
      s += __shfl_xor(s, 2);
      s += __shfl_xor(s, 4);
      s += __shfl_xor(s, 8);
      l_r[r] = l_r[r] * sc[r] + s;
    }
#pragma unroll
    for (int d = 0; d < 8; ++d)
#pragma unroll
      for (int r = 0; r < 4; ++r) oacc[d][r] *= sc[r];

    bf16x8 pa0 = *reinterpret_cast<const bf16x8*>(&Plds[w][r15][8 * g]);
    bf16x8 pa1 = *reinterpret_cast<const bf16x8*>(&Plds[w][r15][32 + 8 * g]);
    __builtin_amdgcn_s_setprio(1);
#pragma unroll
    for (int dt = 0; dt < 8; ++dt) {
      bf16x8 v0 = *reinterpret_cast<const bf16x8*>(&Vlds[dt * 16 + r15][8 * g]);
      bf16x8 v1 = *reinterpret_cast<const bf16x8*>(&Vlds[dt * 16 + r15][32 + 8 * g]);
      oacc[dt] = __builtin_amdgcn_mfma_f32_16x16x32_bf16(pa0, v0, oacc[dt], 0, 0, 0);
      oacc[dt] = __builtin_amdgcn_mfma_f32_16x16x32_bf16(pa1, v1, oacc[dt], 0, 0, 0);
    }
    __builtin_amdgcn_s_setprio(0);
  }

#pragma unroll
  for (int dt = 0; dt < 8; ++dt)
#pragma unroll
    for (int r = 0; r < 4; ++r) {
      int row = q0 + w * 16 + g * 4 + r;
      int col = h * DH + dt * 16 + r15;
      obuf[(size_t)row * 16384 + col] = f2bf(oacc[dt][r] / l_r[r]);
    }
}

// ------------------------------------------------------------------------------
extern "C" void kernel_launch(void* const* d_in, const int* in_sizes, int n_in,
                              void* d_out, int out_size, void* d_ws, size_t ws_size,
                              hipStream_t stream) {
  const float* h    = (const float*)d_in[0];
  const float* Wdq  = (const float*)d_in[1];
  const float* bdq  = (const float*)d_in[2];
  const float* Wdkv = (const float*)d_in[3];
  const float* bdkv = (const float*)d_in[4];
  const float* Wuq  = (const float*)d_in[5];
  const float* buq  = (const float*)d_in[6];
  const float* Wukv = (const float*)d_in[7];
  const float* bukv = (const float*)d_in[8];
  const float* Wrq  = (const float*)d_in[9];
  const float* brq  = (const float*)d_in[10];
  const float* Wrk  = (const float*)d_in[11];
  const float* brk  = (const float*)d_in[12];
  const float* Wo   = (const float*)d_in[13];
  const float* bo   = (const float*)d_in[14];
  float* out = (float*)d_out;

  char* ws = (char*)d_ws;
  size_t off = 0;
  auto alloc = [&](size_t bytes) {
    char* p = ws + off;
    off += (bytes + 255) & ~(size_t)255;
    return p;
  };
  unsigned short* hb    = (unsigned short*)alloc((size_t)1024 * 7168 * 2);
  unsigned short* W1cat = (unsigned short*)alloc((size_t)2176 * 7168 * 2);
  float*          b1cat = (float*)alloc(2176 * 4);
  unsigned short* ccat  = (unsigned short*)alloc((size_t)1024 * 2112 * 2);
  float*          b2cat = (float*)alloc(24576 * 4);
  unsigned short* qcat  = (unsigned short*)alloc((size_t)1024 * 24576 * 2);
  unsigned short* kvbb  = (unsigned short*)alloc((size_t)1024 * 32768 * 2);
  unsigned short* vt    = (unsigned short*)alloc((size_t)16384 * 1024 * 2);
  unsigned short* obuf  = (unsigned short*)alloc((size_t)1024 * 16384 * 2);
  float*          ctab  = (float*)alloc((size_t)S_LEN * 32 * 4);
  float*          stab  = (float*)alloc((size_t)S_LEN * 32 * 4);
  // G1 split-K partials alias not-yet-written qcat (34.6 MB < 50.3 MB)
  float* pbufG1 = (float*)qcat;
  // d_ws is ~1.75 GB (observed poison size); place G4 buffers in fresh regions
  // well past obuf (ends at ~235 MB): Wob @ 288 MiB, pbufG4 @ 416 MiB.
  unsigned short* Wob    = (unsigned short*)(ws + ((size_t)288 << 20));
  float*          pbufG4 = (float*)(ws + ((size_t)416 << 20));

  auto cvt = [&](const float* in, unsigned short* outp, size_t n) {
    int n8 = (int)(n / 8);
    int blocks = (n8 + 255) / 256;
    if (blocks > 2048) blocks = 2048;
    cvt_bf16_kernel<<<blocks, 256, 0, stream>>>(in, outp, n8);
  };

  // --- conversions for h and the small concatenated W1 ---
  cvt(h,    hb,    (size_t)1024 * 7168);
  cvt(Wdq,  W1cat, (size_t)1536 * 7168);
  cvt(Wdkv, W1cat + (size_t)1536 * 7168, (size_t)512 * 7168);
  cvt(Wrk,  W1cat + (size_t)2048 * 7168, (size_t)64 * 7168);
  hipMemsetAsync(W1cat + (size_t)2112 * 7168, 0, (size_t)64 * 7168 * 2, stream);
  hipMemcpyAsync(b1cat,        bdq,  1536 * 4, hipMemcpyDeviceToDevice, stream);
  hipMemcpyAsync(b1cat + 1536, bdkv, 512 * 4,  hipMemcpyDeviceToDevice, stream);
  hipMemcpyAsync(b1cat + 2048, brk,  64 * 4,   hipMemcpyDeviceToDevice, stream);
  hipMemsetAsync(b1cat + 2112, 0, 64 * 4, stream);
  hipMemcpyAsync(b2cat,         buq, 16384 * 4, hipMemcpyDeviceToDevice, stream);
  hipMemcpyAsync(b2cat + 16384, brq, 8192 * 4,  hipMemcpyDeviceToDevice, stream);
  rope_table_kernel<<<(S_LEN * 32 + 255) / 256, 256, 0, stream>>>(ctab, stab);

  const float scale = 0.07216878364870323f;   // 1/sqrt(192)
  const int BIGN = 1 << 30;
  dim3 blk(256);

  // G1 (split-K=4, bf16 W): partials = h @ W1cat^T
  gemm_k<2, 0><<<dim3(24, 8, 4), blk, 0, stream>>>(
      hb, 7168, W1cat, nullptr, nullptr, BIGN, 7168, nullptr,
      pbufG1, 2112, (size_t)1024 * 2112, 2112, 1792, 1.0f);
  reduce_bf16_kernel<<<2112, blk, 0, stream>>>(pbufG1, b1cat, ccat, 2112, 528, 4,
                                               (size_t)1024 * 2112, 1024 * 2112 / 4);
  rope_bf16_kernel<<<(1024 * 32 + 255) / 256, blk, 0, stream>>>(ccat + 2048, 1, 2112, 1024 * 32, ctab, stab);

  // G2 (fp32 W direct): [q_c | q_r] = (c_q @ [Wuq;Wrq]^T + b2cat) * scale
  gemm_k<1, 1><<<dim3(192, 8, 1), blk, 0, stream>>>(
      ccat, 2112, nullptr, Wuq, Wrq, 16384, 1536, b2cat,
      qcat, 24576, 0, 24576, 1536, scale);
  rope_bf16_kernel<<<(1024 * 128 * 32 + 255) / 256, blk, 0, stream>>>(qcat + 16384, 128, 24576, 1024 * 128 * 32, ctab, stab);

  // G3 (fp32 W direct): kv = c_kv @ Wukv^T + bukv
  gemm_k<1, 1><<<dim3(256, 8, 1), blk, 0, stream>>>(
      ccat + 1536, 2112, nullptr, Wukv, Wukv, BIGN, 512, bukv,
      kvbb, 32768, 0, 32768, 512, 1.0f);
  vtrans_kernel<<<dim3(16, 256), blk, 0, stream>>>(kvbb, vt);
  mla_attn_kernel<<<dim3(2048), blk, 0, stream>>>(qcat, kvbb, ccat + 2048, vt, obuf);

  // G4: per L3-fit half (bf16 W-half 117 MB + obuf 33.5 MB << 256 MB L3):
  // cvt Wo->bf16 once, then the proven m97-path gemm_k<2,0> (glds both sides),
  // grid (32,8,4) padded (XCD-aligned W-sharers), split-K=4, then reduce.
  for (int hn = 0; hn < 2; ++hn) {
    cvt(Wo + (size_t)hn * 3584 * 16384, Wob, (size_t)3584 * 16384);
    gemm_k<2, 0><<<dim3(32, 8, 4), blk, 0, stream>>>(
        obuf, 16384, Wob, nullptr, nullptr, BIGN, 16384, nullptr,
        pbufG4, 3584, (size_t)1024 * 3584, 3584, 4096, 1.0f);
    reduce_f32_kernel<<<3584, blk, 0, stream>>>(pbufG4, bo + hn * 3584, out + hn * 3584,
                                                7168, 896, 4, (size_t)1024 * 3584, 1024 * 3584 / 4);
  }
}

// Round 13
// 1185.906 us; speedup vs baseline: 1.0367x; 1.0367x over previous
//
#include <hip/hip_runtime.h>
#include <hip/hip_bf16.h>

#define S_LEN 1024
#define HID 7168
#define NH 128
#define DQ 1536
#define DKV 512
#define DH 128
#define DR 64

typedef __attribute__((ext_vector_type(8))) short bf16x8;
typedef __attribute__((ext_vector_type(4))) float f32x4;
typedef __attribute__((ext_vector_type(4))) float fl4;
typedef __attribute__((ext_vector_type(4))) unsigned short us4;
typedef __attribute__((ext_vector_type(8))) unsigned short us8;
typedef __attribute__((ext_vector_type(4))) unsigned int u32x4;

static __device__ __forceinline__ unsigned short f2bf(float f) {
  union { float f; unsigned int u; } v; v.f = f;
  unsigned int u = v.u;
  return (unsigned short)((u + 0x7fffu + ((u >> 16) & 1u)) >> 16);
}
static __device__ __forceinline__ float bf2f(unsigned short u) {
  union { unsigned int u; float f; } v; v.u = ((unsigned int)u) << 16;
  return v.f;
}
static __device__ __forceinline__ unsigned int cvtpk2(float lo, float hi) {
  unsigned int r;
  asm("v_cvt_pk_bf16_f32 %0, %1, %2" : "=v"(r) : "v"(lo), "v"(hi));
  return r;
}

// ---------------- fp32 -> bf16 conversion -------------------------------------
__global__ __launch_bounds__(256) void cvt_bf16_kernel(
    const float* __restrict__ in, unsigned short* __restrict__ out, int n8) {
  int i = blockIdx.x * 256 + threadIdx.x;
  int stride = gridDim.x * 256;
  for (; i < n8; i += stride) {
    fl4 a = ((const fl4*)in)[2 * i];
    fl4 b = ((const fl4*)in)[2 * i + 1];
    us8 u = { f2bf(a[0]), f2bf(a[1]), f2bf(a[2]), f2bf(a[3]),
              f2bf(b[0]), f2bf(b[1]), f2bf(b[2]), f2bf(b[3]) };
    ((us8*)out)[i] = u;
  }
}

// ---------------- bf16 GEMM (m97 structure + T14 W-prefetch) ------------------
// OUTMODE 1: C = bf16((A@W^T + bias) * alpha), grid.z==1
// OUTMODE 2: fp32 partials per K-slice at Cv + z*zstride (split-K), no bias
// WFP32 1: W read as fp32, prefetched to regs one K-step ahead, cvt in staging.
// grid.x may be PADDED to a multiple of 8 (XCD colocation of m-groups).
template <int OUTMODE, int WFP32>
__global__ __launch_bounds__(256) void gemm_k(
    const unsigned short* __restrict__ A, int lda,
    const unsigned short* __restrict__ Wb16,
    const float* __restrict__ Wfa, const float* __restrict__ Wfb, int nsplit,
    int ldw,
    const float* __restrict__ bias,
    void* __restrict__ Cv, int ldc, size_t zstride,
    int Ncl, int ksl, float alpha)
{
  const int n0 = blockIdx.x * 128;
  if (n0 >= Ncl) return;                 // padded-grid early exit (block-uniform)

  __shared__ unsigned short As[128 * 64];
  __shared__ unsigned short Ws[128 * 64];
  const int t = threadIdx.x;
  const int l = t & 63, w = t >> 6;
  const int r15 = l & 15, g = l >> 4;
  const int wm = (w >> 1) * 64, wn = (w & 1) * 64;
  const int m0 = blockIdx.y * 128;
  const int kbase = blockIdx.z * ksl;
  const int srow = l >> 3;
  const int scol = (l & 7) * 8;

  f32x4 acc[4][4];
#pragma unroll
  for (int i = 0; i < 4; ++i)
#pragma unroll
    for (int j = 0; j < 4; ++j) acc[i][j] = (f32x4){0.f, 0.f, 0.f, 0.f};

  const unsigned short* Ab = A + (size_t)m0 * lda;
  const unsigned short* Wb = nullptr;
  const float* Wf = nullptr;
  if constexpr (WFP32) {
    Wf = (n0 < nsplit) ? Wfa + (size_t)n0 * ldw : Wfb + (size_t)(n0 - nsplit) * ldw;
  } else {
    Wb = Wb16 + (size_t)n0 * ldw;
  }

  fl4 wx[4], wy[4];
  auto issueW = [&](int k0) {
#pragma unroll
    for (int i = 0; i < 4; ++i) {
      int c = t + 256 * i;
      const float* src = Wf + (size_t)(c >> 3) * ldw + k0 + (c & 7) * 8;
      wx[i] = *(const fl4*)src;
      wy[i] = *(const fl4*)(src + 4);
    }
  };

  if constexpr (WFP32) issueW(kbase);
  const int kend = kbase + ksl;

  for (int k0 = kbase; k0 < kend; k0 += 64) {
    __syncthreads();
#pragma unroll
    for (int i = 0; i < 4; ++i) {
      int chunk = w * 4 + i;
      int row = chunk * 8 + srow;
      __builtin_amdgcn_global_load_lds(
          (const __attribute__((address_space(1))) void*)(Ab + (size_t)row * lda + k0 + scol),
          (__attribute__((address_space(3))) void*)(As + chunk * 512), 16, 0, 0);
      if constexpr (!WFP32) {
        __builtin_amdgcn_global_load_lds(
            (const __attribute__((address_space(1))) void*)(Wb + (size_t)row * ldw + k0 + scol),
            (__attribute__((address_space(3))) void*)(Ws + chunk * 512), 16, 0, 0);
      }
    }
    if constexpr (WFP32) {
#pragma unroll
      for (int i = 0; i < 4; ++i) {
        int c = t + 256 * i;
        u32x4 p = { cvtpk2(wx[i][0], wx[i][1]), cvtpk2(wx[i][2], wx[i][3]),
                    cvtpk2(wy[i][0], wy[i][1]), cvtpk2(wy[i][2], wy[i][3]) };
        ((u32x4*)Ws)[c] = p;
      }
    }
    __syncthreads();
    if constexpr (WFP32) {
      if (k0 + 64 < kend) issueW(k0 + 64);   // T14: next W loads fly over MFMA
    }
#pragma unroll
    for (int kk = 0; kk < 2; ++kk) {
      bf16x8 a[4], b[4];
#pragma unroll
      for (int mt = 0; mt < 4; ++mt)
        a[mt] = *reinterpret_cast<const bf16x8*>(&As[(wm + mt * 16 + r15) * 64 + kk * 32 + 8 * g]);
#pragma unroll
      for (int nt = 0; nt < 4; ++nt)
        b[nt] = *reinterpret_cast<const bf16x8*>(&Ws[(wn + nt * 16 + r15) * 64 + kk * 32 + 8 * g]);
#pragma unroll
      for (int mt = 0; mt < 4; ++mt)
#pragma unroll
        for (int nt = 0; nt < 4; ++nt)
          acc[mt][nt] = __builtin_amdgcn_mfma_f32_16x16x32_bf16(a[mt], b[nt], acc[mt][nt], 0, 0, 0);
    }
  }

  if constexpr (OUTMODE == 1) {
    float bv[4];
#pragma unroll
    for (int nt = 0; nt < 4; ++nt) {
      int col = n0 + wn + nt * 16 + r15;
      bv[nt] = (col < Ncl) ? bias[col] : 0.f;
    }
#pragma unroll
    for (int mt = 0; mt < 4; ++mt)
#pragma unroll
      for (int nt = 0; nt < 4; ++nt) {
        int col = n0 + wn + nt * 16 + r15;
        if (col < Ncl) {
#pragma unroll
          for (int r = 0; r < 4; ++r) {
            int row = m0 + wm + mt * 16 + g * 4 + r;
            ((unsigned short*)Cv)[(size_t)row * ldc + col] =
                f2bf((acc[mt][nt][r] + bv[nt]) * alpha);
          }
        }
      }
  } else {
    float* Cp = (float*)Cv + blockIdx.z * zstride;
#pragma unroll
    for (int mt = 0; mt < 4; ++mt)
#pragma unroll
      for (int nt = 0; nt < 4; ++nt) {
        int col = n0 + wn + nt * 16 + r15;
        if (col < Ncl) {
#pragma unroll
          for (int r = 0; r < 4; ++r) {
            int row = m0 + wm + mt * 16 + g * 4 + r;
            Cp[(size_t)row * ldc + col] = acc[mt][nt][r];
          }
        }
      }
  }
}

// ---------------- split-K reductions ------------------------------------------
__global__ __launch_bounds__(256) void reduce_f32_kernel(
    const float* __restrict__ pbuf, const float* __restrict__ bias,
    float* __restrict__ out, int ldo, int rowlen4, int nz, size_t zstride, int total4)
{
  int idx = blockIdx.x * 256 + threadIdx.x;
  if (idx >= total4) return;
  int r = idx / rowlen4, c4 = idx % rowlen4;
  fl4 acc = *(const fl4*)(bias + c4 * 4);
  for (int z = 0; z < nz; ++z)
    acc += *(const fl4*)(pbuf + z * zstride + (size_t)idx * 4);
  *(fl4*)(out + (size_t)r * ldo + c4 * 4) = acc;
}

__global__ __launch_bounds__(256) void reduce_bf16_kernel(
    const float* __restrict__ pbuf, const float* __restrict__ bias,
    unsigned short* __restrict__ out, int ldo, int rowlen4, int nz, size_t zstride, int total4)
{
  int idx = blockIdx.x * 256 + threadIdx.x;
  if (idx >= total4) return;
  int r = idx / rowlen4, c4 = idx % rowlen4;
  fl4 acc = *(const fl4*)(bias + c4 * 4);
  for (int z = 0; z < nz; ++z)
    acc += *(const fl4*)(pbuf + z * zstride + (size_t)idx * 4);
  us4 u = { f2bf(acc[0]), f2bf(acc[1]), f2bf(acc[2]), f2bf(acc[3]) };
  *(us4*)(out + (size_t)r * ldo + c4 * 4) = u;
}

// ---------------- rope tables + table-based rope ------------------------------
__global__ __launch_bounds__(256) void rope_table_kernel(float* __restrict__ ctab,
                                                         float* __restrict__ stab) {
  int idx = blockIdx.x * 256 + threadIdx.x;
  if (idx >= S_LEN * 32) return;
  int j = idx & 31, s = idx >> 5;
  float invf = expf(-0.28782313662425574f * (float)j);
  float ang = (float)s * invf;
  ctab[idx] = cosf(ang);
  stab[idx] = sinf(ang);
}

__global__ void rope_bf16_kernel(unsigned short* __restrict__ x, int nh, int lda, int total,
                                 const float* __restrict__ ctab,
                                 const float* __restrict__ stab) {
  int idx = blockIdx.x * 256 + threadIdx.x;
  if (idx >= total) return;
  int j = idx & 31;
  int rest = idx >> 5;
  int hh = rest % nh;
  int s = rest / nh;
  float c = ctab[s * 32 + j], sn = stab[s * 32 + j];
  size_t base = (size_t)s * lda + hh * 64;
  float x1 = bf2f(x[base + j]), x2 = bf2f(x[base + j + 32]);
  x[base + j]      = f2bf(x1 * c - x2 * sn);
  x[base + j + 32] = f2bf(x2 * c + x1 * sn);
}

// ---------------- V transpose -------------------------------------------------
__global__ __launch_bounds__(256) void vtrans_kernel(
    const unsigned short* __restrict__ kvb, unsigned short* __restrict__ vt) {
  __shared__ unsigned short tl[64][72];
  const int s0 = blockIdx.x * 64;
  const int c0 = blockIdx.y * 64;
  const int t = threadIdx.x;
  const int rr = t >> 3, cc = (t & 7) * 8;
  const int hbase = (c0 >> 7) * 256 + 128 + (c0 & 127);
#pragma unroll
  for (int i = 0; i < 2; ++i) {
    int r = rr + i * 32;
    *reinterpret_cast<bf16x8*>(&tl[r][cc]) =
        *reinterpret_cast<const bf16x8*>(kvb + (size_t)(s0 + r) * 32768 + hbase + cc);
  }
  __syncthreads();
#pragma unroll
  for (int i = 0; i < 2; ++i) {
    int vc = rr + i * 32;
    unsigned short tmp[8];
#pragma unroll
    for (int j = 0; j < 8; ++j) tmp[j] = tl[cc + j][vc];
    *reinterpret_cast<bf16x8*>(&vt[(size_t)(c0 + vc) * 1024 + s0 + cc]) =
        *reinterpret_cast<bf16x8*>(tmp);
  }
}

// ---------------- flash attention: QBLK=128, 8 waves/block --------------------
// 1024 blocks (128 heads x 8 q-blocks), 512 threads. K/V staged ONCE per block
// serve 8 waves (halves K/V read traffic vs 4-wave QBLK=64); per-wave compute
// identical (16 q-rows). LDS 62.4 KB -> 2 blocks/CU = 16 waves/CU.
__global__ __launch_bounds__(512) void mla_attn_kernel(
    const unsigned short* __restrict__ qcat,
    const unsigned short* __restrict__ kvb,
    const unsigned short* __restrict__ kr,
    const unsigned short* __restrict__ vt,
    unsigned short* __restrict__ obuf)
{
  __shared__ unsigned short Klds[64][200];
  __shared__ unsigned short Vlds[128][72];
  __shared__ unsigned short Plds[8][16][72];

  const int t = threadIdx.x;
  const int l = t & 63, w = t >> 6;        // 8 waves
  const int r15 = l & 15, g = l >> 4;
  const int bid = blockIdx.x;
  const int orig = (bid & 7) * 128 + (bid >> 3);   // 1024 % 8 == 0: bijective
  const int h = orig >> 3;
  const int q0 = (orig & 7) * 128;

  bf16x8 qf[6];
  const unsigned short* qrow = qcat + (size_t)(q0 + w * 16 + r15) * 24576;
#pragma unroll
  for (int kk = 0; kk < 4; ++kk)
    qf[kk] = *reinterpret_cast<const bf16x8*>(qrow + h * 128 + kk * 32 + 8 * g);
#pragma unroll
  for (int kk = 4; kk < 6; ++kk)
    qf[kk] = *reinterpret_cast<const bf16x8*>(qrow + 16384 + h * 64 + (kk - 4) * 32 + 8 * g);

  bf16x8 kreg[3], vreg[2];
  auto loadKV = [&](int kk0) {
#pragma unroll
    for (int i = 0; i < 3; ++i) {
      int c = t + 512 * i, row = c / 24, cb = c % 24;   // 1536 cells: 64 x 24
      const unsigned short* src = (cb < 16)
          ? kvb + (size_t)(kk0 + row) * 32768 + h * 256 + cb * 8
          : kr + (size_t)(kk0 + row) * 2112 + (cb - 16) * 8;
      kreg[i] = *reinterpret_cast<const bf16x8*>(src);
    }
#pragma unroll
    for (int i = 0; i < 2; ++i) {
      int c = t + 512 * i, d = c >> 3, kb = c & 7;      // 1024 cells: 128 x 8
      vreg[i] = *reinterpret_cast<const bf16x8*>(vt + ((size_t)h * 128 + d) * 1024 + kk0 + kb * 8);
    }
  };

  float m_r[4], l_r[4];
  f32x4 oacc[8];
#pragma unroll
  for (int r = 0; r < 4; ++r) { m_r[r] = -1e30f; l_r[r] = 0.f; }
#pragma unroll
  for (int d = 0; d < 8; ++d) oacc[d] = (f32x4){0.f, 0.f, 0.f, 0.f};

  loadKV(0);

  for (int kt = 0; kt < 16; ++kt) {
    __syncthreads();
#pragma unroll
    for (int i = 0; i < 3; ++i) {
      int c = t + 512 * i, row = c / 24, cb = c % 24;
      *reinterpret_cast<bf16x8*>(&Klds[row][cb * 8]) = kreg[i];
    }
#pragma unroll
    for (int i = 0; i < 2; ++i) {
      int c = t + 512 * i, d = c >> 3, kb = c & 7;
      *reinterpret_cast<bf16x8*>(&Vlds[d][kb * 8]) = vreg[i];
    }
    __syncthreads();
    if (kt < 15) loadKV((kt + 1) * 64);   // T14: loads land during compute

    // S = Q K^T
    f32x4 sacc[4];
#pragma unroll
    for (int nt = 0; nt < 4; ++nt) sacc[nt] = (f32x4){0.f, 0.f, 0.f, 0.f};
    __builtin_amdgcn_s_setprio(1);
#pragma unroll
    for (int nt = 0; nt < 4; ++nt)
#pragma unroll
      for (int kk = 0; kk < 6; ++kk) {
        bf16x8 b = *reinterpret_cast<const bf16x8*>(&Klds[nt * 16 + r15][kk * 32 + 8 * g]);
        sacc[nt] = __builtin_amdgcn_mfma_f32_16x16x32_bf16(qf[kk], b, sacc[nt], 0, 0, 0);
      }
    __builtin_amdgcn_s_setprio(0);

    // online softmax
    float sc[4], rsum[4];
#pragma unroll
    for (int r = 0; r < 4; ++r) {
      float mx = fmaxf(fmaxf(sacc[0][r], sacc[1][r]), fmaxf(sacc[2][r], sacc[3][r]));
      mx = fmaxf(mx, __shfl_xor(mx, 1));
      mx = fmaxf(mx, __shfl_xor(mx, 2));
      mx = fmaxf(mx, __shfl_xor(mx, 4));
      mx = fmaxf(mx, __shfl_xor(mx, 8));
      float mn = fmaxf(m_r[r], mx);
      sc[r] = __expf(m_r[r] - mn);
      m_r[r] = mn;
      rsum[r] = 0.f;
    }
#pragma unroll
    for (int nt = 0; nt < 4; ++nt)
#pragma unroll
      for (int r = 0; r < 4; ++r) {
        float p = __expf(sacc[nt][r] - m_r[r]);
        rsum[r] += p;
        Plds[w][g * 4 + r][nt * 16 + r15] = f2bf(p);
      }
#pragma unroll
    for (int r = 0; r < 4; ++r) {
      float s = rsum[r];
      s += __shfl_xor(s, 1);
      s += __shfl_xor(s, 2);
      s += __shfl_xor(s, 4);
      s += __shfl_xor(s, 8);
      l_r[r] = l_r[r] * sc[r] + s;
    }
#pragma unroll
    for (int d = 0; d < 8; ++d)
#pragma unroll
      for (int r = 0; r < 4; ++r) oacc[d][r] *= sc[r];

    // O += P V   (Plds is per-wave: wave-synchronous, no barrier needed)
    bf16x8 pa0 = *reinterpret_cast<const bf16x8*>(&Plds[w][r15][8 * g]);
    bf16x8 pa1 = *reinterpret_cast<const bf16x8*>(&Plds[w][r15][32 + 8 * g]);
    __builtin_amdgcn_s_setprio(1);
#pragma unroll
    for (int dt = 0; dt < 8; ++dt) {
      bf16x8 v0 = *reinterpret_cast<const bf16x8*>(&Vlds[dt * 16 + r15][8 * g]);
      bf16x8 v1 = *reinterpret_cast<const bf16x8*>(&Vlds[dt * 16 + r15][32 + 8 * g]);
      oacc[dt] = __builtin_amdgcn_mfma_f32_16x16x32_bf16(pa0, v0, oacc[dt], 0, 0, 0);
      oacc[dt] = __builtin_amdgcn_mfma_f32_16x16x32_bf16(pa1, v1, oacc[dt], 0, 0, 0);
    }
    __builtin_amdgcn_s_setprio(0);
  }

#pragma unroll
  for (int dt = 0; dt < 8; ++dt)
#pragma unroll
    for (int r = 0; r < 4; ++r) {
      int row = q0 + w * 16 + g * 4 + r;
      int col = h * DH + dt * 16 + r15;
      obuf[(size_t)row * 16384 + col] = f2bf(oacc[dt][r] / l_r[r]);
    }
}

// ------------------------------------------------------------------------------
extern "C" void kernel_launch(void* const* d_in, const int* in_sizes, int n_in,
                              void* d_out, int out_size, void* d_ws, size_t ws_size,
                              hipStream_t stream) {
  const float* h    = (const float*)d_in[0];
  const float* Wdq  = (const float*)d_in[1];
  const float* bdq  = (const float*)d_in[2];
  const float* Wdkv = (const float*)d_in[3];
  const float* bdkv = (const float*)d_in[4];
  const float* Wuq  = (const float*)d_in[5];
  const float* buq  = (const float*)d_in[6];
  const float* Wukv = (const float*)d_in[7];
  const float* bukv = (const float*)d_in[8];
  const float* Wrq  = (const float*)d_in[9];
  const float* brq  = (const float*)d_in[10];
  const float* Wrk  = (const float*)d_in[11];
  const float* brk  = (const float*)d_in[12];
  const float* Wo   = (const float*)d_in[13];
  const float* bo   = (const float*)d_in[14];
  float* out = (float*)d_out;

  char* ws = (char*)d_ws;
  size_t off = 0;
  auto alloc = [&](size_t bytes) {
    char* p = ws + off;
    off += (bytes + 255) & ~(size_t)255;
    return p;
  };
  unsigned short* hb    = (unsigned short*)alloc((size_t)1024 * 7168 * 2);
  unsigned short* W1cat = (unsigned short*)alloc((size_t)2176 * 7168 * 2);
  float*          b1cat = (float*)alloc(2176 * 4);
  unsigned short* ccat  = (unsigned short*)alloc((size_t)1024 * 2112 * 2);
  float*          b2cat = (float*)alloc(24576 * 4);
  unsigned short* qcat  = (unsigned short*)alloc((size_t)1024 * 24576 * 2);
  unsigned short* kvbb  = (unsigned short*)alloc((size_t)1024 * 32768 * 2);
  unsigned short* vt    = (unsigned short*)alloc((size_t)16384 * 1024 * 2);
  unsigned short* obuf  = (unsigned short*)alloc((size_t)1024 * 16384 * 2);
  float*          ctab  = (float*)alloc((size_t)S_LEN * 32 * 4);
  float*          stab  = (float*)alloc((size_t)S_LEN * 32 * 4);
  // G1 split-K partials alias not-yet-written qcat (34.6 MB < 50.3 MB)
  float* pbufG1 = (float*)qcat;
  // d_ws ~1.75 GB: Wob (full bf16 Wo, 235 MB) @ 288 MiB; pbufG4 (117.4 MB) @ 544 MiB.
  unsigned short* Wob    = (unsigned short*)(ws + ((size_t)288 << 20));
  float*          pbufG4 = (float*)(ws + ((size_t)544 << 20));

  auto cvt = [&](const float* in, unsigned short* outp, size_t n) {
    int n8 = (int)(n / 8);
    int blocks = (n8 + 255) / 256;
    if (blocks > 2048) blocks = 2048;
    cvt_bf16_kernel<<<blocks, 256, 0, stream>>>(in, outp, n8);
  };

  // --- conversions for h and the small concatenated W1 ---
  cvt(h,    hb,    (size_t)1024 * 7168);
  cvt(Wdq,  W1cat, (size_t)1536 * 7168);
  cvt(Wdkv, W1cat + (size_t)1536 * 7168, (size_t)512 * 7168);
  cvt(Wrk,  W1cat + (size_t)2048 * 7168, (size_t)64 * 7168);
  hipMemsetAsync(W1cat + (size_t)2112 * 7168, 0, (size_t)64 * 7168 * 2, stream);
  hipMemcpyAsync(b1cat,        bdq,  1536 * 4, hipMemcpyDeviceToDevice, stream);
  hipMemcpyAsync(b1cat + 1536, bdkv, 512 * 4,  hipMemcpyDeviceToDevice, stream);
  hipMemcpyAsync(b1cat + 2048, brk,  64 * 4,   hipMemcpyDeviceToDevice, stream);
  hipMemsetAsync(b1cat + 2112, 0, 64 * 4, stream);
  hipMemcpyAsync(b2cat,         buq, 16384 * 4, hipMemcpyDeviceToDevice, stream);
  hipMemcpyAsync(b2cat + 16384, brq, 8192 * 4,  hipMemcpyDeviceToDevice, stream);
  rope_table_kernel<<<(S_LEN * 32 + 255) / 256, 256, 0, stream>>>(ctab, stab);

  const float scale = 0.07216878364870323f;   // 1/sqrt(192)
  const int BIGN = 1 << 30;
  dim3 blk(256);

  // G1 (split-K=4, bf16 W): partials = h @ W1cat^T
  gemm_k<2, 0><<<dim3(24, 8, 4), blk, 0, stream>>>(
      hb, 7168, W1cat, nullptr, nullptr, BIGN, 7168, nullptr,
      pbufG1, 2112, (size_t)1024 * 2112, 2112, 1792, 1.0f);
  reduce_bf16_kernel<<<2112, blk, 0, stream>>>(pbufG1, b1cat, ccat, 2112, 528, 4,
                                               (size_t)1024 * 2112, 1024 * 2112 / 4);
  rope_bf16_kernel<<<(1024 * 32 + 255) / 256, blk, 0, stream>>>(ccat + 2048, 1, 2112, 1024 * 32, ctab, stab);

  // G2 (fp32 W direct): [q_c | q_r] = (c_q @ [Wuq;Wrq]^T + b2cat) * scale
  gemm_k<1, 1><<<dim3(192, 8, 1), blk, 0, stream>>>(
      ccat, 2112, nullptr, Wuq, Wrq, 16384, 1536, b2cat,
      qcat, 24576, 0, 24576, 1536, scale);
  rope_bf16_kernel<<<(1024 * 128 * 32 + 255) / 256, blk, 0, stream>>>(qcat + 16384, 128, 24576, 1024 * 128 * 32, ctab, stab);

  // G3 (fp32 W direct): kv = c_kv @ Wukv^T + bukv
  gemm_k<1, 1><<<dim3(256, 8, 1), blk, 0, stream>>>(
      ccat + 1536, 2112, nullptr, Wukv, Wukv, BIGN, 512, bukv,
      kvbb, 32768, 0, 32768, 512, 1.0f);
  vtrans_kernel<<<dim3(16, 256), blk, 0, stream>>>(kvbb, vt);
  // attention: QBLK=128, 8 waves, 1024 blocks, 512 threads
  mla_attn_kernel<<<dim3(1024), dim3(512), 0, stream>>>(qcat, kvbb, ccat + 2048, vt, obuf);

  // G4: single launch. Full bf16 Wo (235 MB) FITS the 256 MB L3; grid (56,8,4)
  // = 1792 blocks (7/CU queued) restores TLP; 56 % 8 == 0 keeps XCD colocation.
  cvt(Wo, Wob, (size_t)7168 * 16384);
  gemm_k<2, 0><<<dim3(56, 8, 4), blk, 0, stream>>>(
      obuf, 16384, Wob, nullptr, nullptr, BIGN, 16384, nullptr,
      pbufG4, 7168, (size_t)1024 * 7168, 7168, 4096, 1.0f);
  reduce_f32_kernel<<<7168, blk, 0, stream>>>(pbufG4, bo, out,
                                              7168, 1792, 4, (size_t)1024 * 7168, 1024 * 7168 / 4);
}

// Round 14
// 1124.432 us; speedup vs baseline: 1.0934x; 1.0547x over previous
//
#include <hip/hip_runtime.h>
#include <hip/hip_bf16.h>

#define S_LEN 1024
#define HID 7168
#define NH 128
#define DQ 1536
#define DKV 512
#define DH 128
#define DR 64

typedef __attribute__((ext_vector_type(8))) short bf16x8;
typedef __attribute__((ext_vector_type(4))) float f32x4;
typedef __attribute__((ext_vector_type(4))) float fl4;
typedef __attribute__((ext_vector_type(4))) unsigned short us4;
typedef __attribute__((ext_vector_type(8))) unsigned short us8;
typedef __attribute__((ext_vector_type(4))) unsigned int u32x4;

static __device__ __forceinline__ unsigned short f2bf(float f) {
  union { float f; unsigned int u; } v; v.f = f;
  unsigned int u = v.u;
  return (unsigned short)((u + 0x7fffu + ((u >> 16) & 1u)) >> 16);
}
static __device__ __forceinline__ float bf2f(unsigned short u) {
  union { unsigned int u; float f; } v; v.u = ((unsigned int)u) << 16;
  return v.f;
}
static __device__ __forceinline__ unsigned int cvtpk2(float lo, float hi) {
  unsigned int r;
  asm("v_cvt_pk_bf16_f32 %0, %1, %2" : "=v"(r) : "v"(lo), "v"(hi));
  return r;
}

// ---------------- fp32 -> bf16 conversion -------------------------------------
__global__ __launch_bounds__(256) void cvt_bf16_kernel(
    const float* __restrict__ in, unsigned short* __restrict__ out, int n8) {
  int i = blockIdx.x * 256 + threadIdx.x;
  int stride = gridDim.x * 256;
  for (; i < n8; i += stride) {
    fl4 a = ((const fl4*)in)[2 * i];
    fl4 b = ((const fl4*)in)[2 * i + 1];
    us8 u = { f2bf(a[0]), f2bf(a[1]), f2bf(a[2]), f2bf(a[3]),
              f2bf(b[0]), f2bf(b[1]), f2bf(b[2]), f2bf(b[3]) };
    ((us8*)out)[i] = u;
  }
}

// ---------------- bf16 GEMM (m97 structure + T14 W-prefetch) ------------------
// OUTMODE 1: C = bf16((A@W^T + bias) * alpha), grid.z==1
// OUTMODE 2: fp32 partials per K-slice at Cv + z*zstride (split-K), no bias
// WFP32 1: W read as fp32, reg-prefetched 1 K-step ahead, cvt_pk in staging.
// ROPEQ 1: for output cols >= 16384 (q_r), apply RoPE in-epilogue (pair
//          (j, j+32) = (nt, nt+2) same thread/lane/reg), then *alpha, 1 round.
template <int OUTMODE, int WFP32, int ROPEQ = 0>
__global__ __launch_bounds__(256) void gemm_k(
    const unsigned short* __restrict__ A, int lda,
    const unsigned short* __restrict__ Wb16,
    const float* __restrict__ Wfa, const float* __restrict__ Wfb, int nsplit,
    int ldw,
    const float* __restrict__ bias,
    void* __restrict__ Cv, int ldc, size_t zstride,
    int Ncl, int ksl, float alpha,
    const float* __restrict__ ctab = nullptr,
    const float* __restrict__ stab = nullptr)
{
  const int n0 = blockIdx.x * 128;
  if (n0 >= Ncl) return;                 // padded-grid early exit (block-uniform)

  __shared__ unsigned short As[128 * 64];
  __shared__ unsigned short Ws[128 * 64];
  const int t = threadIdx.x;
  const int l = t & 63, w = t >> 6;
  const int r15 = l & 15, g = l >> 4;
  const int wm = (w >> 1) * 64, wn = (w & 1) * 64;
  const int m0 = blockIdx.y * 128;
  const int kbase = blockIdx.z * ksl;
  const int srow = l >> 3;
  const int scol = (l & 7) * 8;

  f32x4 acc[4][4];
#pragma unroll
  for (int i = 0; i < 4; ++i)
#pragma unroll
    for (int j = 0; j < 4; ++j) acc[i][j] = (f32x4){0.f, 0.f, 0.f, 0.f};

  const unsigned short* Ab = A + (size_t)m0 * lda;
  const unsigned short* Wb = nullptr;
  const float* Wf = nullptr;
  if constexpr (WFP32) {
    Wf = (n0 < nsplit) ? Wfa + (size_t)n0 * ldw : Wfb + (size_t)(n0 - nsplit) * ldw;
  } else {
    Wb = Wb16 + (size_t)n0 * ldw;
  }

  fl4 wx[4], wy[4];
  auto issueW = [&](int k0) {
#pragma unroll
    for (int i = 0; i < 4; ++i) {
      int c = t + 256 * i;
      const float* src = Wf + (size_t)(c >> 3) * ldw + k0 + (c & 7) * 8;
      wx[i] = *(const fl4*)src;
      wy[i] = *(const fl4*)(src + 4);
    }
  };

  if constexpr (WFP32) issueW(kbase);
  const int kend = kbase + ksl;

  for (int k0 = kbase; k0 < kend; k0 += 64) {
    __syncthreads();
#pragma unroll
    for (int i = 0; i < 4; ++i) {
      int chunk = w * 4 + i;
      int row = chunk * 8 + srow;
      __builtin_amdgcn_global_load_lds(
          (const __attribute__((address_space(1))) void*)(Ab + (size_t)row * lda + k0 + scol),
          (__attribute__((address_space(3))) void*)(As + chunk * 512), 16, 0, 0);
      if constexpr (!WFP32) {
        __builtin_amdgcn_global_load_lds(
            (const __attribute__((address_space(1))) void*)(Wb + (size_t)row * ldw + k0 + scol),
            (__attribute__((address_space(3))) void*)(Ws + chunk * 512), 16, 0, 0);
      }
    }
    if constexpr (WFP32) {
#pragma unroll
      for (int i = 0; i < 4; ++i) {
        int c = t + 256 * i;
        u32x4 p = { cvtpk2(wx[i][0], wx[i][1]), cvtpk2(wx[i][2], wx[i][3]),
                    cvtpk2(wy[i][0], wy[i][1]), cvtpk2(wy[i][2], wy[i][3]) };
        ((u32x4*)Ws)[c] = p;
      }
    }
    __syncthreads();
    if constexpr (WFP32) {
      if (k0 + 64 < kend) issueW(k0 + 64);   // T14: next W loads fly over MFMA
    }
#pragma unroll
    for (int kk = 0; kk < 2; ++kk) {
      bf16x8 a[4], b[4];
#pragma unroll
      for (int mt = 0; mt < 4; ++mt)
        a[mt] = *reinterpret_cast<const bf16x8*>(&As[(wm + mt * 16 + r15) * 64 + kk * 32 + 8 * g]);
#pragma unroll
      for (int nt = 0; nt < 4; ++nt)
        b[nt] = *reinterpret_cast<const bf16x8*>(&Ws[(wn + nt * 16 + r15) * 64 + kk * 32 + 8 * g]);
#pragma unroll
      for (int mt = 0; mt < 4; ++mt)
#pragma unroll
        for (int nt = 0; nt < 4; ++nt)
          acc[mt][nt] = __builtin_amdgcn_mfma_f32_16x16x32_bf16(a[mt], b[nt], acc[mt][nt], 0, 0, 0);
    }
  }

  if constexpr (OUTMODE == 1) {
    float bv[4];
#pragma unroll
    for (int nt = 0; nt < 4; ++nt) {
      int col = n0 + wn + nt * 16 + r15;
      bv[nt] = (col < Ncl) ? bias[col] : 0.f;
    }
    bool isrope = false;
    if constexpr (ROPEQ) isrope = (n0 + wn) >= 16384;   // wave-uniform
    if (ROPEQ && isrope) {
#pragma unroll
      for (int mt = 0; mt < 4; ++mt)
#pragma unroll
        for (int r = 0; r < 4; ++r) {
          int row = m0 + wm + mt * 16 + g * 4 + r;
#pragma unroll
          for (int ntp = 0; ntp < 2; ++ntp) {
            int j = ntp * 16 + r15;                  // within-head idx, < 32
            float c = ctab[row * 32 + j];
            float s = stab[row * 32 + j];
            float x1 = acc[mt][ntp][r] + bv[ntp];
            float x2 = acc[mt][ntp + 2][r] + bv[ntp + 2];
            int col1 = n0 + wn + ntp * 16 + r15;
            ((unsigned short*)Cv)[(size_t)row * ldc + col1] =
                f2bf((x1 * c - x2 * s) * alpha);
            ((unsigned short*)Cv)[(size_t)row * ldc + col1 + 32] =
                f2bf((x2 * c + x1 * s) * alpha);
          }
        }
    } else {
#pragma unroll
      for (int mt = 0; mt < 4; ++mt)
#pragma unroll
        for (int nt = 0; nt < 4; ++nt) {
          int col = n0 + wn + nt * 16 + r15;
          if (col < Ncl) {
#pragma unroll
            for (int r = 0; r < 4; ++r) {
              int row = m0 + wm + mt * 16 + g * 4 + r;
              ((unsigned short*)Cv)[(size_t)row * ldc + col] =
                  f2bf((acc[mt][nt][r] + bv[nt]) * alpha);
            }
          }
        }
    }
  } else {
    float* Cp = (float*)Cv + blockIdx.z * zstride;
#pragma unroll
    for (int mt = 0; mt < 4; ++mt)
#pragma unroll
      for (int nt = 0; nt < 4; ++nt) {
        int col = n0 + wn + nt * 16 + r15;
        if (col < Ncl) {
#pragma unroll
          for (int r = 0; r < 4; ++r) {
            int row = m0 + wm + mt * 16 + g * 4 + r;
            Cp[(size_t)row * ldc + col] = acc[mt][nt][r];
          }
        }
      }
  }
}

// ---------------- G4 dedicated: fp32-W direct, L2-sharer-adjacent grid --------
// Linear grid 1792 = 4z x 7grp x 8m x 8nlo. id = z*448 + grp*64 + m*8 + nlo.
// The 8 m-sharers of a W-tile sit at id-stride 8: SAME XCD (8%8==0) and
// temporally ADJACENT -> they co-progress through one ~16KB K-window of the
// 2MB fp32 W-tile, always L2-hot -> Wo fetched ~once from HBM.
__global__ __launch_bounds__(256) void gemm_g4(
    const unsigned short* __restrict__ A,      // obuf [1024][16384] bf16
    const float* __restrict__ W,               // Wo  [7168][16384] fp32
    float* __restrict__ pbuf)                  // [4][1024][7168] fp32 partials
{
  __shared__ unsigned short As[128 * 64];
  __shared__ unsigned short Ws[128 * 64];
  const int t = threadIdx.x;
  const int l = t & 63, w = t >> 6;
  const int r15 = l & 15, g = l >> 4;
  const int wm = (w >> 1) * 64, wn = (w & 1) * 64;
  const int bid = blockIdx.x;
  const int z = bid / 448;
  const int r448 = bid % 448;
  const int grp = r448 >> 6, wi = r448 & 63;
  const int m0 = (wi >> 3) * 128;
  const int n0 = (grp * 8 + (wi & 7)) * 128;
  const int kbase = z * 4096;
  const int srow = l >> 3, scol = (l & 7) * 8;

  f32x4 acc[4][4];
#pragma unroll
  for (int i = 0; i < 4; ++i)
#pragma unroll
    for (int j = 0; j < 4; ++j) acc[i][j] = (f32x4){0.f, 0.f, 0.f, 0.f};

  const unsigned short* Ab = A + (size_t)m0 * 16384;
  const float* Wf = W + (size_t)n0 * 16384;

  fl4 wx[4], wy[4];
  auto issueW = [&](int k0) {
#pragma unroll
    for (int i = 0; i < 4; ++i) {
      int c = t + 256 * i;
      const float* src = Wf + (size_t)(c >> 3) * 16384 + k0 + (c & 7) * 8;
      wx[i] = *(const fl4*)src;
      wy[i] = *(const fl4*)(src + 4);
    }
  };
  issueW(kbase);
  const int kend = kbase + 4096;

  for (int k0 = kbase; k0 < kend; k0 += 64) {
    __syncthreads();
#pragma unroll
    for (int i = 0; i < 4; ++i) {
      int chunk = w * 4 + i;
      int row = chunk * 8 + srow;
      __builtin_amdgcn_global_load_lds(
          (const __attribute__((address_space(1))) void*)(Ab + (size_t)row * 16384 + k0 + scol),
          (__attribute__((address_space(3))) void*)(As + chunk * 512), 16, 0, 0);
    }
#pragma unroll
    for (int i = 0; i < 4; ++i) {
      int c = t + 256 * i;
      u32x4 p = { cvtpk2(wx[i][0], wx[i][1]), cvtpk2(wx[i][2], wx[i][3]),
                  cvtpk2(wy[i][0], wy[i][1]), cvtpk2(wy[i][2], wy[i][3]) };
      ((u32x4*)Ws)[c] = p;
    }
    __syncthreads();
    if (k0 + 64 < kend) issueW(k0 + 64);   // T14
#pragma unroll
    for (int kk = 0; kk < 2; ++kk) {
      bf16x8 a[4], b[4];
#pragma unroll
      for (int mt = 0; mt < 4; ++mt)
        a[mt] = *reinterpret_cast<const bf16x8*>(&As[(wm + mt * 16 + r15) * 64 + kk * 32 + 8 * g]);
#pragma unroll
      for (int nt = 0; nt < 4; ++nt)
        b[nt] = *reinterpret_cast<const bf16x8*>(&Ws[(wn + nt * 16 + r15) * 64 + kk * 32 + 8 * g]);
#pragma unroll
      for (int mt = 0; mt < 4; ++mt)
#pragma unroll
        for (int nt = 0; nt < 4; ++nt)
          acc[mt][nt] = __builtin_amdgcn_mfma_f32_16x16x32_bf16(a[mt], b[nt], acc[mt][nt], 0, 0, 0);
    }
  }

  float* Cp = pbuf + (size_t)z * 1024 * 7168;
#pragma unroll
  for (int mt = 0; mt < 4; ++mt)
#pragma unroll
    for (int nt = 0; nt < 4; ++nt) {
      int col = n0 + wn + nt * 16 + r15;
#pragma unroll
      for (int r = 0; r < 4; ++r) {
        int row = m0 + wm + mt * 16 + g * 4 + r;
        Cp[(size_t)row * 7168 + col] = acc[mt][nt][r];
      }
    }
}

// ---------------- split-K reductions ------------------------------------------
__global__ __launch_bounds__(256) void reduce_f32_kernel(
    const float* __restrict__ pbuf, const float* __restrict__ bias,
    float* __restrict__ out, int ldo, int rowlen4, int nz, size_t zstride, int total4)
{
  int idx = blockIdx.x * 256 + threadIdx.x;
  if (idx >= total4) return;
  int r = idx / rowlen4, c4 = idx % rowlen4;
  fl4 acc = *(const fl4*)(bias + c4 * 4);
  for (int z = 0; z < nz; ++z)
    acc += *(const fl4*)(pbuf + z * zstride + (size_t)idx * 4);
  *(fl4*)(out + (size_t)r * ldo + c4 * 4) = acc;
}

__global__ __launch_bounds__(256) void reduce_bf16_kernel(
    const float* __restrict__ pbuf, const float* __restrict__ bias,
    unsigned short* __restrict__ out, int ldo, int rowlen4, int nz, size_t zstride, int total4)
{
  int idx = blockIdx.x * 256 + threadIdx.x;
  if (idx >= total4) return;
  int r = idx / rowlen4, c4 = idx % rowlen4;
  fl4 acc = *(const fl4*)(bias + c4 * 4);
  for (int z = 0; z < nz; ++z)
    acc += *(const fl4*)(pbuf + z * zstride + (size_t)idx * 4);
  us4 u = { f2bf(acc[0]), f2bf(acc[1]), f2bf(acc[2]), f2bf(acc[3]) };
  *(us4*)(out + (size_t)r * ldo + c4 * 4) = u;
}

// ---------------- rope tables + table-based rope (k_r only) -------------------
__global__ __launch_bounds__(256) void rope_table_kernel(float* __restrict__ ctab,
                                                         float* __restrict__ stab) {
  int idx = blockIdx.x * 256 + threadIdx.x;
  if (idx >= S_LEN * 32) return;
  int j = idx & 31, s = idx >> 5;
  float invf = expf(-0.28782313662425574f * (float)j);
  float ang = (float)s * invf;
  ctab[idx] = cosf(ang);
  stab[idx] = sinf(ang);
}

__global__ void rope_bf16_kernel(unsigned short* __restrict__ x, int nh, int lda, int total,
                                 const float* __restrict__ ctab,
                                 const float* __restrict__ stab) {
  int idx = blockIdx.x * 256 + threadIdx.x;
  if (idx >= total) return;
  int j = idx & 31;
  int rest = idx >> 5;
  int hh = rest % nh;
  int s = rest / nh;
  float c = ctab[s * 32 + j], sn = stab[s * 32 + j];
  size_t base = (size_t)s * lda + hh * 64;
  float x1 = bf2f(x[base + j]), x2 = bf2f(x[base + j + 32]);
  x[base + j]      = f2bf(x1 * c - x2 * sn);
  x[base + j + 32] = f2bf(x2 * c + x1 * sn);
}

// ---------------- V transpose -------------------------------------------------
__global__ __launch_bounds__(256) void vtrans_kernel(
    const unsigned short* __restrict__ kvb, unsigned short* __restrict__ vt) {
  __shared__ unsigned short tl[64][72];
  const int s0 = blockIdx.x * 64;
  const int c0 = blockIdx.y * 64;
  const int t = threadIdx.x;
  const int rr = t >> 3, cc = (t & 7) * 8;
  const int hbase = (c0 >> 7) * 256 + 128 + (c0 & 127);
#pragma unroll
  for (int i = 0; i < 2; ++i) {
    int r = rr + i * 32;
    *reinterpret_cast<bf16x8*>(&tl[r][cc]) =
        *reinterpret_cast<const bf16x8*>(kvb + (size_t)(s0 + r) * 32768 + hbase + cc);
  }
  __syncthreads();
#pragma unroll
  for (int i = 0; i < 2; ++i) {
    int vc = rr + i * 32;
    unsigned short tmp[8];
#pragma unroll
    for (int j = 0; j < 8; ++j) tmp[j] = tl[cc + j][vc];
    *reinterpret_cast<bf16x8*>(&vt[(size_t)(c0 + vc) * 1024 + s0 + cc]) =
        *reinterpret_cast<bf16x8*>(tmp);
  }
}

// ---------------- flash attention: QBLK=128, 8 waves/block --------------------
__global__ __launch_bounds__(512) void mla_attn_kernel(
    const unsigned short* __restrict__ qcat,
    const unsigned short* __restrict__ kvb,
    const unsigned short* __restrict__ kr,
    const unsigned short* __restrict__ vt,
    unsigned short* __restrict__ obuf)
{
  __shared__ unsigned short Klds[64][200];
  __shared__ unsigned short Vlds[128][72];
  __shared__ unsigned short Plds[8][16][72];

  const int t = threadIdx.x;
  const int l = t & 63, w = t >> 6;
  const int r15 = l & 15, g = l >> 4;
  const int bid = blockIdx.x;
  const int orig = (bid & 7) * 128 + (bid >> 3);
  const int h = orig >> 3;
  const int q0 = (orig & 7) * 128;

  bf16x8 qf[6];
  const unsigned short* qrow = qcat + (size_t)(q0 + w * 16 + r15) * 24576;
#pragma unroll
  for (int kk = 0; kk < 4; ++kk)
    qf[kk] = *reinterpret_cast<const bf16x8*>(qrow + h * 128 + kk * 32 + 8 * g);
#pragma unroll
  for (int kk = 4; kk < 6; ++kk)
    qf[kk] = *reinterpret_cast<const bf16x8*>(qrow + 16384 + h * 64 + (kk - 4) * 32 + 8 * g);

  bf16x8 kreg[3], vreg[2];
  auto loadKV = [&](int kk0) {
#pragma unroll
    for (int i = 0; i < 3; ++i) {
      int c = t + 512 * i, row = c / 24, cb = c % 24;
      const unsigned short* src = (cb < 16)
          ? kvb + (size_t)(kk0 + row) * 32768 + h * 256 + cb * 8
          : kr + (size_t)(kk0 + row) * 2112 + (cb - 16) * 8;
      kreg[i] = *reinterpret_cast<const bf16x8*>(src);
    }
#pragma unroll
    for (int i = 0; i < 2; ++i) {
      int c = t + 512 * i, d = c >> 3, kb = c & 7;
      vreg[i] = *reinterpret_cast<const bf16x8*>(vt + ((size_t)h * 128 + d) * 1024 + kk0 + kb * 8);
    }
  };

  float m_r[4], l_r[4];
  f32x4 oacc[8];
#pragma unroll
  for (int r = 0; r < 4; ++r) { m_r[r] = -1e30f; l_r[r] = 0.f; }
#pragma unroll
  for (int d = 0; d < 8; ++d) oacc[d] = (f32x4){0.f, 0.f, 0.f, 0.f};

  loadKV(0);

  for (int kt = 0; kt < 16; ++kt) {
    __syncthreads();
#pragma unroll
    for (int i = 0; i < 3; ++i) {
      int c = t + 512 * i, row = c / 24, cb = c % 24;
      *reinterpret_cast<bf16x8*>(&Klds[row][cb * 8]) = kreg[i];
    }
#pragma unroll
    for (int i = 0; i < 2; ++i) {
      int c = t + 512 * i, d = c >> 3, kb = c & 7;
      *reinterpret_cast<bf16x8*>(&Vlds[d][kb * 8]) = vreg[i];
    }
    __syncthreads();
    if (kt < 15) loadKV((kt + 1) * 64);

    f32x4 sacc[4];
#pragma unroll
    for (int nt = 0; nt < 4; ++nt) sacc[nt] = (f32x4){0.f, 0.f, 0.f, 0.f};
    __builtin_amdgcn_s_setprio(1);
#pragma unroll
    for (int nt = 0; nt < 4; ++nt)
#pragma unroll
      for (int kk = 0; kk < 6; ++kk) {
        bf16x8 b = *reinterpret_cast<const bf16x8*>(&Klds[nt * 16 + r15][kk * 32 + 8 * g]);
        sacc[nt] = __builtin_amdgcn_mfma_f32_16x16x32_bf16(qf[kk], b, sacc[nt], 0, 0, 0);
      }
    __builtin_amdgcn_s_setprio(0);

    float sc[4], rsum[4];
#pragma unroll
    for (int r = 0; r < 4; ++r) {
      float mx = fmaxf(fmaxf(sacc[0][r], sacc[1][r]), fmaxf(sacc[2][r], sacc[3][r]));
      mx = fmaxf(mx, __shfl_xor(mx, 1));
      mx = fmaxf(mx, __shfl_xor(mx, 2));
      mx = fmaxf(mx, __shfl_xor(mx, 4));
      mx = fmaxf(mx, __shfl_xor(mx, 8));
      float mn = fmaxf(m_r[r], mx);
      sc[r] = __expf(m_r[r] - mn);
      m_r[r] = mn;
      rsum[r] = 0.f;
    }
#pragma unroll
    for (int nt = 0; nt < 4; ++nt)
#pragma unroll
      for (int r = 0; r < 4; ++r) {
        float p = __expf(sacc[nt][r] - m_r[r]);
        rsum[r] += p;
        Plds[w][g * 4 + r][nt * 16 + r15] = f2bf(p);
      }
#pragma unroll
    for (int r = 0; r < 4; ++r) {
      float s = rsum[r];
      s += __shfl_xor(s, 1);
      s += __shfl_xor(s, 2);
      s += __shfl_xor(s, 4);
      s += __shfl_xor(s, 8);
      l_r[r] = l_r[r] * sc[r] + s;
    }
#pragma unroll
    for (int d = 0; d < 8; ++d)
#pragma unroll
      for (int r = 0; r < 4; ++r) oacc[d][r] *= sc[r];

    bf16x8 pa0 = *reinterpret_cast<const bf16x8*>(&Plds[w][r15][8 * g]);
    bf16x8 pa1 = *reinterpret_cast<const bf16x8*>(&Plds[w][r15][32 + 8 * g]);
    __builtin_amdgcn_s_setprio(1);
#pragma unroll
    for (int dt = 0; dt < 8; ++dt) {
      bf16x8 v0 = *reinterpret_cast<const bf16x8*>(&Vlds[dt * 16 + r15][8 * g]);
      bf16x8 v1 = *reinterpret_cast<const bf16x8*>(&Vlds[dt * 16 + r15][32 + 8 * g]);
      oacc[dt] = __builtin_amdgcn_mfma_f32_16x16x32_bf16(pa0, v0, oacc[dt], 0, 0, 0);
      oacc[dt] = __builtin_amdgcn_mfma_f32_16x16x32_bf16(pa1, v1, oacc[dt], 0, 0, 0);
    }
    __builtin_amdgcn_s_setprio(0);
  }

#pragma unroll
  for (int dt = 0; dt < 8; ++dt)
#pragma unroll
    for (int r = 0; r < 4; ++r) {
      int row = q0 + w * 16 + g * 4 + r;
      int col = h * DH + dt * 16 + r15;
      obuf[(size_t)row * 16384 + col] = f2bf(oacc[dt][r] / l_r[r]);
    }
}

// ------------------------------------------------------------------------------
extern "C" void kernel_launch(void* const* d_in, const int* in_sizes, int n_in,
                              void* d_out, int out_size, void* d_ws, size_t ws_size,
                              hipStream_t stream) {
  const float* h    = (const float*)d_in[0];
  const float* Wdq  = (const float*)d_in[1];
  const float* bdq  = (const float*)d_in[2];
  const float* Wdkv = (const float*)d_in[3];
  const float* bdkv = (const float*)d_in[4];
  const float* Wuq  = (const float*)d_in[5];
  const float* buq  = (const float*)d_in[6];
  const float* Wukv = (const float*)d_in[7];
  const float* bukv = (const float*)d_in[8];
  const float* Wrq  = (const float*)d_in[9];
  const float* brq  = (const float*)d_in[10];
  const float* Wrk  = (const float*)d_in[11];
  const float* brk  = (const float*)d_in[12];
  const float* Wo   = (const float*)d_in[13];
  const float* bo   = (const float*)d_in[14];
  float* out = (float*)d_out;

  char* ws = (char*)d_ws;
  size_t off = 0;
  auto alloc = [&](size_t bytes) {
    char* p = ws + off;
    off += (bytes + 255) & ~(size_t)255;
    return p;
  };
  unsigned short* hb    = (unsigned short*)alloc((size_t)1024 * 7168 * 2);
  unsigned short* W1cat = (unsigned short*)alloc((size_t)2176 * 7168 * 2);
  float*          b1cat = (float*)alloc(2176 * 4);
  unsigned short* ccat  = (unsigned short*)alloc((size_t)1024 * 2112 * 2);
  float*          b2cat = (float*)alloc(24576 * 4);
  unsigned short* qcat  = (unsigned short*)alloc((size_t)1024 * 24576 * 2);
  unsigned short* kvbb  = (unsigned short*)alloc((size_t)1024 * 32768 * 2);
  unsigned short* vt    = (unsigned short*)alloc((size_t)16384 * 1024 * 2);
  unsigned short* obuf  = (unsigned short*)alloc((size_t)1024 * 16384 * 2);
  float*          ctab  = (float*)alloc((size_t)S_LEN * 32 * 4);
  float*          stab  = (float*)alloc((size_t)S_LEN * 32 * 4);
  // G1 split-K partials alias not-yet-written qcat (34.6 MB < 50.3 MB)
  float* pbufG1 = (float*)qcat;
  // G4 partials (4 x 1024 x 7168 fp32 = 117.4 MB) at fresh offset (d_ws ~1.8 GB)
  float* pbufG4 = (float*)(ws + ((size_t)544 << 20));

  auto cvt = [&](const float* in, unsigned short* outp, size_t n) {
    int n8 = (int)(n / 8);
    int blocks = (n8 + 255) / 256;
    if (blocks > 2048) blocks = 2048;
    cvt_bf16_kernel<<<blocks, 256, 0, stream>>>(in, outp, n8);
  };

  // --- conversions for h and the small concatenated W1 ---
  cvt(h,    hb,    (size_t)1024 * 7168);
  cvt(Wdq,  W1cat, (size_t)1536 * 7168);
  cvt(Wdkv, W1cat + (size_t)1536 * 7168, (size_t)512 * 7168);
  cvt(Wrk,  W1cat + (size_t)2048 * 7168, (size_t)64 * 7168);
  hipMemsetAsync(W1cat + (size_t)2112 * 7168, 0, (size_t)64 * 7168 * 2, stream);
  hipMemcpyAsync(b1cat,        bdq,  1536 * 4, hipMemcpyDeviceToDevice, stream);
  hipMemcpyAsync(b1cat + 1536, bdkv, 512 * 4,  hipMemcpyDeviceToDevice, stream);
  hipMemcpyAsync(b1cat + 2048, brk,  64 * 4,   hipMemcpyDeviceToDevice, stream);
  hipMemsetAsync(b1cat + 2112, 0, 64 * 4, stream);
  hipMemcpyAsync(b2cat,         buq, 16384 * 4, hipMemcpyDeviceToDevice, stream);
  hipMemcpyAsync(b2cat + 16384, brq, 8192 * 4,  hipMemcpyDeviceToDevice, stream);
  rope_table_kernel<<<(S_LEN * 32 + 255) / 256, 256, 0, stream>>>(ctab, stab);

  const float scale = 0.07216878364870323f;   // 1/sqrt(192)
  const int BIGN = 1 << 30;
  dim3 blk(256);

  // G1 (split-K=4, bf16 W): partials = h @ W1cat^T
  gemm_k<2, 0><<<dim3(24, 8, 4), blk, 0, stream>>>(
      hb, 7168, W1cat, nullptr, nullptr, BIGN, 7168, nullptr,
      pbufG1, 2112, (size_t)1024 * 2112, 2112, 1792, 1.0f);
  reduce_bf16_kernel<<<2112, blk, 0, stream>>>(pbufG1, b1cat, ccat, 2112, 528, 4,
                                               (size_t)1024 * 2112, 1024 * 2112 / 4);
  rope_bf16_kernel<<<(1024 * 32 + 255) / 256, blk, 0, stream>>>(ccat + 2048, 1, 2112, 1024 * 32, ctab, stab);

  // G2 (fp32 W direct, fused q_r RoPE in epilogue):
  // [q_c | rope(q_r)] = (c_q @ [Wuq;Wrq]^T + b2cat) {rope on cols>=16384} * scale
  gemm_k<1, 1, 1><<<dim3(192, 8, 1), blk, 0, stream>>>(
      ccat, 2112, nullptr, Wuq, Wrq, 16384, 1536, b2cat,
      qcat, 24576, 0, 24576, 1536, scale, ctab, stab);

  // G3 (fp32 W direct): kv = c_kv @ Wukv^T + bukv
  gemm_k<1, 1><<<dim3(256, 8, 1), blk, 0, stream>>>(
      ccat + 1536, 2112, nullptr, Wukv, Wukv, BIGN, 512, bukv,
      kvbb, 32768, 0, 32768, 512, 1.0f);
  vtrans_kernel<<<dim3(16, 256), blk, 0, stream>>>(kvbb, vt);
  mla_attn_kernel<<<dim3(1024), dim3(512), 0, stream>>>(qcat, kvbb, ccat + 2048, vt, obuf);

  // G4: fp32-W direct (no cvt pass), single launch, L2-sharer-adjacent grid,
  // split-K=4, then reduce with bias.
  gemm_g4<<<dim3(1792), blk, 0, stream>>>(obuf, Wo, pbufG4);
  reduce_f32_kernel<<<7168, blk, 0, stream>>>(pbufG4, bo, out,
                                              7168, 1792, 4, (size_t)1024 * 7168, 1024 * 7168 / 4);
}

// Round 15
// 1122.470 us; speedup vs baseline: 1.0953x; 1.0017x over previous
//
#include <hip/hip_runtime.h>
#include <hip/hip_bf16.h>

#define S_LEN 1024
#define HID 7168
#define NH 128
#define DQ 1536
#define DKV 512
#define DH 128
#define DR 64

typedef __attribute__((ext_vector_type(8))) short bf16x8;
typedef __attribute__((ext_vector_type(4))) float f32x4;
typedef __attribute__((ext_vector_type(4))) float fl4;
typedef __attribute__((ext_vector_type(4))) unsigned short us4;
typedef __attribute__((ext_vector_type(8))) unsigned short us8;
typedef __attribute__((ext_vector_type(4))) unsigned int u32x4;

static __device__ __forceinline__ unsigned short f2bf(float f) {
  union { float f; unsigned int u; } v; v.f = f;
  unsigned int u = v.u;
  return (unsigned short)((u + 0x7fffu + ((u >> 16) & 1u)) >> 16);
}
static __device__ __forceinline__ float bf2f(unsigned short u) {
  union { unsigned int u; float f; } v; v.u = ((unsigned int)u) << 16;
  return v.f;
}
static __device__ __forceinline__ unsigned int cvtpk2(float lo, float hi) {
  unsigned int r;
  asm("v_cvt_pk_bf16_f32 %0, %1, %2" : "=v"(r) : "v"(lo), "v"(hi));
  return r;
}

// ---------------- fp32 -> bf16 conversion -------------------------------------
__global__ __launch_bounds__(256) void cvt_bf16_kernel(
    const float* __restrict__ in, unsigned short* __restrict__ out, int n8) {
  int i = blockIdx.x * 256 + threadIdx.x;
  int stride = gridDim.x * 256;
  for (; i < n8; i += stride) {
    fl4 a = ((const fl4*)in)[2 * i];
    fl4 b = ((const fl4*)in)[2 * i + 1];
    us8 u = { f2bf(a[0]), f2bf(a[1]), f2bf(a[2]), f2bf(a[3]),
              f2bf(b[0]), f2bf(b[1]), f2bf(b[2]), f2bf(b[3]) };
    ((us8*)out)[i] = u;
  }
}

// ---------------- bf16 GEMM (m97 structure) -----------------------------------
// OUTMODE 1: C = bf16((A@W^T + bias) * alpha), grid.z==1
// OUTMODE 2: fp32 partials per K-slice at Cv + z*zstride (split-K), no bias
// WFP32 1: W read as fp32 into REGISTERS one K-step ahead; counted-vmcnt
//          pipeline (raw s_barrier, never drains the W prefetch): per step
//          issue 4 A-glds -> vmcnt(4) [drains 8 older W(k) reg-loads] ->
//          cvt+ds_write -> issue 8 W(k+64) -> vmcnt(8)+lgkm0 [drains A] ->
//          s_barrier -> MFMA. Last iter: vmcnt(0).
// ROPEQ 1: fused q_r RoPE in epilogue (cols >= 16384).
template <int OUTMODE, int WFP32, int ROPEQ = 0>
__global__ __launch_bounds__(256) void gemm_k(
    const unsigned short* __restrict__ A, int lda,
    const unsigned short* __restrict__ Wb16,
    const float* __restrict__ Wfa, const float* __restrict__ Wfb, int nsplit,
    int ldw,
    const float* __restrict__ bias,
    void* __restrict__ Cv, int ldc, size_t zstride,
    int Ncl, int ksl, float alpha,
    const float* __restrict__ ctab = nullptr,
    const float* __restrict__ stab = nullptr)
{
  const int n0 = blockIdx.x * 128;
  if (n0 >= Ncl) return;                 // padded-grid early exit (block-uniform)

  __shared__ unsigned short As[128 * 64];
  __shared__ unsigned short Ws[128 * 64];
  const int t = threadIdx.x;
  const int l = t & 63, w = t >> 6;
  const int r15 = l & 15, g = l >> 4;
  const int wm = (w >> 1) * 64, wn = (w & 1) * 64;
  const int m0 = blockIdx.y * 128;
  const int kbase = blockIdx.z * ksl;
  const int srow = l >> 3;
  const int scol = (l & 7) * 8;

  f32x4 acc[4][4];
#pragma unroll
  for (int i = 0; i < 4; ++i)
#pragma unroll
    for (int j = 0; j < 4; ++j) acc[i][j] = (f32x4){0.f, 0.f, 0.f, 0.f};

  const unsigned short* Ab = A + (size_t)m0 * lda;
  const unsigned short* Wb = nullptr;
  const float* Wf = nullptr;
  if constexpr (WFP32) {
    Wf = (n0 < nsplit) ? Wfa + (size_t)n0 * ldw : Wfb + (size_t)(n0 - nsplit) * ldw;
  } else {
    Wb = Wb16 + (size_t)n0 * ldw;
  }

  fl4 wx[4], wy[4];
  auto issueW = [&](int k0) {
#pragma unroll
    for (int i = 0; i < 4; ++i) {
      int c = t + 256 * i;
      const float* src = Wf + (size_t)(c >> 3) * ldw + k0 + (c & 7) * 8;
      wx[i] = *(const fl4*)src;
      wy[i] = *(const fl4*)(src + 4);
    }
  };

  if constexpr (WFP32) issueW(kbase);
  const int kend = kbase + ksl;

  for (int k0 = kbase; k0 < kend; k0 += 64) {
    if constexpr (WFP32) {
      __builtin_amdgcn_s_barrier();              // readers of As/Ws done
      __builtin_amdgcn_sched_barrier(0);
    } else {
      __syncthreads();
    }
#pragma unroll
    for (int i = 0; i < 4; ++i) {
      int chunk = w * 4 + i;
      int row = chunk * 8 + srow;
      __builtin_amdgcn_global_load_lds(
          (const __attribute__((address_space(1))) void*)(Ab + (size_t)row * lda + k0 + scol),
          (__attribute__((address_space(3))) void*)(As + chunk * 512), 16, 0, 0);
      if constexpr (!WFP32) {
        __builtin_amdgcn_global_load_lds(
            (const __attribute__((address_space(1))) void*)(Wb + (size_t)row * ldw + k0 + scol),
            (__attribute__((address_space(3))) void*)(Ws + chunk * 512), 16, 0, 0);
      }
    }
    if constexpr (WFP32) {
      __builtin_amdgcn_sched_barrier(0);
      asm volatile("s_waitcnt vmcnt(4)" ::: "memory");   // W(k) regs arrived; A in flight
      __builtin_amdgcn_sched_barrier(0);
#pragma unroll
      for (int i = 0; i < 4; ++i) {
        int c = t + 256 * i;
        u32x4 p = { cvtpk2(wx[i][0], wx[i][1]), cvtpk2(wx[i][2], wx[i][3]),
                    cvtpk2(wy[i][0], wy[i][1]), cvtpk2(wy[i][2], wy[i][3]) };
        ((u32x4*)Ws)[c] = p;
      }
      if (k0 + 64 < kend) {
        issueW(k0 + 64);                  // stays in flight across the barrier (T4)
        __builtin_amdgcn_sched_barrier(0);
        asm volatile("s_waitcnt vmcnt(8) lgkmcnt(0)" ::: "memory");  // drains A only
      } else {
        asm volatile("s_waitcnt vmcnt(0) lgkmcnt(0)" ::: "memory");
      }
      __builtin_amdgcn_sched_barrier(0);
      __builtin_amdgcn_s_barrier();
    } else {
      __syncthreads();
    }
#pragma unroll
    for (int kk = 0; kk < 2; ++kk) {
      bf16x8 a[4], b[4];
#pragma unroll
      for (int mt = 0; mt < 4; ++mt)
        a[mt] = *reinterpret_cast<const bf16x8*>(&As[(wm + mt * 16 + r15) * 64 + kk * 32 + 8 * g]);
#pragma unroll
      for (int nt = 0; nt < 4; ++nt)
        b[nt] = *reinterpret_cast<const bf16x8*>(&Ws[(wn + nt * 16 + r15) * 64 + kk * 32 + 8 * g]);
#pragma unroll
      for (int mt = 0; mt < 4; ++mt)
#pragma unroll
        for (int nt = 0; nt < 4; ++nt)
          acc[mt][nt] = __builtin_amdgcn_mfma_f32_16x16x32_bf16(a[mt], b[nt], acc[mt][nt], 0, 0, 0);
    }
  }

  if constexpr (OUTMODE == 1) {
    float bv[4];
#pragma unroll
    for (int nt = 0; nt < 4; ++nt) {
      int col = n0 + wn + nt * 16 + r15;
      bv[nt] = (col < Ncl) ? bias[col] : 0.f;
    }
    bool isrope = false;
    if constexpr (ROPEQ) isrope = (n0 + wn) >= 16384;   // wave-uniform
    if (ROPEQ && isrope) {
#pragma unroll
      for (int mt = 0; mt < 4; ++mt)
#pragma unroll
        for (int r = 0; r < 4; ++r) {
          int row = m0 + wm + mt * 16 + g * 4 + r;
#pragma unroll
          for (int ntp = 0; ntp < 2; ++ntp) {
            int j = ntp * 16 + r15;
            float c = ctab[row * 32 + j];
            float s = stab[row * 32 + j];
            float x1 = acc[mt][ntp][r] + bv[ntp];
            float x2 = acc[mt][ntp + 2][r] + bv[ntp + 2];
            int col1 = n0 + wn + ntp * 16 + r15;
            ((unsigned short*)Cv)[(size_t)row * ldc + col1] =
                f2bf((x1 * c - x2 * s) * alpha);
            ((unsigned short*)Cv)[(size_t)row * ldc + col1 + 32] =
                f2bf((x2 * c + x1 * s) * alpha);
          }
        }
    } else {
#pragma unroll
      for (int mt = 0; mt < 4; ++mt)
#pragma unroll
        for (int nt = 0; nt < 4; ++nt) {
          int col = n0 + wn + nt * 16 + r15;
          if (col < Ncl) {
#pragma unroll
            for (int r = 0; r < 4; ++r) {
              int row = m0 + wm + mt * 16 + g * 4 + r;
              ((unsigned short*)Cv)[(size_t)row * ldc + col] =
                  f2bf((acc[mt][nt][r] + bv[nt]) * alpha);
            }
          }
        }
    }
  } else {
    float* Cp = (float*)Cv + blockIdx.z * zstride;
#pragma unroll
    for (int mt = 0; mt < 4; ++mt)
#pragma unroll
      for (int nt = 0; nt < 4; ++nt) {
        int col = n0 + wn + nt * 16 + r15;
        if (col < Ncl) {
#pragma unroll
          for (int r = 0; r < 4; ++r) {
            int row = m0 + wm + mt * 16 + g * 4 + r;
            Cp[(size_t)row * ldc + col] = acc[mt][nt][r];
          }
        }
      }
  }
}

// ---------------- G4 dedicated: fp32-W, counted-vmcnt pipeline ----------------
// Grid 896 = 2z x 7grp x 8m x 8nlo; id = z*448 + grp*64 + m*8 + nlo.
// m-sharers of a W-tile: id-stride 8 -> same XCD (id%8==nlo), temporally
// adjacent -> W-tile L2-hot, Wo fetched ~once (R14: FETCH 780MB ~= ideal).
// Counted-vmcnt keeps the W reg-prefetch in flight across barriers.
__global__ __launch_bounds__(256) void gemm_g4(
    const unsigned short* __restrict__ A,      // obuf [1024][16384] bf16
    const float* __restrict__ W,               // Wo  [7168][16384] fp32
    float* __restrict__ pbuf)                  // [2][1024][7168] fp32 partials
{
  __shared__ unsigned short As[128 * 64];
  __shared__ unsigned short Ws[128 * 64];
  const int t = threadIdx.x;
  const int l = t & 63, w = t >> 6;
  const int r15 = l & 15, g = l >> 4;
  const int wm = (w >> 1) * 64, wn = (w & 1) * 64;
  const int bid = blockIdx.x;
  const int z = bid / 448;
  const int r448 = bid % 448;
  const int grp = r448 >> 6, wi = r448 & 63;
  const int m0 = (wi >> 3) * 128;
  const int n0 = (grp * 8 + (wi & 7)) * 128;
  const int kbase = z * 8192;
  const int srow = l >> 3, scol = (l & 7) * 8;

  f32x4 acc[4][4];
#pragma unroll
  for (int i = 0; i < 4; ++i)
#pragma unroll
    for (int j = 0; j < 4; ++j) acc[i][j] = (f32x4){0.f, 0.f, 0.f, 0.f};

  const unsigned short* Ab = A + (size_t)m0 * 16384;
  const float* Wf = W + (size_t)n0 * 16384;

  fl4 wx[4], wy[4];
  auto issueW = [&](int k0) {
#pragma unroll
    for (int i = 0; i < 4; ++i) {
      int c = t + 256 * i;
      const float* src = Wf + (size_t)(c >> 3) * 16384 + k0 + (c & 7) * 8;
      wx[i] = *(const fl4*)src;
      wy[i] = *(const fl4*)(src + 4);
    }
  };
  issueW(kbase);
  const int kend = kbase + 8192;

  for (int k0 = kbase; k0 < kend; k0 += 64) {
    __builtin_amdgcn_s_barrier();
    __builtin_amdgcn_sched_barrier(0);
#pragma unroll
    for (int i = 0; i < 4; ++i) {
      int chunk = w * 4 + i;
      int row = chunk * 8 + srow;
      __builtin_amdgcn_global_load_lds(
          (const __attribute__((address_space(1))) void*)(Ab + (size_t)row * 16384 + k0 + scol),
          (__attribute__((address_space(3))) void*)(As + chunk * 512), 16, 0, 0);
    }
    __builtin_amdgcn_sched_barrier(0);
    asm volatile("s_waitcnt vmcnt(4)" ::: "memory");   // W(k) regs ready; A in flight
    __builtin_amdgcn_sched_barrier(0);
#pragma unroll
    for (int i = 0; i < 4; ++i) {
      int c = t + 256 * i;
      u32x4 p = { cvtpk2(wx[i][0], wx[i][1]), cvtpk2(wx[i][2], wx[i][3]),
                  cvtpk2(wy[i][0], wy[i][1]), cvtpk2(wy[i][2], wy[i][3]) };
      ((u32x4*)Ws)[c] = p;
    }
    if (k0 + 64 < kend) {
      issueW(k0 + 64);                    // in flight across barrier + MFMA (T4)
      __builtin_amdgcn_sched_barrier(0);
      asm volatile("s_waitcnt vmcnt(8) lgkmcnt(0)" ::: "memory");
    } else {
      asm volatile("s_waitcnt vmcnt(0) lgkmcnt(0)" ::: "memory");
    }
    __builtin_amdgcn_sched_barrier(0);
    __builtin_amdgcn_s_barrier();
#pragma unroll
    for (int kk = 0; kk < 2; ++kk) {
      bf16x8 a[4], b[4];
#pragma unroll
      for (int mt = 0; mt < 4; ++mt)
        a[mt] = *reinterpret_cast<const bf16x8*>(&As[(wm + mt * 16 + r15) * 64 + kk * 32 + 8 * g]);
#pragma unroll
      for (int nt = 0; nt < 4; ++nt)
        b[nt] = *reinterpret_cast<const bf16x8*>(&Ws[(wn + nt * 16 + r15) * 64 + kk * 32 + 8 * g]);
#pragma unroll
      for (int mt = 0; mt < 4; ++mt)
#pragma unroll
        for (int nt = 0; nt < 4; ++nt)
          acc[mt][nt] = __builtin_amdgcn_mfma_f32_16x16x32_bf16(a[mt], b[nt], acc[mt][nt], 0, 0, 0);
    }
  }

  float* Cp = pbuf + (size_t)z * 1024 * 7168;
#pragma unroll
  for (int mt = 0; mt < 4; ++mt)
#pragma unroll
    for (int nt = 0; nt < 4; ++nt) {
      int col = n0 + wn + nt * 16 + r15;
#pragma unroll
      for (int r = 0; r < 4; ++r) {
        int row = m0 + wm + mt * 16 + g * 4 + r;
        Cp[(size_t)row * 7168 + col] = acc[mt][nt][r];
      }
    }
}

// ---------------- split-K reductions ------------------------------------------
__global__ __launch_bounds__(256) void reduce_f32_kernel(
    const float* __restrict__ pbuf, const float* __restrict__ bias,
    float* __restrict__ out, int ldo, int rowlen4, int nz, size_t zstride, int total4)
{
  int idx = blockIdx.x * 256 + threadIdx.x;
  if (idx >= total4) return;
  int r = idx / rowlen4, c4 = idx % rowlen4;
  fl4 acc = *(const fl4*)(bias + c4 * 4);
  for (int z = 0; z < nz; ++z)
    acc += *(const fl4*)(pbuf + z * zstride + (size_t)idx * 4);
  *(fl4*)(out + (size_t)r * ldo + c4 * 4) = acc;
}

__global__ __launch_bounds__(256) void reduce_bf16_kernel(
    const float* __restrict__ pbuf, const float* __restrict__ bias,
    unsigned short* __restrict__ out, int ldo, int rowlen4, int nz, size_t zstride, int total4)
{
  int idx = blockIdx.x * 256 + threadIdx.x;
  if (idx >= total4) return;
  int r = idx / rowlen4, c4 = idx % rowlen4;
  fl4 acc = *(const fl4*)(bias + c4 * 4);
  for (int z = 0; z < nz; ++z)
    acc += *(const fl4*)(pbuf + z * zstride + (size_t)idx * 4);
  us4 u = { f2bf(acc[0]), f2bf(acc[1]), f2bf(acc[2]), f2bf(acc[3]) };
  *(us4*)(out + (size_t)r * ldo + c4 * 4) = u;
}

// ---------------- rope tables + table-based rope (k_r only) -------------------
__global__ __launch_bounds__(256) void rope_table_kernel(float* __restrict__ ctab,
                                                         float* __restrict__ stab) {
  int idx = blockIdx.x * 256 + threadIdx.x;
  if (idx >= S_LEN * 32) return;
  int j = idx & 31, s = idx >> 5;
  float invf = expf(-0.28782313662425574f * (float)j);
  float ang = (float)s * invf;
  ctab[idx] = cosf(ang);
  stab[idx] = sinf(ang);
}

__global__ void rope_bf16_kernel(unsigned short* __restrict__ x, int nh, int lda, int total,
                                 const float* __restrict__ ctab,
                                 const float* __restrict__ stab) {
  int idx = blockIdx.x * 256 + threadIdx.x;
  if (idx >= total) return;
  int j = idx & 31;
  int rest = idx >> 5;
  int hh = rest % nh;
  int s = rest / nh;
  float c = ctab[s * 32 + j], sn = stab[s * 32 + j];
  size_t base = (size_t)s * lda + hh * 64;
  float x1 = bf2f(x[base + j]), x2 = bf2f(x[base + j + 32]);
  x[base + j]      = f2bf(x1 * c - x2 * sn);
  x[base + j + 32] = f2bf(x2 * c + x1 * sn);
}

// ---------------- V transpose -------------------------------------------------
__global__ __launch_bounds__(256) void vtrans_kernel(
    const unsigned short* __restrict__ kvb, unsigned short* __restrict__ vt) {
  __shared__ unsigned short tl[64][72];
  const int s0 = blockIdx.x * 64;
  const int c0 = blockIdx.y * 64;
  const int t = threadIdx.x;
  const int rr = t >> 3, cc = (t & 7) * 8;
  const int hbase = (c0 >> 7) * 256 + 128 + (c0 & 127);
#pragma unroll
  for (int i = 0; i < 2; ++i) {
    int r = rr + i * 32;
    *reinterpret_cast<bf16x8*>(&tl[r][cc]) =
        *reinterpret_cast<const bf16x8*>(kvb + (size_t)(s0 + r) * 32768 + hbase + cc);
  }
  __syncthreads();
#pragma unroll
  for (int i = 0; i < 2; ++i) {
    int vc = rr + i * 32;
    unsigned short tmp[8];
#pragma unroll
    for (int j = 0; j < 8; ++j) tmp[j] = tl[cc + j][vc];
    *reinterpret_cast<bf16x8*>(&vt[(size_t)(c0 + vc) * 1024 + s0 + cc]) =
        *reinterpret_cast<bf16x8*>(tmp);
  }
}

// ---------------- flash attention: QBLK=128, 8 waves/block --------------------
__global__ __launch_bounds__(512) void mla_attn_kernel(
    const unsigned short* __restrict__ qcat,
    const unsigned short* __restrict__ kvb,
    const unsigned short* __restrict__ kr,
    const unsigned short* __restrict__ vt,
    unsigned short* __restrict__ obuf)
{
  __shared__ unsigned short Klds[64][200];
  __shared__ unsigned short Vlds[128][72];
  __shared__ unsigned short Plds[8][16][72];

  const int t = threadIdx.x;
  const int l = t & 63, w = t >> 6;
  const int r15 = l & 15, g = l >> 4;
  const int bid = blockIdx.x;
  const int orig = (bid & 7) * 128 + (bid >> 3);
  const int h = orig >> 3;
  const int q0 = (orig & 7) * 128;

  bf16x8 qf[6];
  const unsigned short* qrow = qcat + (size_t)(q0 + w * 16 + r15) * 24576;
#pragma unroll
  for (int kk = 0; kk < 4; ++kk)
    qf[kk] = *reinterpret_cast<const bf16x8*>(qrow + h * 128 + kk * 32 + 8 * g);
#pragma unroll
  for (int kk = 4; kk < 6; ++kk)
    qf[kk] = *reinterpret_cast<const bf16x8*>(qrow + 16384 + h * 64 + (kk - 4) * 32 + 8 * g);

  bf16x8 kreg[3], vreg[2];
  auto loadKV = [&](int kk0) {
#pragma unroll
    for (int i = 0; i < 3; ++i) {
      int c = t + 512 * i, row = c / 24, cb = c % 24;
      const unsigned short* src = (cb < 16)
          ? kvb + (size_t)(kk0 + row) * 32768 + h * 256 + cb * 8
          : kr + (size_t)(kk0 + row) * 2112 + (cb - 16) * 8;
      kreg[i] = *reinterpret_cast<const bf16x8*>(src);
    }
#pragma unroll
    for (int i = 0; i < 2; ++i) {
      int c = t + 512 * i, d = c >> 3, kb = c & 7;
      vreg[i] = *reinterpret_cast<const bf16x8*>(vt + ((size_t)h * 128 + d) * 1024 + kk0 + kb * 8);
    }
  };

  float m_r[4], l_r[4];
  f32x4 oacc[8];
#pragma unroll
  for (int r = 0; r < 4; ++r) { m_r[r] = -1e30f; l_r[r] = 0.f; }
#pragma unroll
  for (int d = 0; d < 8; ++d) oacc[d] = (f32x4){0.f, 0.f, 0.f, 0.f};

  loadKV(0);

  for (int kt = 0; kt < 16; ++kt) {
    __syncthreads();
#pragma unroll
    for (int i = 0; i < 3; ++i) {
      int c = t + 512 * i, row = c / 24, cb = c % 24;
      *reinterpret_cast<bf16x8*>(&Klds[row][cb * 8]) = kreg[i];
    }
#pragma unroll
    for (int i = 0; i < 2; ++i) {
      int c = t + 512 * i, d = c >> 3, kb = c & 7;
      *reinterpret_cast<bf16x8*>(&Vlds[d][kb * 8]) = vreg[i];
    }
    __syncthreads();
    if (kt < 15) loadKV((kt + 1) * 64);

    f32x4 sacc[4];
#pragma unroll
    for (int nt = 0; nt < 4; ++nt) sacc[nt] = (f32x4){0.f, 0.f, 0.f, 0.f};
    __builtin_amdgcn_s_setprio(1);
#pragma unroll
    for (int nt = 0; nt < 4; ++nt)
#pragma unroll
      for (int kk = 0; kk < 6; ++kk) {
        bf16x8 b = *reinterpret_cast<const bf16x8*>(&Klds[nt * 16 + r15][kk * 32 + 8 * g]);
        sacc[nt] = __builtin_amdgcn_mfma_f32_16x16x32_bf16(qf[kk], b, sacc[nt], 0, 0, 0);
      }
    __builtin_amdgcn_s_setprio(0);

    float sc[4], rsum[4];
#pragma unroll
    for (int r = 0; r < 4; ++r) {
      float mx = fmaxf(fmaxf(sacc[0][r], sacc[1][r]), fmaxf(sacc[2][r], sacc[3][r]));
      mx = fmaxf(mx, __shfl_xor(mx, 1));
      mx = fmaxf(mx, __shfl_xor(mx, 2));
      mx = fmaxf(mx, __shfl_xor(mx, 4));
      mx = fmaxf(mx, __shfl_xor(mx, 8));
      float mn = fmaxf(m_r[r], mx);
      sc[r] = __expf(m_r[r] - mn);
      m_r[r] = mn;
      rsum[r] = 0.f;
    }
#pragma unroll
    for (int nt = 0; nt < 4; ++nt)
#pragma unroll
      for (int r = 0; r < 4; ++r) {
        float p = __expf(sacc[nt][r] - m_r[r]);
        rsum[r] += p;
        Plds[w][g * 4 + r][nt * 16 + r15] = f2bf(p);
      }
#pragma unroll
    for (int r = 0; r < 4; ++r) {
      float s = rsum[r];
      s += __shfl_xor(s, 1);
      s += __shfl_xor(s, 2);
      s += __shfl_xor(s, 4);
      s += __shfl_xor(s, 8);
      l_r[r] = l_r[r] * sc[r] + s;
    }
#pragma unroll
    for (int d = 0; d < 8; ++d)
#pragma unroll
      for (int r = 0; r < 4; ++r) oacc[d][r] *= sc[r];

    bf16x8 pa0 = *reinterpret_cast<const bf16x8*>(&Plds[w][r15][8 * g]);
    bf16x8 pa1 = *reinterpret_cast<const bf16x8*>(&Plds[w][r15][32 + 8 * g]);
    __builtin_amdgcn_s_setprio(1);
#pragma unroll
    for (int dt = 0; dt < 8; ++dt) {
      bf16x8 v0 = *reinterpret_cast<const bf16x8*>(&Vlds[dt * 16 + r15][8 * g]);
      bf16x8 v1 = *reinterpret_cast<const bf16x8*>(&Vlds[dt * 16 + r15][32 + 8 * g]);
      oacc[dt] = __builtin_amdgcn_mfma_f32_16x16x32_bf16(pa0, v0, oacc[dt], 0, 0, 0);
      oacc[dt] = __builtin_amdgcn_mfma_f32_16x16x32_bf16(pa1, v1, oacc[dt], 0, 0, 0);
    }
    __builtin_amdgcn_s_setprio(0);
  }

#pragma unroll
  for (int dt = 0; dt < 8; ++dt)
#pragma unroll
    for (int r = 0; r < 4; ++r) {
      int row = q0 + w * 16 + g * 4 + r;
      int col = h * DH + dt * 16 + r15;
      obuf[(size_t)row * 16384 + col] = f2bf(oacc[dt][r] / l_r[r]);
    }
}

// ------------------------------------------------------------------------------
extern "C" void kernel_launch(void* const* d_in, const int* in_sizes, int n_in,
                              void* d_out, int out_size, void* d_ws, size_t ws_size,
                              hipStream_t stream) {
  const float* h    = (const float*)d_in[0];
  const float* Wdq  = (const float*)d_in[1];
  const float* bdq  = (const float*)d_in[2];
  const float* Wdkv = (const float*)d_in[3];
  const float* bdkv = (const float*)d_in[4];
  const float* Wuq  = (const float*)d_in[5];
  const float* buq  = (const float*)d_in[6];
  const float* Wukv = (const float*)d_in[7];
  const float* bukv = (const float*)d_in[8];
  const float* Wrq  = (const float*)d_in[9];
  const float* brq  = (const float*)d_in[10];
  const float* Wrk  = (const float*)d_in[11];
  const float* brk  = (const float*)d_in[12];
  const float* Wo   = (const float*)d_in[13];
  const float* bo   = (const float*)d_in[14];
  float* out = (float*)d_out;

  char* ws = (char*)d_ws;
  size_t off = 0;
  auto alloc = [&](size_t bytes) {
    char* p = ws + off;
    off += (bytes + 255) & ~(size_t)255;
    return p;
  };
  unsigned short* hb    = (unsigned short*)alloc((size_t)1024 * 7168 * 2);
  unsigned short* W1cat = (unsigned short*)alloc((size_t)2176 * 7168 * 2);
  float*          b1cat = (float*)alloc(2176 * 4);
  float*          b2cat = (float*)alloc(24576 * 4);
  unsigned short* ccat  = (unsigned short*)alloc((size_t)1024 * 2112 * 2);
  unsigned short* qcat  = (unsigned short*)alloc((size_t)1024 * 24576 * 2);
  unsigned short* kvbb  = (unsigned short*)alloc((size_t)1024 * 32768 * 2);
  unsigned short* vt    = (unsigned short*)alloc((size_t)16384 * 1024 * 2);
  unsigned short* obuf  = (unsigned short*)alloc((size_t)1024 * 16384 * 2);
  float*          ctab  = (float*)alloc((size_t)S_LEN * 32 * 4);
  float*          stab  = (float*)alloc((size_t)S_LEN * 32 * 4);
  // G1 split-K partials alias not-yet-written qcat (34.6 MB < 50.3 MB)
  float* pbufG1 = (float*)qcat;
  // G4 partials (2 x 1024 x 7168 fp32 = 58.7 MB) at fresh offset (d_ws ~1.8 GB)
  float* pbufG4 = (float*)(ws + ((size_t)544 << 20));

  auto cvt = [&](const float* in, unsigned short* outp, size_t n) {
    int n8 = (int)(n / 8);
    int blocks = (n8 + 255) / 256;
    if (blocks > 2048) blocks = 2048;
    cvt_bf16_kernel<<<blocks, 256, 0, stream>>>(in, outp, n8);
  };

  // --- conversions for h and the small concatenated W1 ---
  cvt(h,    hb,    (size_t)1024 * 7168);
  cvt(Wdq,  W1cat, (size_t)1536 * 7168);
  cvt(Wdkv, W1cat + (size_t)1536 * 7168, (size_t)512 * 7168);
  cvt(Wrk,  W1cat + (size_t)2048 * 7168, (size_t)64 * 7168);
  hipMemsetAsync(W1cat + (size_t)2112 * 7168, 0, (size_t)64 * 7168 * 2, stream);
  hipMemcpyAsync(b1cat,        bdq,  1536 * 4, hipMemcpyDeviceToDevice, stream);
  hipMemcpyAsync(b1cat + 1536, bdkv, 512 * 4,  hipMemcpyDeviceToDevice, stream);
  hipMemcpyAsync(b1cat + 2048, brk,  64 * 4,   hipMemcpyDeviceToDevice, stream);
  hipMemsetAsync(b1cat + 2112, 0, 64 * 4, stream);
  hipMemcpyAsync(b2cat,         buq, 16384 * 4, hipMemcpyDeviceToDevice, stream);
  hipMemcpyAsync(b2cat + 16384, brq, 8192 * 4,  hipMemcpyDeviceToDevice, stream);
  rope_table_kernel<<<(S_LEN * 32 + 255) / 256, 256, 0, stream>>>(ctab, stab);

  const float scale = 0.07216878364870323f;   // 1/sqrt(192)
  const int BIGN = 1 << 30;
  dim3 blk(256);

  // G1 (split-K=4, bf16 W): partials = h @ W1cat^T
  gemm_k<2, 0><<<dim3(24, 8, 4), blk, 0, stream>>>(
      hb, 7168, W1cat, nullptr, nullptr, BIGN, 7168, nullptr,
      pbufG1, 2112, (size_t)1024 * 2112, 2112, 1792, 1.0f);
  reduce_bf16_kernel<<<2112, blk, 0, stream>>>(pbufG1, b1cat, ccat, 2112, 528, 4,
                                               (size_t)1024 * 2112, 1024 * 2112 / 4);
  rope_bf16_kernel<<<(1024 * 32 + 255) / 256, blk, 0, stream>>>(ccat + 2048, 1, 2112, 1024 * 32, ctab, stab);

  // G2 (fp32 W direct, counted-vmcnt pipeline, fused q_r RoPE):
  gemm_k<1, 1, 1><<<dim3(192, 8, 1), blk, 0, stream>>>(
      ccat, 2112, nullptr, Wuq, Wrq, 16384, 1536, b2cat,
      qcat, 24576, 0, 24576, 1536, scale, ctab, stab);

  // G3 (fp32 W direct, counted-vmcnt pipeline): kv = c_kv @ Wukv^T + bukv
  gemm_k<1, 1><<<dim3(256, 8, 1), blk, 0, stream>>>(
      ccat + 1536, 2112, nullptr, Wukv, Wukv, BIGN, 512, bukv,
      kvbb, 32768, 0, 32768, 512, 1.0f);
  vtrans_kernel<<<dim3(16, 256), blk, 0, stream>>>(kvbb, vt);
  mla_attn_kernel<<<dim3(1024), dim3(512), 0, stream>>>(qcat, kvbb, ccat + 2048, vt, obuf);

  // G4: fp32-W, counted-vmcnt pipeline, L2-sharer-adjacent grid, split-K=2.
  gemm_g4<<<dim3(896), blk, 0, stream>>>(obuf, Wo, pbufG4);
  reduce_f32_kernel<<<7168, blk, 0, stream>>>(pbufG4, bo, out,
                                              7168, 1792, 2, (size_t)1024 * 7168, 1024 * 7168 / 4);
}

// Round 16
// 1053.640 us; speedup vs baseline: 1.1668x; 1.0653x over previous
//
#include <hip/hip_runtime.h>
#include <hip/hip_bf16.h>

#define S_LEN 1024
#define HID 7168
#define NH 128
#define DQ 1536
#define DKV 512
#define DH 128
#define DR 64

typedef __attribute__((ext_vector_type(8))) short bf16x8;
typedef __attribute__((ext_vector_type(4))) float f32x4;
typedef __attribute__((ext_vector_type(4))) float fl4;
typedef __attribute__((ext_vector_type(4))) unsigned short us4;
typedef __attribute__((ext_vector_type(8))) unsigned short us8;
typedef __attribute__((ext_vector_type(4))) unsigned int u32x4;

static __device__ __forceinline__ unsigned short f2bf(float f) {
  union { float f; unsigned int u; } v; v.f = f;
  unsigned int u = v.u;
  return (unsigned short)((u + 0x7fffu + ((u >> 16) & 1u)) >> 16);
}
static __device__ __forceinline__ float bf2f(unsigned short u) {
  union { unsigned int u; float f; } v; v.u = ((unsigned int)u) << 16;
  return v.f;
}
static __device__ __forceinline__ unsigned int cvtpk2(float lo, float hi) {
  unsigned int r;
  asm("v_cvt_pk_bf16_f32 %0, %1, %2" : "=v"(r) : "v"(lo), "v"(hi));
  return r;
}

// ---------------- fp32 -> bf16 conversion -------------------------------------
__global__ __launch_bounds__(256) void cvt_bf16_kernel(
    const float* __restrict__ in, unsigned short* __restrict__ out, int n8) {
  int i = blockIdx.x * 256 + threadIdx.x;
  int stride = gridDim.x * 256;
  for (; i < n8; i += stride) {
    fl4 a = ((const fl4*)in)[2 * i];
    fl4 b = ((const fl4*)in)[2 * i + 1];
    us8 u = { f2bf(a[0]), f2bf(a[1]), f2bf(a[2]), f2bf(a[3]),
              f2bf(b[0]), f2bf(b[1]), f2bf(b[2]), f2bf(b[3]) };
    ((us8*)out)[i] = u;
  }
}

// ---------------- bf16 GEMM (m97 structure, counted-vmcnt WFP32) --------------
template <int OUTMODE, int WFP32, int ROPEQ = 0>
__global__ __launch_bounds__(256) void gemm_k(
    const unsigned short* __restrict__ A, int lda,
    const unsigned short* __restrict__ Wb16,
    const float* __restrict__ Wfa, const float* __restrict__ Wfb, int nsplit,
    int ldw,
    const float* __restrict__ bias,
    void* __restrict__ Cv, int ldc, size_t zstride,
    int Ncl, int ksl, float alpha,
    const float* __restrict__ ctab = nullptr,
    const float* __restrict__ stab = nullptr)
{
  const int n0 = blockIdx.x * 128;
  if (n0 >= Ncl) return;

  __shared__ unsigned short As[128 * 64];
  __shared__ unsigned short Ws[128 * 64];
  const int t = threadIdx.x;
  const int l = t & 63, w = t >> 6;
  const int r15 = l & 15, g = l >> 4;
  const int wm = (w >> 1) * 64, wn = (w & 1) * 64;
  const int m0 = blockIdx.y * 128;
  const int kbase = blockIdx.z * ksl;
  const int srow = l >> 3;
  const int scol = (l & 7) * 8;

  f32x4 acc[4][4];
#pragma unroll
  for (int i = 0; i < 4; ++i)
#pragma unroll
    for (int j = 0; j < 4; ++j) acc[i][j] = (f32x4){0.f, 0.f, 0.f, 0.f};

  const unsigned short* Ab = A + (size_t)m0 * lda;
  const unsigned short* Wb = nullptr;
  const float* Wf = nullptr;
  if constexpr (WFP32) {
    Wf = (n0 < nsplit) ? Wfa + (size_t)n0 * ldw : Wfb + (size_t)(n0 - nsplit) * ldw;
  } else {
    Wb = Wb16 + (size_t)n0 * ldw;
  }

  fl4 wx[4], wy[4];
  auto issueW = [&](int k0) {
#pragma unroll
    for (int i = 0; i < 4; ++i) {
      int c = t + 256 * i;
      const float* src = Wf + (size_t)(c >> 3) * ldw + k0 + (c & 7) * 8;
      wx[i] = *(const fl4*)src;
      wy[i] = *(const fl4*)(src + 4);
    }
  };

  if constexpr (WFP32) issueW(kbase);
  const int kend = kbase + ksl;

  for (int k0 = kbase; k0 < kend; k0 += 64) {
    if constexpr (WFP32) {
      __builtin_amdgcn_s_barrier();
      __builtin_amdgcn_sched_barrier(0);
    } else {
      __syncthreads();
    }
#pragma unroll
    for (int i = 0; i < 4; ++i) {
      int chunk = w * 4 + i;
      int row = chunk * 8 + srow;
      __builtin_amdgcn_global_load_lds(
          (const __attribute__((address_space(1))) void*)(Ab + (size_t)row * lda + k0 + scol),
          (__attribute__((address_space(3))) void*)(As + chunk * 512), 16, 0, 0);
      if constexpr (!WFP32) {
        __builtin_amdgcn_global_load_lds(
            (const __attribute__((address_space(1))) void*)(Wb + (size_t)row * ldw + k0 + scol),
            (__attribute__((address_space(3))) void*)(Ws + chunk * 512), 16, 0, 0);
      }
    }
    if constexpr (WFP32) {
      __builtin_amdgcn_sched_barrier(0);
      asm volatile("s_waitcnt vmcnt(4)" ::: "memory");
      __builtin_amdgcn_sched_barrier(0);
#pragma unroll
      for (int i = 0; i < 4; ++i) {
        int c = t + 256 * i;
        u32x4 p = { cvtpk2(wx[i][0], wx[i][1]), cvtpk2(wx[i][2], wx[i][3]),
                    cvtpk2(wy[i][0], wy[i][1]), cvtpk2(wy[i][2], wy[i][3]) };
        ((u32x4*)Ws)[c] = p;
      }
      if (k0 + 64 < kend) {
        issueW(k0 + 64);
        __builtin_amdgcn_sched_barrier(0);
        asm volatile("s_waitcnt vmcnt(8) lgkmcnt(0)" ::: "memory");
      } else {
        asm volatile("s_waitcnt vmcnt(0) lgkmcnt(0)" ::: "memory");
      }
      __builtin_amdgcn_sched_barrier(0);
      __builtin_amdgcn_s_barrier();
    } else {
      __syncthreads();
    }
#pragma unroll
    for (int kk = 0; kk < 2; ++kk) {
      bf16x8 a[4], b[4];
#pragma unroll
      for (int mt = 0; mt < 4; ++mt)
        a[mt] = *reinterpret_cast<const bf16x8*>(&As[(wm + mt * 16 + r15) * 64 + kk * 32 + 8 * g]);
#pragma unroll
      for (int nt = 0; nt < 4; ++nt)
        b[nt] = *reinterpret_cast<const bf16x8*>(&Ws[(wn + nt * 16 + r15) * 64 + kk * 32 + 8 * g]);
#pragma unroll
      for (int mt = 0; mt < 4; ++mt)
#pragma unroll
        for (int nt = 0; nt < 4; ++nt)
          acc[mt][nt] = __builtin_amdgcn_mfma_f32_16x16x32_bf16(a[mt], b[nt], acc[mt][nt], 0, 0, 0);
    }
  }

  if constexpr (OUTMODE == 1) {
    float bv[4];
#pragma unroll
    for (int nt = 0; nt < 4; ++nt) {
      int col = n0 + wn + nt * 16 + r15;
      bv[nt] = (col < Ncl) ? bias[col] : 0.f;
    }
    bool isrope = false;
    if constexpr (ROPEQ) isrope = (n0 + wn) >= 16384;
    if (ROPEQ && isrope) {
#pragma unroll
      for (int mt = 0; mt < 4; ++mt)
#pragma unroll
        for (int r = 0; r < 4; ++r) {
          int row = m0 + wm + mt * 16 + g * 4 + r;
#pragma unroll
          for (int ntp = 0; ntp < 2; ++ntp) {
            int j = ntp * 16 + r15;
            float c = ctab[row * 32 + j];
            float s = stab[row * 32 + j];
            float x1 = acc[mt][ntp][r] + bv[ntp];
            float x2 = acc[mt][ntp + 2][r] + bv[ntp + 2];
            int col1 = n0 + wn + ntp * 16 + r15;
            ((unsigned short*)Cv)[(size_t)row * ldc + col1] =
                f2bf((x1 * c - x2 * s) * alpha);
            ((unsigned short*)Cv)[(size_t)row * ldc + col1 + 32] =
                f2bf((x2 * c + x1 * s) * alpha);
          }
        }
    } else {
#pragma unroll
      for (int mt = 0; mt < 4; ++mt)
#pragma unroll
        for (int nt = 0; nt < 4; ++nt) {
          int col = n0 + wn + nt * 16 + r15;
          if (col < Ncl) {
#pragma unroll
            for (int r = 0; r < 4; ++r) {
              int row = m0 + wm + mt * 16 + g * 4 + r;
              ((unsigned short*)Cv)[(size_t)row * ldc + col] =
                  f2bf((acc[mt][nt][r] + bv[nt]) * alpha);
            }
          }
        }
    }
  } else {
    float* Cp = (float*)Cv + blockIdx.z * zstride;
#pragma unroll
    for (int mt = 0; mt < 4; ++mt)
#pragma unroll
      for (int nt = 0; nt < 4; ++nt) {
        int col = n0 + wn + nt * 16 + r15;
        if (col < Ncl) {
#pragma unroll
          for (int r = 0; r < 4; ++r) {
            int row = m0 + wm + mt * 16 + g * 4 + r;
            Cp[(size_t)row * ldc + col] = acc[mt][nt][r];
          }
        }
      }
  }
}

// ---------------- G4: 8-phase 256x256 template (T2+T3+T4+T5) ------------------
// BM=BN=256, BK=64, 8 waves (512 thr). LDS 128KB = 2 buf x {A0,A1,B0,B1} of
// 128x64 bf16 (16KB each). Per K-tile, 4 phases compute C-quadrants in gray
// order (0,0)->(0,1)->(1,1)->(1,0); operand reuse gives ds_reads 12/4/8/0.
// Stages (1 half-tile = 2 glds/thread/phase): P1:(t+1).A1, P2..P5:(t+2).A0,
// B0,B1,A1, P6..P8:(t+3).A0,B0,B1.  vmcnt(6) at P4 & P8 drains exactly one
// tile, leaves 3 half-tiles in flight (T4).  st_16x32 swizzle both sides (T2).
#define G4_DSREAD_A(buf, mh)                                                  \
  _Pragma("unroll") for (int mf = 0; mf < 4; ++mf)                            \
  _Pragma("unroll") for (int kk = 0; kk < 2; ++kk)                            \
    af[mf][kk] = rdA(buf, mh, mf, kk);

#define G4_DSREAD_B(buf, nh, breg)                                            \
  _Pragma("unroll") for (int nf = 0; nf < 2; ++nf)                            \
  _Pragma("unroll") for (int kk = 0; kk < 2; ++kk)                            \
    breg[nf][kk] = rdB(buf, nh, nf, kk);

#define G4_MFMA(mh, nh, breg)                                                 \
  __builtin_amdgcn_s_setprio(1);                                              \
  _Pragma("unroll") for (int kk = 0; kk < 2; ++kk)                            \
  _Pragma("unroll") for (int mf = 0; mf < 4; ++mf)                            \
  _Pragma("unroll") for (int nf = 0; nf < 2; ++nf)                            \
    acc[mh][nh][mf][nf] = __builtin_amdgcn_mfma_f32_16x16x32_bf16(            \
        af[mf][kk], breg[nf][kk], acc[mh][nh][mf][nf], 0, 0, 0);              \
  __builtin_amdgcn_s_setprio(0);

#define G4_BAR_IN()                                                           \
  __builtin_amdgcn_s_barrier();                                               \
  asm volatile("s_waitcnt lgkmcnt(0)" ::: "memory");                          \
  __builtin_amdgcn_sched_barrier(0);

#define G4_BAR_OUT()                                                          \
  __builtin_amdgcn_sched_barrier(0);                                          \
  __builtin_amdgcn_s_barrier();

__global__ __launch_bounds__(512, 2) void gemm_g4_8ph(
    const unsigned short* __restrict__ A,      // obuf [1024][16384] bf16
    const unsigned short* __restrict__ W,      // Wob [7168][16384] bf16
    float* __restrict__ pbuf)                  // [8][1024][7168] fp32 partials
{
  __shared__ unsigned short S[65536];          // 128 KB
  const int t = threadIdx.x;
  const int l = t & 63, w = t >> 6;            // 8 waves
  const int r15 = l & 15, g = l >> 4;
  const int n0 = blockIdx.x * 256;
  const int m0 = blockIdx.y * 256;
  const int kbase = blockIdx.z * 2048;
  const int NT = 32;                           // K-tiles per block

  // glds staging: linear LDS dest, pre-swizzled global source (T2, rule #21)
  const int lp = l ^ (((l >> 5) & 1) << 1);
  const int srow = lp >> 3;
  const int scol = (lp & 7) * 8;
  // wave's piece within each 128x128 quadrant: rows (w>>2)*64, cols (w&3)*32
  const int pr = (w >> 2) * 64;
  const int pc = (w & 3) * 32;

  f32x4 acc[2][2][4][2];
#pragma unroll
  for (int a0 = 0; a0 < 2; ++a0)
#pragma unroll
    for (int a1 = 0; a1 < 2; ++a1)
#pragma unroll
      for (int a2 = 0; a2 < 4; ++a2)
#pragma unroll
        for (int a3 = 0; a3 < 2; ++a3)
          acc[a0][a1][a2][a3] = (f32x4){0.f, 0.f, 0.f, 0.f};

  // stage one half-tile (16KB): which: 0=A0,1=A1,2=B0,3=B1
  auto stage = [&](int tile, int which) {
    if (tile >= NT) return;
    const int k0 = kbase + tile * 64;
    const unsigned short* gb = (which < 2)
        ? A + (size_t)(m0 + which * 128) * 16384 + k0
        : W + (size_t)(n0 + (which - 2) * 128) * 16384 + k0;
    unsigned short* dst = S + (tile & 1) * 32768 + which * 8192;
#pragma unroll
    for (int i = 0; i < 2; ++i) {
      __builtin_amdgcn_global_load_lds(
          (const __attribute__((address_space(1))) void*)(gb + (size_t)((w * 2 + i) * 8 + srow) * 16384 + scol),
          (__attribute__((address_space(3))) void*)(dst + (w * 2 + i) * 512 + l * 8), 16, 0, 0);
    }
  };

  auto rdA = [&](int buf, int mh, int mf, int kk) -> bf16x8 {
    int row = pr + mf * 16 + r15;
    int L = row * 128 + kk * 64 + g * 16;
    L ^= ((L >> 9) & 1) << 5;
    return *(const bf16x8*)((const char*)S + buf * 65536 + mh * 16384 + L);
  };
  auto rdB = [&](int buf, int nh, int nf, int kk) -> bf16x8 {
    int row = pc + nf * 16 + r15;
    int L = row * 128 + kk * 64 + g * 16;
    L ^= ((L >> 9) & 1) << 5;
    return *(const bf16x8*)((const char*)S + buf * 65536 + (2 + nh) * 16384 + L);
  };

  bf16x8 af[4][2], bA[2][2], bB[2][2];

  // prologue: t0 all 4 halves + t1.{A0,B0,B1}; t1.A1 staged at P1 of iter 0
  stage(0, 0); stage(0, 1); stage(0, 2); stage(0, 3);
  stage(1, 0); stage(1, 2); stage(1, 3);
  __builtin_amdgcn_sched_barrier(0);
  asm volatile("s_waitcnt vmcnt(6)" ::: "memory");   // t0 landed; t1 x3 in flight
  __builtin_amdgcn_sched_barrier(0);
  __builtin_amdgcn_s_barrier();

  for (int i = 0; i < 16; ++i) {
    const int tb = 2 * i;
    const bool last = (i == 15);
    // P1: quadrant (0,0) of tile tb (buf0)
    G4_DSREAD_A(0, 0)
    G4_DSREAD_B(0, 0, bA)
    stage(tb + 1, 1);
    G4_BAR_IN()
    G4_MFMA(0, 0, bA)
    G4_BAR_OUT()
    // P2: (0,1) — reuse af
    G4_DSREAD_B(0, 1, bB)
    stage(tb + 2, 0);
    G4_BAR_IN()
    G4_MFMA(0, 1, bB)
    G4_BAR_OUT()
    // P3: (1,1) — reuse bB
    G4_DSREAD_A(0, 1)
    stage(tb + 2, 2);
    G4_BAR_IN()
    G4_MFMA(1, 1, bB)
    G4_BAR_OUT()
    // P4: (1,0) — reuse af, bA; no ds_reads
    stage(tb + 2, 3);
    G4_BAR_IN()
    G4_MFMA(1, 0, bA)
    if (last) { asm volatile("s_waitcnt vmcnt(0)" ::: "memory"); }
    else      { asm volatile("s_waitcnt vmcnt(6)" ::: "memory"); }
    G4_BAR_OUT()
    // P5: quadrant (0,0) of tile tb+1 (buf1)
    G4_DSREAD_A(1, 0)
    G4_DSREAD_B(1, 0, bA)
    stage(tb + 2, 1);
    G4_BAR_IN()
    G4_MFMA(0, 0, bA)
    G4_BAR_OUT()
    // P6: (0,1)
    G4_DSREAD_B(1, 1, bB)
    stage(tb + 3, 0);
    G4_BAR_IN()
    G4_MFMA(0, 1, bB)
    G4_BAR_OUT()
    // P7: (1,1)
    G4_DSREAD_A(1, 1)
    stage(tb + 3, 2);
    G4_BAR_IN()
    G4_MFMA(1, 1, bB)
    G4_BAR_OUT()
    // P8: (1,0)
    stage(tb + 3, 3);
    G4_BAR_IN()
    G4_MFMA(1, 0, bA)
    if (last) { asm volatile("s_waitcnt vmcnt(0)" ::: "memory"); }
    else      { asm volatile("s_waitcnt vmcnt(6)" ::: "memory"); }
    G4_BAR_OUT()
  }

  float* Cp = pbuf + (size_t)blockIdx.z * 1024 * 7168;
#pragma unroll
  for (int mh = 0; mh < 2; ++mh)
#pragma unroll
    for (int nh = 0; nh < 2; ++nh)
#pragma unroll
      for (int mf = 0; mf < 4; ++mf)
#pragma unroll
        for (int nf = 0; nf < 2; ++nf) {
          int col = n0 + nh * 128 + pc + nf * 16 + r15;
#pragma unroll
          for (int r = 0; r < 4; ++r) {
            int row = m0 + mh * 128 + pr + mf * 16 + g * 4 + r;
            Cp[(size_t)row * 7168 + col] = acc[mh][nh][mf][nf][r];
          }
        }
}

// ---------------- split-K reductions ------------------------------------------
__global__ __launch_bounds__(256) void reduce_f32_kernel(
    const float* __restrict__ pbuf, const float* __restrict__ bias,
    float* __restrict__ out, int ldo, int rowlen4, int nz, size_t zstride, int total4)
{
  int idx = blockIdx.x * 256 + threadIdx.x;
  if (idx >= total4) return;
  int r = idx / rowlen4, c4 = idx % rowlen4;
  fl4 acc = *(const fl4*)(bias + c4 * 4);
  for (int z = 0; z < nz; ++z)
    acc += *(const fl4*)(pbuf + z * zstride + (size_t)idx * 4);
  *(fl4*)(out + (size_t)r * ldo + c4 * 4) = acc;
}

__global__ __launch_bounds__(256) void reduce_bf16_kernel(
    const float* __restrict__ pbuf, const float* __restrict__ bias,
    unsigned short* __restrict__ out, int ldo, int rowlen4, int nz, size_t zstride, int total4)
{
  int idx = blockIdx.x * 256 + threadIdx.x;
  if (idx >= total4) return;
  int r = idx / rowlen4, c4 = idx % rowlen4;
  fl4 acc = *(const fl4*)(bias + c4 * 4);
  for (int z = 0; z < nz; ++z)
    acc += *(const fl4*)(pbuf + z * zstride + (size_t)idx * 4);
  us4 u = { f2bf(acc[0]), f2bf(acc[1]), f2bf(acc[2]), f2bf(acc[3]) };
  *(us4*)(out + (size_t)r * ldo + c4 * 4) = u;
}

// ---------------- rope tables + table-based rope (k_r only) -------------------
__global__ __launch_bounds__(256) void rope_table_kernel(float* __restrict__ ctab,
                                                         float* __restrict__ stab) {
  int idx = blockIdx.x * 256 + threadIdx.x;
  if (idx >= S_LEN * 32) return;
  int j = idx & 31, s = idx >> 5;
  float invf = expf(-0.28782313662425574f * (float)j);
  float ang = (float)s * invf;
  ctab[idx] = cosf(ang);
  stab[idx] = sinf(ang);
}

__global__ void rope_bf16_kernel(unsigned short* __restrict__ x, int nh, int lda, int total,
                                 const float* __restrict__ ctab,
                                 const float* __restrict__ stab) {
  int idx = blockIdx.x * 256 + threadIdx.x;
  if (idx >= total) return;
  int j = idx & 31;
  int rest = idx >> 5;
  int hh = rest % nh;
  int s = rest / nh;
  float c = ctab[s * 32 + j], sn = stab[s * 32 + j];
  size_t base = (size_t)s * lda + hh * 64;
  float x1 = bf2f(x[base + j]), x2 = bf2f(x[base + j + 32]);
  x[base + j]      = f2bf(x1 * c - x2 * sn);
  x[base + j + 32] = f2bf(x2 * c + x1 * sn);
}

// ---------------- V transpose -------------------------------------------------
__global__ __launch_bounds__(256) void vtrans_kernel(
    const unsigned short* __restrict__ kvb, unsigned short* __restrict__ vt) {
  __shared__ unsigned short tl[64][72];
  const int s0 = blockIdx.x * 64;
  const int c0 = blockIdx.y * 64;
  const int t = threadIdx.x;
  const int rr = t >> 3, cc = (t & 7) * 8;
  const int hbase = (c0 >> 7) * 256 + 128 + (c0 & 127);
#pragma unroll
  for (int i = 0; i < 2; ++i) {
    int r = rr + i * 32;
    *reinterpret_cast<bf16x8*>(&tl[r][cc]) =
        *reinterpret_cast<const bf16x8*>(kvb + (size_t)(s0 + r) * 32768 + hbase + cc);
  }
  __syncthreads();
#pragma unroll
  for (int i = 0; i < 2; ++i) {
    int vc = rr + i * 32;
    unsigned short tmp[8];
#pragma unroll
    for (int j = 0; j < 8; ++j) tmp[j] = tl[cc + j][vc];
    *reinterpret_cast<bf16x8*>(&vt[(size_t)(c0 + vc) * 1024 + s0 + cc]) =
        *reinterpret_cast<bf16x8*>(tmp);
  }
}

// ---------------- flash attention: QBLK=128, 8 waves/block --------------------
__global__ __launch_bounds__(512) void mla_attn_kernel(
    const unsigned short* __restrict__ qcat,
    const unsigned short* __restrict__ kvb,
    const unsigned short* __restrict__ kr,
    const unsigned short* __restrict__ vt,
    unsigned short* __restrict__ obuf)
{
  __shared__ unsigned short Klds[64][200];
  __shared__ unsigned short Vlds[128][72];
  __shared__ unsigned short Plds[8][16][72];

  const int t = threadIdx.x;
  const int l = t & 63, w = t >> 6;
  const int r15 = l & 15, g = l >> 4;
  const int bid = blockIdx.x;
  const int orig = (bid & 7) * 128 + (bid >> 3);
  const int h = orig >> 3;
  const int q0 = (orig & 7) * 128;

  bf16x8 qf[6];
  const unsigned short* qrow = qcat + (size_t)(q0 + w * 16 + r15) * 24576;
#pragma unroll
  for (int kk = 0; kk < 4; ++kk)
    qf[kk] = *reinterpret_cast<const bf16x8*>(qrow + h * 128 + kk * 32 + 8 * g);
#pragma unroll
  for (int kk = 4; kk < 6; ++kk)
    qf[kk] = *reinterpret_cast<const bf16x8*>(qrow + 16384 + h * 64 + (kk - 4) * 32 + 8 * g);

  bf16x8 kreg[3], vreg[2];
  auto loadKV = [&](int kk0) {
#pragma unroll
    for (int i = 0; i < 3; ++i) {
      int c = t + 512 * i, row = c / 24, cb = c % 24;
      const unsigned short* src = (cb < 16)
          ? kvb + (size_t)(kk0 + row) * 32768 + h * 256 + cb * 8
          : kr + (size_t)(kk0 + row) * 2112 + (cb - 16) * 8;
      kreg[i] = *reinterpret_cast<const bf16x8*>(src);
    }
#pragma unroll
    for (int i = 0; i < 2; ++i) {
      int c = t + 512 * i, d = c >> 3, kb = c & 7;
      vreg[i] = *reinterpret_cast<const bf16x8*>(vt + ((size_t)h * 128 + d) * 1024 + kk0 + kb * 8);
    }
  };

  float m_r[4], l_r[4];
  f32x4 oacc[8];
#pragma unroll
  for (int r = 0; r < 4; ++r) { m_r[r] = -1e30f; l_r[r] = 0.f; }
#pragma unroll
  for (int d = 0; d < 8; ++d) oacc[d] = (f32x4){0.f, 0.f, 0.f, 0.f};

  loadKV(0);

  for (int kt = 0; kt < 16; ++kt) {
    __syncthreads();
#pragma unroll
    for (int i = 0; i < 3; ++i) {
      int c = t + 512 * i, row = c / 24, cb = c % 24;
      *reinterpret_cast<bf16x8*>(&Klds[row][cb * 8]) = kreg[i];
    }
#pragma unroll
    for (int i = 0; i < 2; ++i) {
      int c = t + 512 * i, d = c >> 3, kb = c & 7;
      *reinterpret_cast<bf16x8*>(&Vlds[d][kb * 8]) = vreg[i];
    }
    __syncthreads();
    if (kt < 15) loadKV((kt + 1) * 64);

    f32x4 sacc[4];
#pragma unroll
    for (int nt = 0; nt < 4; ++nt) sacc[nt] = (f32x4){0.f, 0.f, 0.f, 0.f};
    __builtin_amdgcn_s_setprio(1);
#pragma unroll
    for (int nt = 0; nt < 4; ++nt)
#pragma unroll
      for (int kk = 0; kk < 6; ++kk) {
        bf16x8 b = *reinterpret_cast<const bf16x8*>(&Klds[nt * 16 + r15][kk * 32 + 8 * g]);
        sacc[nt] = __builtin_amdgcn_mfma_f32_16x16x32_bf16(qf[kk], b, sacc[nt], 0, 0, 0);
      }
    __builtin_amdgcn_s_setprio(0);

    float sc[4], rsum[4];
#pragma unroll
    for (int r = 0; r < 4; ++r) {
      float mx = fmaxf(fmaxf(sacc[0][r], sacc[1][r]), fmaxf(sacc[2][r], sacc[3][r]));
      mx = fmaxf(mx, __shfl_xor(mx, 1));
      mx = fmaxf(mx, __shfl_xor(mx, 2));
      mx = fmaxf(mx, __shfl_xor(mx, 4));
      mx = fmaxf(mx, __shfl_xor(mx, 8));
      float mn = fmaxf(m_r[r], mx);
      sc[r] = __expf(m_r[r] - mn);
      m_r[r] = mn;
      rsum[r] = 0.f;
    }
#pragma unroll
    for (int nt = 0; nt < 4; ++nt)
#pragma unroll
      for (int r = 0; r < 4; ++r) {
        float p = __expf(sacc[nt][r] - m_r[r]);
        rsum[r] += p;
        Plds[w][g * 4 + r][nt * 16 + r15] = f2bf(p);
      }
#pragma unroll
    for (int r = 0; r < 4; ++r) {
      float s = rsum[r];
      s += __shfl_xor(s, 1);
      s += __shfl_xor(s, 2);
      s += __shfl_xor(s, 4);
      s += __shfl_xor(s, 8);
      l_r[r] = l_r[r] * sc[r] + s;
    }
#pragma unroll
    for (int d = 0; d < 8; ++d)
#pragma unroll
      for (int r = 0; r < 4; ++r) oacc[d][r] *= sc[r];

    bf16x8 pa0 = *reinterpret_cast<const bf16x8*>(&Plds[w][r15][8 * g]);
    bf16x8 pa1 = *reinterpret_cast<const bf16x8*>(&Plds[w][r15][32 + 8 * g]);
    __builtin_amdgcn_s_setprio(1);
#pragma unroll
    for (int dt = 0; dt < 8; ++dt) {
      bf16x8 v0 = *reinterpret_cast<const bf16x8*>(&Vlds[dt * 16 + r15][8 * g]);
      bf16x8 v1 = *reinterpret_cast<const bf16x8*>(&Vlds[dt * 16 + r15][32 + 8 * g]);
      oacc[dt] = __builtin_amdgcn_mfma_f32_16x16x32_bf16(pa0, v0, oacc[dt], 0, 0, 0);
      oacc[dt] = __builtin_amdgcn_mfma_f32_16x16x32_bf16(pa1, v1, oacc[dt], 0, 0, 0);
    }
    __builtin_amdgcn_s_setprio(0);
  }

#pragma unroll
  for (int dt = 0; dt < 8; ++dt)
#pragma unroll
    for (int r = 0; r < 4; ++r) {
      int row = q0 + w * 16 + g * 4 + r;
      int col = h * DH + dt * 16 + r15;
      obuf[(size_t)row * 16384 + col] = f2bf(oacc[dt][r] / l_r[r]);
    }
}

// ------------------------------------------------------------------------------
extern "C" void kernel_launch(void* const* d_in, const int* in_sizes, int n_in,
                              void* d_out, int out_size, void* d_ws, size_t ws_size,
                              hipStream_t stream) {
  const float* h    = (const float*)d_in[0];
  const float* Wdq  = (const float*)d_in[1];
  const float* bdq  = (const float*)d_in[2];
  const float* Wdkv = (const float*)d_in[3];
  const float* bdkv = (const float*)d_in[4];
  const float* Wuq  = (const float*)d_in[5];
  const float* buq  = (const float*)d_in[6];
  const float* Wukv = (const float*)d_in[7];
  const float* bukv = (const float*)d_in[8];
  const float* Wrq  = (const float*)d_in[9];
  const float* brq  = (const float*)d_in[10];
  const float* Wrk  = (const float*)d_in[11];
  const float* brk  = (const float*)d_in[12];
  const float* Wo   = (const float*)d_in[13];
  const float* bo   = (const float*)d_in[14];
  float* out = (float*)d_out;

  char* ws = (char*)d_ws;
  size_t off = 0;
  auto alloc = [&](size_t bytes) {
    char* p = ws + off;
    off += (bytes + 255) & ~(size_t)255;
    return p;
  };
  unsigned short* hb    = (unsigned short*)alloc((size_t)1024 * 7168 * 2);
  unsigned short* W1cat = (unsigned short*)alloc((size_t)2176 * 7168 * 2);
  float*          b1cat = (float*)alloc(2176 * 4);
  float*          b2cat = (float*)alloc(24576 * 4);
  unsigned short* ccat  = (unsigned short*)alloc((size_t)1024 * 2112 * 2);
  unsigned short* qcat  = (unsigned short*)alloc((size_t)1024 * 24576 * 2);
  unsigned short* kvbb  = (unsigned short*)alloc((size_t)1024 * 32768 * 2);
  unsigned short* vt    = (unsigned short*)alloc((size_t)16384 * 1024 * 2);
  unsigned short* obuf  = (unsigned short*)alloc((size_t)1024 * 16384 * 2);
  float*          ctab  = (float*)alloc((size_t)S_LEN * 32 * 4);
  float*          stab  = (float*)alloc((size_t)S_LEN * 32 * 4);
  // G1 split-K partials alias not-yet-written qcat (34.6 MB < 50.3 MB)
  float* pbufG1 = (float*)qcat;
  // d_ws ~1.8 GB: Wob (bf16 Wo, 235 MB) @ 288 MiB; pbufG4 (8x29.4=235 MB) @ 544 MiB
  unsigned short* Wob    = (unsigned short*)(ws + ((size_t)288 << 20));
  float*          pbufG4 = (float*)(ws + ((size_t)544 << 20));

  auto cvt = [&](const float* in, unsigned short* outp, size_t n) {
    int n8 = (int)(n / 8);
    int blocks = (n8 + 255) / 256;
    if (blocks > 2048) blocks = 2048;
    cvt_bf16_kernel<<<blocks, 256, 0, stream>>>(in, outp, n8);
  };

  // --- conversions for h and the small concatenated W1 ---
  cvt(h,    hb,    (size_t)1024 * 7168);
  cvt(Wdq,  W1cat, (size_t)1536 * 7168);
  cvt(Wdkv, W1cat + (size_t)1536 * 7168, (size_t)512 * 7168);
  cvt(Wrk,  W1cat + (size_t)2048 * 7168, (size_t)64 * 7168);
  hipMemsetAsync(W1cat + (size_t)2112 * 7168, 0, (size_t)64 * 7168 * 2, stream);
  hipMemcpyAsync(b1cat,        bdq,  1536 * 4, hipMemcpyDeviceToDevice, stream);
  hipMemcpyAsync(b1cat + 1536, bdkv, 512 * 4,  hipMemcpyDeviceToDevice, stream);
  hipMemcpyAsync(b1cat + 2048, brk,  64 * 4,   hipMemcpyDeviceToDevice, stream);
  hipMemsetAsync(b1cat + 2112, 0, 64 * 4, stream);
  hipMemcpyAsync(b2cat,         buq, 16384 * 4, hipMemcpyDeviceToDevice, stream);
  hipMemcpyAsync(b2cat + 16384, brq, 8192 * 4,  hipMemcpyDeviceToDevice, stream);
  rope_table_kernel<<<(S_LEN * 32 + 255) / 256, 256, 0, stream>>>(ctab, stab);

  const float scale = 0.07216878364870323f;   // 1/sqrt(192)
  const int BIGN = 1 << 30;
  dim3 blk(256);

  // G1 (split-K=4, bf16 W): partials = h @ W1cat^T
  gemm_k<2, 0><<<dim3(24, 8, 4), blk, 0, stream>>>(
      hb, 7168, W1cat, nullptr, nullptr, BIGN, 7168, nullptr,
      pbufG1, 2112, (size_t)1024 * 2112, 2112, 1792, 1.0f);
  reduce_bf16_kernel<<<2112, blk, 0, stream>>>(pbufG1, b1cat, ccat, 2112, 528, 4,
                                               (size_t)1024 * 2112, 1024 * 2112 / 4);
  rope_bf16_kernel<<<(1024 * 32 + 255) / 256, blk, 0, stream>>>(ccat + 2048, 1, 2112, 1024 * 32, ctab, stab);

  // G2 (fp32 W direct, counted-vmcnt pipeline, fused q_r RoPE):
  gemm_k<1, 1, 1><<<dim3(192, 8, 1), blk, 0, stream>>>(
      ccat, 2112, nullptr, Wuq, Wrq, 16384, 1536, b2cat,
      qcat, 24576, 0, 24576, 1536, scale, ctab, stab);

  // G3 (fp32 W direct, counted-vmcnt pipeline): kv = c_kv @ Wukv^T + bukv
  gemm_k<1, 1><<<dim3(256, 8, 1), blk, 0, stream>>>(
      ccat + 1536, 2112, nullptr, Wukv, Wukv, BIGN, 512, bukv,
      kvbb, 32768, 0, 32768, 512, 1.0f);
  vtrans_kernel<<<dim3(16, 256), blk, 0, stream>>>(kvbb, vt);
  mla_attn_kernel<<<dim3(1024), dim3(512), 0, stream>>>(qcat, kvbb, ccat + 2048, vt, obuf);

  // G4: cvt Wo -> bf16 once, 8-phase 256^2 GEMM (split-K=8), reduce.
  cvt(Wo, Wob, (size_t)7168 * 16384);
  gemm_g4_8ph<<<dim3(28, 4, 8), dim3(512), 0, stream>>>(obuf, Wob, pbufG4);
  reduce_f32_kernel<<<7168, blk, 0, stream>>>(pbufG4, bo, out,
                                              7168, 1792, 8, (size_t)1024 * 7168, 1024 * 7168 / 4);
}

// Round 17
// 1025.983 us; speedup vs baseline: 1.1983x; 1.0270x over previous
//
#include <hip/hip_runtime.h>
#include <hip/hip_bf16.h>

#define S_LEN 1024
#define HID 7168
#define NH 128
#define DQ 1536
#define DKV 512
#define DH 128
#define DR 64

typedef __attribute__((ext_vector_type(8))) short bf16x8;
typedef __attribute__((ext_vector_type(4))) float f32x4;
typedef __attribute__((ext_vector_type(4))) float fl4;
typedef __attribute__((ext_vector_type(4))) unsigned short us4;
typedef __attribute__((ext_vector_type(8))) unsigned short us8;
typedef __attribute__((ext_vector_type(4))) unsigned int u32x4;

static __device__ __forceinline__ unsigned short f2bf(float f) {
  union { float f; unsigned int u; } v; v.f = f;
  unsigned int u = v.u;
  return (unsigned short)((u + 0x7fffu + ((u >> 16) & 1u)) >> 16);
}
static __device__ __forceinline__ float bf2f(unsigned short u) {
  union { unsigned int u; float f; } v; v.u = ((unsigned int)u) << 16;
  return v.f;
}
static __device__ __forceinline__ unsigned int cvtpk2(float lo, float hi) {
  unsigned int r;
  asm("v_cvt_pk_bf16_f32 %0, %1, %2" : "=v"(r) : "v"(lo), "v"(hi));
  return r;
}

// ---------------- fp32 -> bf16 conversion -------------------------------------
__global__ __launch_bounds__(256) void cvt_bf16_kernel(
    const float* __restrict__ in, unsigned short* __restrict__ out, int n8) {
  int i = blockIdx.x * 256 + threadIdx.x;
  int stride = gridDim.x * 256;
  for (; i < n8; i += stride) {
    fl4 a = ((const fl4*)in)[2 * i];
    fl4 b = ((const fl4*)in)[2 * i + 1];
    us8 u = { f2bf(a[0]), f2bf(a[1]), f2bf(a[2]), f2bf(a[3]),
              f2bf(b[0]), f2bf(b[1]), f2bf(b[2]), f2bf(b[3]) };
    ((us8*)out)[i] = u;
  }
}

// ---------------- bf16 GEMM (m97 structure, counted-vmcnt WFP32) --------------
template <int OUTMODE, int WFP32, int ROPEQ = 0>
__global__ __launch_bounds__(256) void gemm_k(
    const unsigned short* __restrict__ A, int lda,
    const unsigned short* __restrict__ Wb16,
    const float* __restrict__ Wfa, const float* __restrict__ Wfb, int nsplit,
    int ldw,
    const float* __restrict__ bias,
    void* __restrict__ Cv, int ldc, size_t zstride,
    int Ncl, int ksl, float alpha,
    const float* __restrict__ ctab = nullptr,
    const float* __restrict__ stab = nullptr)
{
  const int n0 = blockIdx.x * 128;
  if (n0 >= Ncl) return;

  __shared__ unsigned short As[128 * 64];
  __shared__ unsigned short Ws[128 * 64];
  const int t = threadIdx.x;
  const int l = t & 63, w = t >> 6;
  const int r15 = l & 15, g = l >> 4;
  const int wm = (w >> 1) * 64, wn = (w & 1) * 64;
  const int m0 = blockIdx.y * 128;
  const int kbase = blockIdx.z * ksl;
  const int srow = l >> 3;
  const int scol = (l & 7) * 8;

  f32x4 acc[4][4];
#pragma unroll
  for (int i = 0; i < 4; ++i)
#pragma unroll
    for (int j = 0; j < 4; ++j) acc[i][j] = (f32x4){0.f, 0.f, 0.f, 0.f};

  const unsigned short* Ab = A + (size_t)m0 * lda;
  const unsigned short* Wb = nullptr;
  const float* Wf = nullptr;
  if constexpr (WFP32) {
    Wf = (n0 < nsplit) ? Wfa + (size_t)n0 * ldw : Wfb + (size_t)(n0 - nsplit) * ldw;
  } else {
    Wb = Wb16 + (size_t)n0 * ldw;
  }

  fl4 wx[4], wy[4];
  auto issueW = [&](int k0) {
#pragma unroll
    for (int i = 0; i < 4; ++i) {
      int c = t + 256 * i;
      const float* src = Wf + (size_t)(c >> 3) * ldw + k0 + (c & 7) * 8;
      wx[i] = *(const fl4*)src;
      wy[i] = *(const fl4*)(src + 4);
    }
  };

  if constexpr (WFP32) issueW(kbase);
  const int kend = kbase + ksl;

  for (int k0 = kbase; k0 < kend; k0 += 64) {
    if constexpr (WFP32) {
      __builtin_amdgcn_s_barrier();
      __builtin_amdgcn_sched_barrier(0);
    } else {
      __syncthreads();
    }
#pragma unroll
    for (int i = 0; i < 4; ++i) {
      int chunk = w * 4 + i;
      int row = chunk * 8 + srow;
      __builtin_amdgcn_global_load_lds(
          (const __attribute__((address_space(1))) void*)(Ab + (size_t)row * lda + k0 + scol),
          (__attribute__((address_space(3))) void*)(As + chunk * 512), 16, 0, 0);
      if constexpr (!WFP32) {
        __builtin_amdgcn_global_load_lds(
            (const __attribute__((address_space(1))) void*)(Wb + (size_t)row * ldw + k0 + scol),
            (__attribute__((address_space(3))) void*)(Ws + chunk * 512), 16, 0, 0);
      }
    }
    if constexpr (WFP32) {
      __builtin_amdgcn_sched_barrier(0);
      asm volatile("s_waitcnt vmcnt(4)" ::: "memory");
      __builtin_amdgcn_sched_barrier(0);
#pragma unroll
      for (int i = 0; i < 4; ++i) {
        int c = t + 256 * i;
        u32x4 p = { cvtpk2(wx[i][0], wx[i][1]), cvtpk2(wx[i][2], wx[i][3]),
                    cvtpk2(wy[i][0], wy[i][1]), cvtpk2(wy[i][2], wy[i][3]) };
        ((u32x4*)Ws)[c] = p;
      }
      if (k0 + 64 < kend) {
        issueW(k0 + 64);
        __builtin_amdgcn_sched_barrier(0);
        asm volatile("s_waitcnt vmcnt(8) lgkmcnt(0)" ::: "memory");
      } else {
        asm volatile("s_waitcnt vmcnt(0) lgkmcnt(0)" ::: "memory");
      }
      __builtin_amdgcn_sched_barrier(0);
      __builtin_amdgcn_s_barrier();
    } else {
      __syncthreads();
    }
#pragma unroll
    for (int kk = 0; kk < 2; ++kk) {
      bf16x8 a[4], b[4];
#pragma unroll
      for (int mt = 0; mt < 4; ++mt)
        a[mt] = *reinterpret_cast<const bf16x8*>(&As[(wm + mt * 16 + r15) * 64 + kk * 32 + 8 * g]);
#pragma unroll
      for (int nt = 0; nt < 4; ++nt)
        b[nt] = *reinterpret_cast<const bf16x8*>(&Ws[(wn + nt * 16 + r15) * 64 + kk * 32 + 8 * g]);
#pragma unroll
      for (int mt = 0; mt < 4; ++mt)
#pragma unroll
        for (int nt = 0; nt < 4; ++nt)
          acc[mt][nt] = __builtin_amdgcn_mfma_f32_16x16x32_bf16(a[mt], b[nt], acc[mt][nt], 0, 0, 0);
    }
  }

  if constexpr (OUTMODE == 1) {
    float bv[4];
#pragma unroll
    for (int nt = 0; nt < 4; ++nt) {
      int col = n0 + wn + nt * 16 + r15;
      bv[nt] = (col < Ncl) ? bias[col] : 0.f;
    }
    bool isrope = false;
    if constexpr (ROPEQ) isrope = (n0 + wn) >= 16384;
    if (ROPEQ && isrope) {
#pragma unroll
      for (int mt = 0; mt < 4; ++mt)
#pragma unroll
        for (int r = 0; r < 4; ++r) {
          int row = m0 + wm + mt * 16 + g * 4 + r;
#pragma unroll
          for (int ntp = 0; ntp < 2; ++ntp) {
            int j = ntp * 16 + r15;
            float c = ctab[row * 32 + j];
            float s = stab[row * 32 + j];
            float x1 = acc[mt][ntp][r] + bv[ntp];
            float x2 = acc[mt][ntp + 2][r] + bv[ntp + 2];
            int col1 = n0 + wn + ntp * 16 + r15;
            ((unsigned short*)Cv)[(size_t)row * ldc + col1] =
                f2bf((x1 * c - x2 * s) * alpha);
            ((unsigned short*)Cv)[(size_t)row * ldc + col1 + 32] =
                f2bf((x2 * c + x1 * s) * alpha);
          }
        }
    } else {
#pragma unroll
      for (int mt = 0; mt < 4; ++mt)
#pragma unroll
        for (int nt = 0; nt < 4; ++nt) {
          int col = n0 + wn + nt * 16 + r15;
          if (col < Ncl) {
#pragma unroll
            for (int r = 0; r < 4; ++r) {
              int row = m0 + wm + mt * 16 + g * 4 + r;
              ((unsigned short*)Cv)[(size_t)row * ldc + col] =
                  f2bf((acc[mt][nt][r] + bv[nt]) * alpha);
            }
          }
        }
    }
  } else {
    float* Cp = (float*)Cv + blockIdx.z * zstride;
#pragma unroll
    for (int mt = 0; mt < 4; ++mt)
#pragma unroll
      for (int nt = 0; nt < 4; ++nt) {
        int col = n0 + wn + nt * 16 + r15;
        if (col < Ncl) {
#pragma unroll
          for (int r = 0; r < 4; ++r) {
            int row = m0 + wm + mt * 16 + g * 4 + r;
            Cp[(size_t)row * ldc + col] = acc[mt][nt][r];
          }
        }
      }
  }
}

// ---------------- G4: 8-phase 256x256 template (T2+T3+T4+T5) ------------------
// As R16 but with FULL st-swizzle: L ^= ((L>>7)&7)<<4 (3 row bits -> 16B-slot),
// glds source lane perm lp = (l&56) | ((l ^ (l>>3)) & 7).  Rows r..r+7 hit 8
// distinct 16B slots = all 32 banks; 16-lane b128 read -> 2-way (free).
#define G4_DSREAD_A(buf, mh)                                                  \
  _Pragma("unroll") for (int mf = 0; mf < 4; ++mf)                            \
  _Pragma("unroll") for (int kk = 0; kk < 2; ++kk)                            \
    af[mf][kk] = rdA(buf, mh, mf, kk);

#define G4_DSREAD_B(buf, nh, breg)                                            \
  _Pragma("unroll") for (int nf = 0; nf < 2; ++nf)                            \
  _Pragma("unroll") for (int kk = 0; kk < 2; ++kk)                            \
    breg[nf][kk] = rdB(buf, nh, nf, kk);

#define G4_MFMA(mh, nh, breg)                                                 \
  __builtin_amdgcn_s_setprio(1);                                              \
  _Pragma("unroll") for (int kk = 0; kk < 2; ++kk)                            \
  _Pragma("unroll") for (int mf = 0; mf < 4; ++mf)                            \
  _Pragma("unroll") for (int nf = 0; nf < 2; ++nf)                            \
    acc[mh][nh][mf][nf] = __builtin_amdgcn_mfma_f32_16x16x32_bf16(            \
        af[mf][kk], breg[nf][kk], acc[mh][nh][mf][nf], 0, 0, 0);              \
  __builtin_amdgcn_s_setprio(0);

#define G4_BAR_IN()                                                           \
  __builtin_amdgcn_s_barrier();                                               \
  asm volatile("s_waitcnt lgkmcnt(0)" ::: "memory");                          \
  __builtin_amdgcn_sched_barrier(0);

#define G4_BAR_OUT()                                                          \
  __builtin_amdgcn_sched_barrier(0);                                          \
  __builtin_amdgcn_s_barrier();

__global__ __launch_bounds__(512, 2) void gemm_g4_8ph(
    const unsigned short* __restrict__ A,      // obuf [1024][16384] bf16
    const unsigned short* __restrict__ W,      // Wob [7168][16384] bf16
    float* __restrict__ pbuf)                  // [8][1024][7168] fp32 partials
{
  __shared__ unsigned short S[65536];          // 128 KB
  const int t = threadIdx.x;
  const int l = t & 63, w = t >> 6;            // 8 waves
  const int r15 = l & 15, g = l >> 4;
  const int n0 = blockIdx.x * 256;
  const int m0 = blockIdx.y * 256;
  const int kbase = blockIdx.z * 2048;
  const int NT = 32;

  // glds: linear LDS dest, pre-swizzled global source (T2 both-sides, rule #21)
  const int lp = (l & 56) | ((l ^ (l >> 3)) & 7);
  const int srow = lp >> 3;                    // == l >> 3 (row unchanged)
  const int scol = (lp & 7) * 8;
  const int pr = (w >> 2) * 64;
  const int pc = (w & 3) * 32;

  f32x4 acc[2][2][4][2];
#pragma unroll
  for (int a0 = 0; a0 < 2; ++a0)
#pragma unroll
    for (int a1 = 0; a1 < 2; ++a1)
#pragma unroll
      for (int a2 = 0; a2 < 4; ++a2)
#pragma unroll
        for (int a3 = 0; a3 < 2; ++a3)
          acc[a0][a1][a2][a3] = (f32x4){0.f, 0.f, 0.f, 0.f};

  auto stage = [&](int tile, int which) {
    if (tile >= NT) return;
    const int k0 = kbase + tile * 64;
    const unsigned short* gb = (which < 2)
        ? A + (size_t)(m0 + which * 128) * 16384 + k0
        : W + (size_t)(n0 + (which - 2) * 128) * 16384 + k0;
    unsigned short* dst = S + (tile & 1) * 32768 + which * 8192;
#pragma unroll
    for (int i = 0; i < 2; ++i) {
      __builtin_amdgcn_global_load_lds(
          (const __attribute__((address_space(1))) void*)(gb + (size_t)((w * 2 + i) * 8 + srow) * 16384 + scol),
          (__attribute__((address_space(3))) void*)(dst + (w * 2 + i) * 512 + l * 8), 16, 0, 0);
    }
  };

  auto rdA = [&](int buf, int mh, int mf, int kk) -> bf16x8 {
    int row = pr + mf * 16 + r15;
    int L = row * 128 + kk * 64 + g * 16;
    L ^= ((L >> 7) & 7) << 4;
    return *(const bf16x8*)((const char*)S + buf * 65536 + mh * 16384 + L);
  };
  auto rdB = [&](int buf, int nh, int nf, int kk) -> bf16x8 {
    int row = pc + nf * 16 + r15;
    int L = row * 128 + kk * 64 + g * 16;
    L ^= ((L >> 7) & 7) << 4;
    return *(const bf16x8*)((const char*)S + buf * 65536 + (2 + nh) * 16384 + L);
  };

  bf16x8 af[4][2], bA[2][2], bB[2][2];

  stage(0, 0); stage(0, 1); stage(0, 2); stage(0, 3);
  stage(1, 0); stage(1, 2); stage(1, 3);
  __builtin_amdgcn_sched_barrier(0);
  asm volatile("s_waitcnt vmcnt(6)" ::: "memory");
  __builtin_amdgcn_sched_barrier(0);
  __builtin_amdgcn_s_barrier();

  for (int i = 0; i < 16; ++i) {
    const int tb = 2 * i;
    const bool last = (i == 15);
    // P1: (0,0) of tile tb (buf0)
    G4_DSREAD_A(0, 0)
    G4_DSREAD_B(0, 0, bA)
    stage(tb + 1, 1);
    G4_BAR_IN()
    G4_MFMA(0, 0, bA)
    G4_BAR_OUT()
    // P2: (0,1)
    G4_DSREAD_B(0, 1, bB)
    stage(tb + 2, 0);
    G4_BAR_IN()
    G4_MFMA(0, 1, bB)
    G4_BAR_OUT()
    // P3: (1,1)
    G4_DSREAD_A(0, 1)
    stage(tb + 2, 2);
    G4_BAR_IN()
    G4_MFMA(1, 1, bB)
    G4_BAR_OUT()
    // P4: (1,0)
    stage(tb + 2, 3);
    G4_BAR_IN()
    G4_MFMA(1, 0, bA)
    if (last) { asm volatile("s_waitcnt vmcnt(0)" ::: "memory"); }
    else      { asm volatile("s_waitcnt vmcnt(6)" ::: "memory"); }
    G4_BAR_OUT()
    // P5: (0,0) of tile tb+1 (buf1)
    G4_DSREAD_A(1, 0)
    G4_DSREAD_B(1, 0, bA)
    stage(tb + 2, 1);
    G4_BAR_IN()
    G4_MFMA(0, 0, bA)
    G4_BAR_OUT()
    // P6: (0,1)
    G4_DSREAD_B(1, 1, bB)
    stage(tb + 3, 0);
    G4_BAR_IN()
    G4_MFMA(0, 1, bB)
    G4_BAR_OUT()
    // P7: (1,1)
    G4_DSREAD_A(1, 1)
    stage(tb + 3, 2);
    G4_BAR_IN()
    G4_MFMA(1, 1, bB)
    G4_BAR_OUT()
    // P8: (1,0)
    stage(tb + 3, 3);
    G4_BAR_IN()
    G4_MFMA(1, 0, bA)
    if (last) { asm volatile("s_waitcnt vmcnt(0)" ::: "memory"); }
    else      { asm volatile("s_waitcnt vmcnt(6)" ::: "memory"); }
    G4_BAR_OUT()
  }

  float* Cp = pbuf + (size_t)blockIdx.z * 1024 * 7168;
#pragma unroll
  for (int mh = 0; mh < 2; ++mh)
#pragma unroll
    for (int nh = 0; nh < 2; ++nh)
#pragma unroll
      for (int mf = 0; mf < 4; ++mf)
#pragma unroll
        for (int nf = 0; nf < 2; ++nf) {
          int col = n0 + nh * 128 + pc + nf * 16 + r15;
#pragma unroll
          for (int r = 0; r < 4; ++r) {
            int row = m0 + mh * 128 + pr + mf * 16 + g * 4 + r;
            Cp[(size_t)row * 7168 + col] = acc[mh][nh][mf][nf][r];
          }
        }
}

// ---------------- split-K reductions ------------------------------------------
__global__ __launch_bounds__(256) void reduce_f32_kernel(
    const float* __restrict__ pbuf, const float* __restrict__ bias,
    float* __restrict__ out, int ldo, int rowlen4, int nz, size_t zstride, int total4)
{
  int idx = blockIdx.x * 256 + threadIdx.x;
  if (idx >= total4) return;
  int r = idx / rowlen4, c4 = idx % rowlen4;
  fl4 acc = *(const fl4*)(bias + c4 * 4);
  for (int z = 0; z < nz; ++z)
    acc += *(const fl4*)(pbuf + z * zstride + (size_t)idx * 4);
  *(fl4*)(out + (size_t)r * ldo + c4 * 4) = acc;
}

__global__ __launch_bounds__(256) void reduce_bf16_kernel(
    const float* __restrict__ pbuf, const float* __restrict__ bias,
    unsigned short* __restrict__ out, int ldo, int rowlen4, int nz, size_t zstride, int total4)
{
  int idx = blockIdx.x * 256 + threadIdx.x;
  if (idx >= total4) return;
  int r = idx / rowlen4, c4 = idx % rowlen4;
  fl4 acc = *(const fl4*)(bias + c4 * 4);
  for (int z = 0; z < nz; ++z)
    acc += *(const fl4*)(pbuf + z * zstride + (size_t)idx * 4);
  us4 u = { f2bf(acc[0]), f2bf(acc[1]), f2bf(acc[2]), f2bf(acc[3]) };
  *(us4*)(out + (size_t)r * ldo + c4 * 4) = u;
}

// ---------------- rope tables + table-based rope (k_r only) -------------------
__global__ __launch_bounds__(256) void rope_table_kernel(float* __restrict__ ctab,
                                                         float* __restrict__ stab) {
  int idx = blockIdx.x * 256 + threadIdx.x;
  if (idx >= S_LEN * 32) return;
  int j = idx & 31, s = idx >> 5;
  float invf = expf(-0.28782313662425574f * (float)j);
  float ang = (float)s * invf;
  ctab[idx] = cosf(ang);
  stab[idx] = sinf(ang);
}

__global__ void rope_bf16_kernel(unsigned short* __restrict__ x, int nh, int lda, int total,
                                 const float* __restrict__ ctab,
                                 const float* __restrict__ stab) {
  int idx = blockIdx.x * 256 + threadIdx.x;
  if (idx >= total) return;
  int j = idx & 31;
  int rest = idx >> 5;
  int hh = rest % nh;
  int s = rest / nh;
  float c = ctab[s * 32 + j], sn = stab[s * 32 + j];
  size_t base = (size_t)s * lda + hh * 64;
  float x1 = bf2f(x[base + j]), x2 = bf2f(x[base + j + 32]);
  x[base + j]      = f2bf(x1 * c - x2 * sn);
  x[base + j + 32] = f2bf(x2 * c + x1 * sn);
}

// ---------------- V transpose -------------------------------------------------
__global__ __launch_bounds__(256) void vtrans_kernel(
    const unsigned short* __restrict__ kvb, unsigned short* __restrict__ vt) {
  __shared__ unsigned short tl[64][72];
  const int s0 = blockIdx.x * 64;
  const int c0 = blockIdx.y * 64;
  const int t = threadIdx.x;
  const int rr = t >> 3, cc = (t & 7) * 8;
  const int hbase = (c0 >> 7) * 256 + 128 + (c0 & 127);
#pragma unroll
  for (int i = 0; i < 2; ++i) {
    int r = rr + i * 32;
    *reinterpret_cast<bf16x8*>(&tl[r][cc]) =
        *reinterpret_cast<const bf16x8*>(kvb + (size_t)(s0 + r) * 32768 + hbase + cc);
  }
  __syncthreads();
#pragma unroll
  for (int i = 0; i < 2; ++i) {
    int vc = rr + i * 32;
    unsigned short tmp[8];
#pragma unroll
    for (int j = 0; j < 8; ++j) tmp[j] = tl[cc + j][vc];
    *reinterpret_cast<bf16x8*>(&vt[(size_t)(c0 + vc) * 1024 + s0 + cc]) =
        *reinterpret_cast<bf16x8*>(tmp);
  }
}

// ---------------- flash attention: QBLK=128, 8 waves/block --------------------
__global__ __launch_bounds__(512) void mla_attn_kernel(
    const unsigned short* __restrict__ qcat,
    const unsigned short* __restrict__ kvb,
    const unsigned short* __restrict__ kr,
    const unsigned short* __restrict__ vt,
    unsigned short* __restrict__ obuf)
{
  __shared__ unsigned short Klds[64][200];
  __shared__ unsigned short Vlds[128][72];
  __shared__ unsigned short Plds[8][16][72];

  const int t = threadIdx.x;
  const int l = t & 63, w = t >> 6;
  const int r15 = l & 15, g = l >> 4;
  const int bid = blockIdx.x;
  const int orig = (bid & 7) * 128 + (bid >> 3);
  const int h = orig >> 3;
  const int q0 = (orig & 7) * 128;

  bf16x8 qf[6];
  const unsigned short* qrow = qcat + (size_t)(q0 + w * 16 + r15) * 24576;
#pragma unroll
  for (int kk = 0; kk < 4; ++kk)
    qf[kk] = *reinterpret_cast<const bf16x8*>(qrow + h * 128 + kk * 32 + 8 * g);
#pragma unroll
  for (int kk = 4; kk < 6; ++kk)
    qf[kk] = *reinterpret_cast<const bf16x8*>(qrow + 16384 + h * 64 + (kk - 4) * 32 + 8 * g);

  bf16x8 kreg[3], vreg[2];
  auto loadKV = [&](int kk0) {
#pragma unroll
    for (int i = 0; i < 3; ++i) {
      int c = t + 512 * i, row = c / 24, cb = c % 24;
      const unsigned short* src = (cb < 16)
          ? kvb + (size_t)(kk0 + row) * 32768 + h * 256 + cb * 8
          : kr + (size_t)(kk0 + row) * 2112 + (cb - 16) * 8;
      kreg[i] = *reinterpret_cast<const bf16x8*>(src);
    }
#pragma unroll
    for (int i = 0; i < 2; ++i) {
      int c = t + 512 * i, d = c >> 3, kb = c & 7;
      vreg[i] = *reinterpret_cast<const bf16x8*>(vt + ((size_t)h * 128 + d) * 1024 + kk0 + kb * 8);
    }
  };

  float m_r[4], l_r[4];
  f32x4 oacc[8];
#pragma unroll
  for (int r = 0; r < 4; ++r) { m_r[r] = -1e30f; l_r[r] = 0.f; }
#pragma unroll
  for (int d = 0; d < 8; ++d) oacc[d] = (f32x4){0.f, 0.f, 0.f, 0.f};

  loadKV(0);

  for (int kt = 0; kt < 16; ++kt) {
    __syncthreads();
#pragma unroll
    for (int i = 0; i < 3; ++i) {
      int c = t + 512 * i, row = c / 24, cb = c % 24;
      *reinterpret_cast<bf16x8*>(&Klds[row][cb * 8]) = kreg[i];
    }
#pragma unroll
    for (int i = 0; i < 2; ++i) {
      int c = t + 512 * i, d = c >> 3, kb = c & 7;
      *reinterpret_cast<bf16x8*>(&Vlds[d][kb * 8]) = vreg[i];
    }
    __syncthreads();
    if (kt < 15) loadKV((kt + 1) * 64);

    f32x4 sacc[4];
#pragma unroll
    for (int nt = 0; nt < 4; ++nt) sacc[nt] = (f32x4){0.f, 0.f, 0.f, 0.f};
    __builtin_amdgcn_s_setprio(1);
#pragma unroll
    for (int nt = 0; nt < 4; ++nt)
#pragma unroll
      for (int kk = 0; kk < 6; ++kk) {
        bf16x8 b = *reinterpret_cast<const bf16x8*>(&Klds[nt * 16 + r15][kk * 32 + 8 * g]);
        sacc[nt] = __builtin_amdgcn_mfma_f32_16x16x32_bf16(qf[kk], b, sacc[nt], 0, 0, 0);
      }
    __builtin_amdgcn_s_setprio(0);

    float sc[4], rsum[4];
#pragma unroll
    for (int r = 0; r < 4; ++r) {
      float mx = fmaxf(fmaxf(sacc[0][r], sacc[1][r]), fmaxf(sacc[2][r], sacc[3][r]));
      mx = fmaxf(mx, __shfl_xor(mx, 1));
      mx = fmaxf(mx, __shfl_xor(mx, 2));
      mx = fmaxf(mx, __shfl_xor(mx, 4));
      mx = fmaxf(mx, __shfl_xor(mx, 8));
      float mn = fmaxf(m_r[r], mx);
      sc[r] = __expf(m_r[r] - mn);
      m_r[r] = mn;
      rsum[r] = 0.f;
    }
#pragma unroll
    for (int nt = 0; nt < 4; ++nt)
#pragma unroll
      for (int r = 0; r < 4; ++r) {
        float p = __expf(sacc[nt][r] - m_r[r]);
        rsum[r] += p;
        Plds[w][g * 4 + r][nt * 16 + r15] = f2bf(p);
      }
#pragma unroll
    for (int r = 0; r < 4; ++r) {
      float s = rsum[r];
      s += __shfl_xor(s, 1);
      s += __shfl_xor(s, 2);
      s += __shfl_xor(s, 4);
      s += __shfl_xor(s, 8);
      l_r[r] = l_r[r] * sc[r] + s;
    }
#pragma unroll
    for (int d = 0; d < 8; ++d)
#pragma unroll
      for (int r = 0; r < 4; ++r) oacc[d][r] *= sc[r];

    bf16x8 pa0 = *reinterpret_cast<const bf16x8*>(&Plds[w][r15][8 * g]);
    bf16x8 pa1 = *reinterpret_cast<const bf16x8*>(&Plds[w][r15][32 + 8 * g]);
    __builtin_amdgcn_s_setprio(1);
#pragma unroll
    for (int dt = 0; dt < 8; ++dt) {
      bf16x8 v0 = *reinterpret_cast<const bf16x8*>(&Vlds[dt * 16 + r15][8 * g]);
      bf16x8 v1 = *reinterpret_cast<const bf16x8*>(&Vlds[dt * 16 + r15][32 + 8 * g]);
      oacc[dt] = __builtin_amdgcn_mfma_f32_16x16x32_bf16(pa0, v0, oacc[dt], 0, 0, 0);
      oacc[dt] = __builtin_amdgcn_mfma_f32_16x16x32_bf16(pa1, v1, oacc[dt], 0, 0, 0);
    }
    __builtin_amdgcn_s_setprio(0);
  }

#pragma unroll
  for (int dt = 0; dt < 8; ++dt)
#pragma unroll
    for (int r = 0; r < 4; ++r) {
      int row = q0 + w * 16 + g * 4 + r;
      int col = h * DH + dt * 16 + r15;
      obuf[(size_t)row * 16384 + col] = f2bf(oacc[dt][r] / l_r[r]);
    }
}

// ------------------------------------------------------------------------------
extern "C" void kernel_launch(void* const* d_in, const int* in_sizes, int n_in,
                              void* d_out, int out_size, void* d_ws, size_t ws_size,
                              hipStream_t stream) {
  const float* h    = (const float*)d_in[0];
  const float* Wdq  = (const float*)d_in[1];
  const float* bdq  = (const float*)d_in[2];
  const float* Wdkv = (const float*)d_in[3];
  const float* bdkv = (const float*)d_in[4];
  const float* Wuq  = (const float*)d_in[5];
  const float* buq  = (const float*)d_in[6];
  const float* Wukv = (const float*)d_in[7];
  const float* bukv = (const float*)d_in[8];
  const float* Wrq  = (const float*)d_in[9];
  const float* brq  = (const float*)d_in[10];
  const float* Wrk  = (const float*)d_in[11];
  const float* brk  = (const float*)d_in[12];
  const float* Wo   = (const float*)d_in[13];
  const float* bo   = (const float*)d_in[14];
  float* out = (float*)d_out;

  char* ws = (char*)d_ws;
  size_t off = 0;
  auto alloc = [&](size_t bytes) {
    char* p = ws + off;
    off += (bytes + 255) & ~(size_t)255;
    return p;
  };
  unsigned short* hb    = (unsigned short*)alloc((size_t)1024 * 7168 * 2);
  unsigned short* W1cat = (unsigned short*)alloc((size_t)2176 * 7168 * 2);
  float*          b1cat = (float*)alloc(2176 * 4);
  float*          b2cat = (float*)alloc(24576 * 4);
  unsigned short* ccat  = (unsigned short*)alloc((size_t)1024 * 2112 * 2);
  unsigned short* qcat  = (unsigned short*)alloc((size_t)1024 * 24576 * 2);
  unsigned short* kvbb  = (unsigned short*)alloc((size_t)1024 * 32768 * 2);
  unsigned short* vt    = (unsigned short*)alloc((size_t)16384 * 1024 * 2);
  unsigned short* obuf  = (unsigned short*)alloc((size_t)1024 * 16384 * 2);
  float*          ctab  = (float*)alloc((size_t)S_LEN * 32 * 4);
  float*          stab  = (float*)alloc((size_t)S_LEN * 32 * 4);
  unsigned short* Wukvb = (unsigned short*)alloc((size_t)32768 * 512 * 2);
  // G1 split-K partials alias not-yet-written qcat (34.6 MB < 50.3 MB)
  float* pbufG1 = (float*)qcat;
  // d_ws ~1.8 GB: Wob (bf16 Wo, 235 MB) @ 288 MiB; pbufG4 (235 MB) @ 544 MiB
  unsigned short* Wob    = (unsigned short*)(ws + ((size_t)288 << 20));
  float*          pbufG4 = (float*)(ws + ((size_t)544 << 20));

  auto cvt = [&](const float* in, unsigned short* outp, size_t n) {
    int n8 = (int)(n / 8);
    int blocks = (n8 + 255) / 256;
    if (blocks > 2048) blocks = 2048;
    cvt_bf16_kernel<<<blocks, 256, 0, stream>>>(in, outp, n8);
  };

  // --- conversions for h, W1cat, Wukv ---
  cvt(h,    hb,    (size_t)1024 * 7168);
  cvt(Wdq,  W1cat, (size_t)1536 * 7168);
  cvt(Wdkv, W1cat + (size_t)1536 * 7168, (size_t)512 * 7168);
  cvt(Wrk,  W1cat + (size_t)2048 * 7168, (size_t)64 * 7168);
  cvt(Wukv, Wukvb, (size_t)32768 * 512);
  hipMemsetAsync(W1cat + (size_t)2112 * 7168, 0, (size_t)64 * 7168 * 2, stream);
  hipMemcpyAsync(b1cat,        bdq,  1536 * 4, hipMemcpyDeviceToDevice, stream);
  hipMemcpyAsync(b1cat + 1536, bdkv, 512 * 4,  hipMemcpyDeviceToDevice, stream);
  hipMemcpyAsync(b1cat + 2048, brk,  64 * 4,   hipMemcpyDeviceToDevice, stream);
  hipMemsetAsync(b1cat + 2112, 0, 64 * 4, stream);
  hipMemcpyAsync(b2cat,         buq, 16384 * 4, hipMemcpyDeviceToDevice, stream);
  hipMemcpyAsync(b2cat + 16384, brq, 8192 * 4,  hipMemcpyDeviceToDevice, stream);
  rope_table_kernel<<<(S_LEN * 32 + 255) / 256, 256, 0, stream>>>(ctab, stab);

  const float scale = 0.07216878364870323f;   // 1/sqrt(192)
  const int BIGN = 1 << 30;
  dim3 blk(256);

  // G1 (split-K=4, bf16 W): partials = h @ W1cat^T
  gemm_k<2, 0><<<dim3(24, 8, 4), blk, 0, stream>>>(
      hb, 7168, W1cat, nullptr, nullptr, BIGN, 7168, nullptr,
      pbufG1, 2112, (size_t)1024 * 2112, 2112, 1792, 1.0f);
  reduce_bf16_kernel<<<2112, blk, 0, stream>>>(pbufG1, b1cat, ccat, 2112, 528, 4,
                                               (size_t)1024 * 2112, 1024 * 2112 / 4);
  rope_bf16_kernel<<<(1024 * 32 + 255) / 256, blk, 0, stream>>>(ccat + 2048, 1, 2112, 1024 * 32, ctab, stab);

  // G2 (fp32 W direct, counted-vmcnt pipeline, fused q_r RoPE):
  gemm_k<1, 1, 1><<<dim3(192, 8, 1), blk, 0, stream>>>(
      ccat, 2112, nullptr, Wuq, Wrq, 16384, 1536, b2cat,
      qcat, 24576, 0, 24576, 1536, scale, ctab, stab);

  // G3 (bf16 W via glds — K=512 too short for the fp32 pipeline):
  gemm_k<1, 0><<<dim3(256, 8, 1), blk, 0, stream>>>(
      ccat + 1536, 2112, Wukvb, nullptr, nullptr, BIGN, 512, bukv,
      kvbb, 32768, 0, 32768, 512, 1.0f);
  vtrans_kernel<<<dim3(16, 256), blk, 0, stream>>>(kvbb, vt);
  mla_attn_kernel<<<dim3(1024), dim3(512), 0, stream>>>(qcat, kvbb, ccat + 2048, vt, obuf);

  // G4: cvt Wo -> bf16 once, 8-phase 256^2 GEMM (split-K=8), reduce.
  cvt(Wo, Wob, (size_t)7168 * 16384);
  gemm_g4_8ph<<<dim3(28, 4, 8), dim3(512), 0, stream>>>(obuf, Wob, pbufG4);
  reduce_f32_kernel<<<7168, blk, 0, stream>>>(pbufG4, bo, out,
                                              7168, 1792, 8, (size_t)1024 * 7168, 1024 * 7168 / 4);
}

// Round 18
// 976.204 us; speedup vs baseline: 1.2594x; 1.0510x over previous
//
#include <hip/hip_runtime.h>
#include <hip/hip_bf16.h>

#define S_LEN 1024
#define HID 7168
#define NH 128
#define DQ 1536
#define DKV 512
#define DH 128
#define DR 64

typedef __attribute__((ext_vector_type(8))) short bf16x8;
typedef __attribute__((ext_vector_type(4))) float f32x4;
typedef __attribute__((ext_vector_type(4))) float fl4;
typedef __attribute__((ext_vector_type(4))) unsigned short us4;
typedef __attribute__((ext_vector_type(8))) unsigned short us8;
typedef __attribute__((ext_vector_type(4))) unsigned int u32x4;

static __device__ __forceinline__ unsigned short f2bf(float f) {
  union { float f; unsigned int u; } v; v.f = f;
  unsigned int u = v.u;
  return (unsigned short)((u + 0x7fffu + ((u >> 16) & 1u)) >> 16);
}
static __device__ __forceinline__ float bf2f(unsigned short u) {
  union { unsigned int u; float f; } v; v.u = ((unsigned int)u) << 16;
  return v.f;
}
static __device__ __forceinline__ unsigned int cvtpk2(float lo, float hi) {
  unsigned int r;
  asm("v_cvt_pk_bf16_f32 %0, %1, %2" : "=v"(r) : "v"(lo), "v"(hi));
  return r;
}

// ---------------- fp32 -> bf16 conversion -------------------------------------
__global__ __launch_bounds__(256) void cvt_bf16_kernel(
    const float* __restrict__ in, unsigned short* __restrict__ out, int n8) {
  int i = blockIdx.x * 256 + threadIdx.x;
  int stride = gridDim.x * 256;
  for (; i < n8; i += stride) {
    fl4 a = ((const fl4*)in)[2 * i];
    fl4 b = ((const fl4*)in)[2 * i + 1];
    us8 u = { f2bf(a[0]), f2bf(a[1]), f2bf(a[2]), f2bf(a[3]),
              f2bf(b[0]), f2bf(b[1]), f2bf(b[2]), f2bf(b[3]) };
    ((us8*)out)[i] = u;
  }
}

// ---------------- bf16 GEMM (m97 structure, counted-vmcnt WFP32) --------------
template <int OUTMODE, int WFP32, int ROPEQ = 0>
__global__ __launch_bounds__(256) void gemm_k(
    const unsigned short* __restrict__ A, int lda,
    const unsigned short* __restrict__ Wb16,
    const float* __restrict__ Wfa, const float* __restrict__ Wfb, int nsplit,
    int ldw,
    const float* __restrict__ bias,
    void* __restrict__ Cv, int ldc, size_t zstride,
    int Ncl, int ksl, float alpha,
    const float* __restrict__ ctab = nullptr,
    const float* __restrict__ stab = nullptr)
{
  const int n0 = blockIdx.x * 128;
  if (n0 >= Ncl) return;

  __shared__ unsigned short As[128 * 64];
  __shared__ unsigned short Ws[128 * 64];
  const int t = threadIdx.x;
  const int l = t & 63, w = t >> 6;
  const int r15 = l & 15, g = l >> 4;
  const int wm = (w >> 1) * 64, wn = (w & 1) * 64;
  const int m0 = blockIdx.y * 128;
  const int kbase = blockIdx.z * ksl;
  const int srow = l >> 3;
  const int scol = (l & 7) * 8;

  f32x4 acc[4][4];
#pragma unroll
  for (int i = 0; i < 4; ++i)
#pragma unroll
    for (int j = 0; j < 4; ++j) acc[i][j] = (f32x4){0.f, 0.f, 0.f, 0.f};

  const unsigned short* Ab = A + (size_t)m0 * lda;
  const unsigned short* Wb = nullptr;
  const float* Wf = nullptr;
  if constexpr (WFP32) {
    Wf = (n0 < nsplit) ? Wfa + (size_t)n0 * ldw : Wfb + (size_t)(n0 - nsplit) * ldw;
  } else {
    Wb = Wb16 + (size_t)n0 * ldw;
  }

  fl4 wx[4], wy[4];
  auto issueW = [&](int k0) {
#pragma unroll
    for (int i = 0; i < 4; ++i) {
      int c = t + 256 * i;
      const float* src = Wf + (size_t)(c >> 3) * ldw + k0 + (c & 7) * 8;
      wx[i] = *(const fl4*)src;
      wy[i] = *(const fl4*)(src + 4);
    }
  };

  if constexpr (WFP32) issueW(kbase);
  const int kend = kbase + ksl;

  for (int k0 = kbase; k0 < kend; k0 += 64) {
    if constexpr (WFP32) {
      __builtin_amdgcn_s_barrier();
      __builtin_amdgcn_sched_barrier(0);
    } else {
      __syncthreads();
    }
#pragma unroll
    for (int i = 0; i < 4; ++i) {
      int chunk = w * 4 + i;
      int row = chunk * 8 + srow;
      __builtin_amdgcn_global_load_lds(
          (const __attribute__((address_space(1))) void*)(Ab + (size_t)row * lda + k0 + scol),
          (__attribute__((address_space(3))) void*)(As + chunk * 512), 16, 0, 0);
      if constexpr (!WFP32) {
        __builtin_amdgcn_global_load_lds(
            (const __attribute__((address_space(1))) void*)(Wb + (size_t)row * ldw + k0 + scol),
            (__attribute__((address_space(3))) void*)(Ws + chunk * 512), 16, 0, 0);
      }
    }
    if constexpr (WFP32) {
      __builtin_amdgcn_sched_barrier(0);
      asm volatile("s_waitcnt vmcnt(4)" ::: "memory");
      __builtin_amdgcn_sched_barrier(0);
#pragma unroll
      for (int i = 0; i < 4; ++i) {
        int c = t + 256 * i;
        u32x4 p = { cvtpk2(wx[i][0], wx[i][1]), cvtpk2(wx[i][2], wx[i][3]),
                    cvtpk2(wy[i][0], wy[i][1]), cvtpk2(wy[i][2], wy[i][3]) };
        ((u32x4*)Ws)[c] = p;
      }
      if (k0 + 64 < kend) {
        issueW(k0 + 64);
        __builtin_amdgcn_sched_barrier(0);
        asm volatile("s_waitcnt vmcnt(8) lgkmcnt(0)" ::: "memory");
      } else {
        asm volatile("s_waitcnt vmcnt(0) lgkmcnt(0)" ::: "memory");
      }
      __builtin_amdgcn_sched_barrier(0);
      __builtin_amdgcn_s_barrier();
    } else {
      __syncthreads();
    }
#pragma unroll
    for (int kk = 0; kk < 2; ++kk) {
      bf16x8 a[4], b[4];
#pragma unroll
      for (int mt = 0; mt < 4; ++mt)
        a[mt] = *reinterpret_cast<const bf16x8*>(&As[(wm + mt * 16 + r15) * 64 + kk * 32 + 8 * g]);
#pragma unroll
      for (int nt = 0; nt < 4; ++nt)
        b[nt] = *reinterpret_cast<const bf16x8*>(&Ws[(wn + nt * 16 + r15) * 64 + kk * 32 + 8 * g]);
#pragma unroll
      for (int mt = 0; mt < 4; ++mt)
#pragma unroll
        for (int nt = 0; nt < 4; ++nt)
          acc[mt][nt] = __builtin_amdgcn_mfma_f32_16x16x32_bf16(a[mt], b[nt], acc[mt][nt], 0, 0, 0);
    }
  }

  if constexpr (OUTMODE == 1) {
    float bv[4];
#pragma unroll
    for (int nt = 0; nt < 4; ++nt) {
      int col = n0 + wn + nt * 16 + r15;
      bv[nt] = (col < Ncl) ? bias[col] : 0.f;
    }
    bool isrope = false;
    if constexpr (ROPEQ) isrope = (n0 + wn) >= 16384;
    if (ROPEQ && isrope) {
#pragma unroll
      for (int mt = 0; mt < 4; ++mt)
#pragma unroll
        for (int r = 0; r < 4; ++r) {
          int row = m0 + wm + mt * 16 + g * 4 + r;
#pragma unroll
          for (int ntp = 0; ntp < 2; ++ntp) {
            int j = ntp * 16 + r15;
            float c = ctab[row * 32 + j];
            float s = stab[row * 32 + j];
            float x1 = acc[mt][ntp][r] + bv[ntp];
            float x2 = acc[mt][ntp + 2][r] + bv[ntp + 2];
            int col1 = n0 + wn + ntp * 16 + r15;
            ((unsigned short*)Cv)[(size_t)row * ldc + col1] =
                f2bf((x1 * c - x2 * s) * alpha);
            ((unsigned short*)Cv)[(size_t)row * ldc + col1 + 32] =
                f2bf((x2 * c + x1 * s) * alpha);
          }
        }
    } else {
#pragma unroll
      for (int mt = 0; mt < 4; ++mt)
#pragma unroll
        for (int nt = 0; nt < 4; ++nt) {
          int col = n0 + wn + nt * 16 + r15;
          if (col < Ncl) {
#pragma unroll
            for (int r = 0; r < 4; ++r) {
              int row = m0 + wm + mt * 16 + g * 4 + r;
              ((unsigned short*)Cv)[(size_t)row * ldc + col] =
                  f2bf((acc[mt][nt][r] + bv[nt]) * alpha);
            }
          }
        }
    }
  } else {
    float* Cp = (float*)Cv + blockIdx.z * zstride;
#pragma unroll
    for (int mt = 0; mt < 4; ++mt)
#pragma unroll
      for (int nt = 0; nt < 4; ++nt) {
        int col = n0 + wn + nt * 16 + r15;
        if (col < Ncl) {
#pragma unroll
          for (int r = 0; r < 4; ++r) {
            int row = m0 + wm + mt * 16 + g * 4 + r;
            Cp[(size_t)row * ldc + col] = acc[mt][nt][r];
          }
        }
      }
  }
}

// ---------------- G4: 8-phase 256x256 template (T2+T3+T4+T5), split-K=4 -------
#define G4_DSREAD_A(buf, mh)                                                  \
  _Pragma("unroll") for (int mf = 0; mf < 4; ++mf)                            \
  _Pragma("unroll") for (int kk = 0; kk < 2; ++kk)                            \
    af[mf][kk] = rdA(buf, mh, mf, kk);

#define G4_DSREAD_B(buf, nh, breg)                                            \
  _Pragma("unroll") for (int nf = 0; nf < 2; ++nf)                            \
  _Pragma("unroll") for (int kk = 0; kk < 2; ++kk)                            \
    breg[nf][kk] = rdB(buf, nh, nf, kk);

#define G4_MFMA(mh, nh, breg)                                                 \
  __builtin_amdgcn_s_setprio(1);                                              \
  _Pragma("unroll") for (int kk = 0; kk < 2; ++kk)                            \
  _Pragma("unroll") for (int mf = 0; mf < 4; ++mf)                            \
  _Pragma("unroll") for (int nf = 0; nf < 2; ++nf)                            \
    acc[mh][nh][mf][nf] = __builtin_amdgcn_mfma_f32_16x16x32_bf16(            \
        af[mf][kk], breg[nf][kk], acc[mh][nh][mf][nf], 0, 0, 0);              \
  __builtin_amdgcn_s_setprio(0);

#define G4_BAR_IN()                                                           \
  __builtin_amdgcn_s_barrier();                                               \
  asm volatile("s_waitcnt lgkmcnt(0)" ::: "memory");                          \
  __builtin_amdgcn_sched_barrier(0);

#define G4_BAR_OUT()                                                          \
  __builtin_amdgcn_sched_barrier(0);                                          \
  __builtin_amdgcn_s_barrier();

__global__ __launch_bounds__(512, 2) void gemm_g4_8ph(
    const unsigned short* __restrict__ A,      // obuf [1024][16384] bf16
    const unsigned short* __restrict__ W,      // Wob [7168][16384] bf16
    float* __restrict__ pbuf)                  // [4][1024][7168] fp32 partials
{
  __shared__ unsigned short S[65536];          // 128 KB
  const int t = threadIdx.x;
  const int l = t & 63, w = t >> 6;            // 8 waves
  const int r15 = l & 15, g = l >> 4;
  const int n0 = blockIdx.x * 256;
  const int m0 = blockIdx.y * 256;
  const int kbase = blockIdx.z * 4096;
  const int NT = 64;

  const int lp = (l & 56) | ((l ^ (l >> 3)) & 7);
  const int srow = lp >> 3;
  const int scol = (lp & 7) * 8;
  const int pr = (w >> 2) * 64;
  const int pc = (w & 3) * 32;

  f32x4 acc[2][2][4][2];
#pragma unroll
  for (int a0 = 0; a0 < 2; ++a0)
#pragma unroll
    for (int a1 = 0; a1 < 2; ++a1)
#pragma unroll
      for (int a2 = 0; a2 < 4; ++a2)
#pragma unroll
        for (int a3 = 0; a3 < 2; ++a3)
          acc[a0][a1][a2][a3] = (f32x4){0.f, 0.f, 0.f, 0.f};

  auto stage = [&](int tile, int which) {
    if (tile >= NT) return;
    const int k0 = kbase + tile * 64;
    const unsigned short* gb = (which < 2)
        ? A + (size_t)(m0 + which * 128) * 16384 + k0
        : W + (size_t)(n0 + (which - 2) * 128) * 16384 + k0;
    unsigned short* dst = S + (tile & 1) * 32768 + which * 8192;
#pragma unroll
    for (int i = 0; i < 2; ++i) {
      __builtin_amdgcn_global_load_lds(
          (const __attribute__((address_space(1))) void*)(gb + (size_t)((w * 2 + i) * 8 + srow) * 16384 + scol),
          (__attribute__((address_space(3))) void*)(dst + (w * 2 + i) * 512 + l * 8), 16, 0, 0);
    }
  };

  auto rdA = [&](int buf, int mh, int mf, int kk) -> bf16x8 {
    int row = pr + mf * 16 + r15;
    int L = row * 128 + kk * 64 + g * 16;
    L ^= ((L >> 7) & 7) << 4;
    return *(const bf16x8*)((const char*)S + buf * 65536 + mh * 16384 + L);
  };
  auto rdB = [&](int buf, int nh, int nf, int kk) -> bf16x8 {
    int row = pc + nf * 16 + r15;
    int L = row * 128 + kk * 64 + g * 16;
    L ^= ((L >> 7) & 7) << 4;
    return *(const bf16x8*)((const char*)S + buf * 65536 + (2 + nh) * 16384 + L);
  };

  bf16x8 af[4][2], bA[2][2], bB[2][2];

  stage(0, 0); stage(0, 1); stage(0, 2); stage(0, 3);
  stage(1, 0); stage(1, 2); stage(1, 3);
  __builtin_amdgcn_sched_barrier(0);
  asm volatile("s_waitcnt vmcnt(6)" ::: "memory");
  __builtin_amdgcn_sched_barrier(0);
  __builtin_amdgcn_s_barrier();

  for (int i = 0; i < 32; ++i) {
    const int tb = 2 * i;
    const bool last = (i == 31);
    // P1: (0,0) of tile tb (buf0)
    G4_DSREAD_A(0, 0)
    G4_DSREAD_B(0, 0, bA)
    stage(tb + 1, 1);
    G4_BAR_IN()
    G4_MFMA(0, 0, bA)
    G4_BAR_OUT()
    // P2: (0,1)
    G4_DSREAD_B(0, 1, bB)
    stage(tb + 2, 0);
    G4_BAR_IN()
    G4_MFMA(0, 1, bB)
    G4_BAR_OUT()
    // P3: (1,1)
    G4_DSREAD_A(0, 1)
    stage(tb + 2, 2);
    G4_BAR_IN()
    G4_MFMA(1, 1, bB)
    G4_BAR_OUT()
    // P4: (1,0)
    stage(tb + 2, 3);
    G4_BAR_IN()
    G4_MFMA(1, 0, bA)
    if (last) { asm volatile("s_waitcnt vmcnt(0)" ::: "memory"); }
    else      { asm volatile("s_waitcnt vmcnt(6)" ::: "memory"); }
    G4_BAR_OUT()
    // P5: (0,0) of tile tb+1 (buf1)
    G4_DSREAD_A(1, 0)
    G4_DSREAD_B(1, 0, bA)
    stage(tb + 2, 1);
    G4_BAR_IN()
    G4_MFMA(0, 0, bA)
    G4_BAR_OUT()
    // P6: (0,1)
    G4_DSREAD_B(1, 1, bB)
    stage(tb + 3, 0);
    G4_BAR_IN()
    G4_MFMA(0, 1, bB)
    G4_BAR_OUT()
    // P7: (1,1)
    G4_DSREAD_A(1, 1)
    stage(tb + 3, 2);
    G4_BAR_IN()
    G4_MFMA(1, 1, bB)
    G4_BAR_OUT()
    // P8: (1,0)
    stage(tb + 3, 3);
    G4_BAR_IN()
    G4_MFMA(1, 0, bA)
    if (last) { asm volatile("s_waitcnt vmcnt(0)" ::: "memory"); }
    else      { asm volatile("s_waitcnt vmcnt(6)" ::: "memory"); }
    G4_BAR_OUT()
  }

  float* Cp = pbuf + (size_t)blockIdx.z * 1024 * 7168;
#pragma unroll
  for (int mh = 0; mh < 2; ++mh)
#pragma unroll
    for (int nh = 0; nh < 2; ++nh)
#pragma unroll
      for (int mf = 0; mf < 4; ++mf)
#pragma unroll
        for (int nf = 0; nf < 2; ++nf) {
          int col = n0 + nh * 128 + pc + nf * 16 + r15;
#pragma unroll
          for (int r = 0; r < 4; ++r) {
            int row = m0 + mh * 128 + pr + mf * 16 + g * 4 + r;
            Cp[(size_t)row * 7168 + col] = acc[mh][nh][mf][nf][r];
          }
        }
}

// ---------------- split-K reductions ------------------------------------------
__global__ __launch_bounds__(256) void reduce_f32_kernel(
    const float* __restrict__ pbuf, const float* __restrict__ bias,
    float* __restrict__ out, int ldo, int rowlen4, int nz, size_t zstride, int total4)
{
  int idx = blockIdx.x * 256 + threadIdx.x;
  if (idx >= total4) return;
  int r = idx / rowlen4, c4 = idx % rowlen4;
  fl4 acc = *(const fl4*)(bias + c4 * 4);
  for (int z = 0; z < nz; ++z)
    acc += *(const fl4*)(pbuf + z * zstride + (size_t)idx * 4);
  *(fl4*)(out + (size_t)r * ldo + c4 * 4) = acc;
}

__global__ __launch_bounds__(256) void reduce_bf16_kernel(
    const float* __restrict__ pbuf, const float* __restrict__ bias,
    unsigned short* __restrict__ out, int ldo, int rowlen4, int nz, size_t zstride, int total4)
{
  int idx = blockIdx.x * 256 + threadIdx.x;
  if (idx >= total4) return;
  int r = idx / rowlen4, c4 = idx % rowlen4;
  fl4 acc = *(const fl4*)(bias + c4 * 4);
  for (int z = 0; z < nz; ++z)
    acc += *(const fl4*)(pbuf + z * zstride + (size_t)idx * 4);
  us4 u = { f2bf(acc[0]), f2bf(acc[1]), f2bf(acc[2]), f2bf(acc[3]) };
  *(us4*)(out + (size_t)r * ldo + c4 * 4) = u;
}

// ---------------- rope tables + table-based rope (k_r only) -------------------
__global__ __launch_bounds__(256) void rope_table_kernel(float* __restrict__ ctab,
                                                         float* __restrict__ stab) {
  int idx = blockIdx.x * 256 + threadIdx.x;
  if (idx >= S_LEN * 32) return;
  int j = idx & 31, s = idx >> 5;
  float invf = expf(-0.28782313662425574f * (float)j);
  float ang = (float)s * invf;
  ctab[idx] = cosf(ang);
  stab[idx] = sinf(ang);
}

__global__ void rope_bf16_kernel(unsigned short* __restrict__ x, int nh, int lda, int total,
                                 const float* __restrict__ ctab,
                                 const float* __restrict__ stab) {
  int idx = blockIdx.x * 256 + threadIdx.x;
  if (idx >= total) return;
  int j = idx & 31;
  int rest = idx >> 5;
  int hh = rest % nh;
  int s = rest / nh;
  float c = ctab[s * 32 + j], sn = stab[s * 32 + j];
  size_t base = (size_t)s * lda + hh * 64;
  float x1 = bf2f(x[base + j]), x2 = bf2f(x[base + j + 32]);
  x[base + j]      = f2bf(x1 * c - x2 * sn);
  x[base + j + 32] = f2bf(x2 * c + x1 * sn);
}

// ---------------- V transpose -------------------------------------------------
__global__ __launch_bounds__(256) void vtrans_kernel(
    const unsigned short* __restrict__ kvb, unsigned short* __restrict__ vt) {
  __shared__ unsigned short tl[64][72];
  const int s0 = blockIdx.x * 64;
  const int c0 = blockIdx.y * 64;
  const int t = threadIdx.x;
  const int rr = t >> 3, cc = (t & 7) * 8;
  const int hbase = (c0 >> 7) * 256 + 128 + (c0 & 127);
#pragma unroll
  for (int i = 0; i < 2; ++i) {
    int r = rr + i * 32;
    *reinterpret_cast<bf16x8*>(&tl[r][cc]) =
        *reinterpret_cast<const bf16x8*>(kvb + (size_t)(s0 + r) * 32768 + hbase + cc);
  }
  __syncthreads();
#pragma unroll
  for (int i = 0; i < 2; ++i) {
    int vc = rr + i * 32;
    unsigned short tmp[8];
#pragma unroll
    for (int j = 0; j < 8; ++j) tmp[j] = tl[cc + j][vc];
    *reinterpret_cast<bf16x8*>(&vt[(size_t)(c0 + vc) * 1024 + s0 + cc]) =
        *reinterpret_cast<bf16x8*>(tmp);
  }
}

// ---------------- flash attention: QBLK=128, 8 waves, T13 defer-max -----------
__global__ __launch_bounds__(512) void mla_attn_kernel(
    const unsigned short* __restrict__ qcat,
    const unsigned short* __restrict__ kvb,
    const unsigned short* __restrict__ kr,
    const unsigned short* __restrict__ vt,
    unsigned short* __restrict__ obuf)
{
  __shared__ unsigned short Klds[64][200];
  __shared__ unsigned short Vlds[128][72];
  __shared__ unsigned short Plds[8][16][72];

  const int t = threadIdx.x;
  const int l = t & 63, w = t >> 6;
  const int r15 = l & 15, g = l >> 4;
  const int bid = blockIdx.x;
  const int orig = (bid & 7) * 128 + (bid >> 3);
  const int h = orig >> 3;
  const int q0 = (orig & 7) * 128;

  bf16x8 qf[6];
  const unsigned short* qrow = qcat + (size_t)(q0 + w * 16 + r15) * 24576;
#pragma unroll
  for (int kk = 0; kk < 4; ++kk)
    qf[kk] = *reinterpret_cast<const bf16x8*>(qrow + h * 128 + kk * 32 + 8 * g);
#pragma unroll
  for (int kk = 4; kk < 6; ++kk)
    qf[kk] = *reinterpret_cast<const bf16x8*>(qrow + 16384 + h * 64 + (kk - 4) * 32 + 8 * g);

  bf16x8 kreg[3], vreg[2];
  auto loadKV = [&](int kk0) {
#pragma unroll
    for (int i = 0; i < 3; ++i) {
      int c = t + 512 * i, row = c / 24, cb = c % 24;
      const unsigned short* src = (cb < 16)
          ? kvb + (size_t)(kk0 + row) * 32768 + h * 256 + cb * 8
          : kr + (size_t)(kk0 + row) * 2112 + (cb - 16) * 8;
      kreg[i] = *reinterpret_cast<const bf16x8*>(src);
    }
#pragma unroll
    for (int i = 0; i < 2; ++i) {
      int c = t + 512 * i, d = c >> 3, kb = c & 7;
      vreg[i] = *reinterpret_cast<const bf16x8*>(vt + ((size_t)h * 128 + d) * 1024 + kk0 + kb * 8);
    }
  };

  float m_r[4], l_r[4];
  f32x4 oacc[8];
#pragma unroll
  for (int r = 0; r < 4; ++r) { m_r[r] = -1e30f; l_r[r] = 0.f; }
#pragma unroll
  for (int d = 0; d < 8; ++d) oacc[d] = (f32x4){0.f, 0.f, 0.f, 0.f};

  loadKV(0);

  for (int kt = 0; kt < 16; ++kt) {
    __syncthreads();
#pragma unroll
    for (int i = 0; i < 3; ++i) {
      int c = t + 512 * i, row = c / 24, cb = c % 24;
      *reinterpret_cast<bf16x8*>(&Klds[row][cb * 8]) = kreg[i];
    }
#pragma unroll
    for (int i = 0; i < 2; ++i) {
      int c = t + 512 * i, d = c >> 3, kb = c & 7;
      *reinterpret_cast<bf16x8*>(&Vlds[d][kb * 8]) = vreg[i];
    }
    __syncthreads();
    if (kt < 15) loadKV((kt + 1) * 64);

    f32x4 sacc[4];
#pragma unroll
    for (int nt = 0; nt < 4; ++nt) sacc[nt] = (f32x4){0.f, 0.f, 0.f, 0.f};
    __builtin_amdgcn_s_setprio(1);
#pragma unroll
    for (int nt = 0; nt < 4; ++nt)
#pragma unroll
      for (int kk = 0; kk < 6; ++kk) {
        bf16x8 b = *reinterpret_cast<const bf16x8*>(&Klds[nt * 16 + r15][kk * 32 + 8 * g]);
        sacc[nt] = __builtin_amdgcn_mfma_f32_16x16x32_bf16(qf[kk], b, sacc[nt], 0, 0, 0);
      }
    __builtin_amdgcn_s_setprio(0);

    // online softmax with T13 defer-max (skip rescale when growth <= 8)
    float mx[4];
#pragma unroll
    for (int r = 0; r < 4; ++r) {
      float m = fmaxf(fmaxf(sacc[0][r], sacc[1][r]), fmaxf(sacc[2][r], sacc[3][r]));
      m = fmaxf(m, __shfl_xor(m, 1));
      m = fmaxf(m, __shfl_xor(m, 2));
      m = fmaxf(m, __shfl_xor(m, 4));
      m = fmaxf(m, __shfl_xor(m, 8));
      mx[r] = m;
    }
    float grow = fmaxf(fmaxf(mx[0] - m_r[0], mx[1] - m_r[1]),
                       fmaxf(mx[2] - m_r[2], mx[3] - m_r[3]));
    if (__any(grow > 8.0f)) {
      float sc[4];
#pragma unroll
      for (int r = 0; r < 4; ++r) {
        float mn = fmaxf(m_r[r], mx[r]);
        sc[r] = __expf(m_r[r] - mn);
        m_r[r] = mn;
        l_r[r] *= sc[r];
      }
#pragma unroll
      for (int d = 0; d < 8; ++d)
#pragma unroll
        for (int r = 0; r < 4; ++r) oacc[d][r] *= sc[r];
    }
    float rsum[4] = {0.f, 0.f, 0.f, 0.f};
#pragma unroll
    for (int nt = 0; nt < 4; ++nt)
#pragma unroll
      for (int r = 0; r < 4; ++r) {
        float p = __expf(sacc[nt][r] - m_r[r]);
        rsum[r] += p;
        Plds[w][g * 4 + r][nt * 16 + r15] = f2bf(p);
      }
#pragma unroll
    for (int r = 0; r < 4; ++r) {
      float s = rsum[r];
      s += __shfl_xor(s, 1);
      s += __shfl_xor(s, 2);
      s += __shfl_xor(s, 4);
      s += __shfl_xor(s, 8);
      l_r[r] += s;
    }

    bf16x8 pa0 = *reinterpret_cast<const bf16x8*>(&Plds[w][r15][8 * g]);
    bf16x8 pa1 = *reinterpret_cast<const bf16x8*>(&Plds[w][r15][32 + 8 * g]);
    __builtin_amdgcn_s_setprio(1);
#pragma unroll
    for (int dt = 0; dt < 8; ++dt) {
      bf16x8 v0 = *reinterpret_cast<const bf16x8*>(&Vlds[dt * 16 + r15][8 * g]);
      bf16x8 v1 = *reinterpret_cast<const bf16x8*>(&Vlds[dt * 16 + r15][32 + 8 * g]);
      oacc[dt] = __builtin_amdgcn_mfma_f32_16x16x32_bf16(pa0, v0, oacc[dt], 0, 0, 0);
      oacc[dt] = __builtin_amdgcn_mfma_f32_16x16x32_bf16(pa1, v1, oacc[dt], 0, 0, 0);
    }
    __builtin_amdgcn_s_setprio(0);
  }

#pragma unroll
  for (int dt = 0; dt < 8; ++dt)
#pragma unroll
    for (int r = 0; r < 4; ++r) {
      int row = q0 + w * 16 + g * 4 + r;
      int col = h * DH + dt * 16 + r15;
      obuf[(size_t)row * 16384 + col] = f2bf(oacc[dt][r] / l_r[r]);
    }
}

// ------------------------------------------------------------------------------
extern "C" void kernel_launch(void* const* d_in, const int* in_sizes, int n_in,
                              void* d_out, int out_size, void* d_ws, size_t ws_size,
                              hipStream_t stream) {
  const float* h    = (const float*)d_in[0];
  const float* Wdq  = (const float*)d_in[1];
  const float* bdq  = (const float*)d_in[2];
  const float* Wdkv = (const float*)d_in[3];
  const float* bdkv = (const float*)d_in[4];
  const float* Wuq  = (const float*)d_in[5];
  const float* buq  = (const float*)d_in[6];
  const float* Wukv = (const float*)d_in[7];
  const float* bukv = (const float*)d_in[8];
  const float* Wrq  = (const float*)d_in[9];
  const float* brq  = (const float*)d_in[10];
  const float* Wrk  = (const float*)d_in[11];
  const float* brk  = (const float*)d_in[12];
  const float* Wo   = (const float*)d_in[13];
  const float* bo   = (const float*)d_in[14];
  float* out = (float*)d_out;

  char* ws = (char*)d_ws;
  size_t off = 0;
  auto alloc = [&](size_t bytes) {
    char* p = ws + off;
    off += (bytes + 255) & ~(size_t)255;
    return p;
  };
  unsigned short* hb    = (unsigned short*)alloc((size_t)1024 * 7168 * 2);
  unsigned short* W1cat = (unsigned short*)alloc((size_t)2176 * 7168 * 2);
  float*          b1cat = (float*)alloc(2176 * 4);
  float*          b2cat = (float*)alloc(24576 * 4);
  unsigned short* ccat  = (unsigned short*)alloc((size_t)1024 * 2112 * 2);
  unsigned short* qcat  = (unsigned short*)alloc((size_t)1024 * 24576 * 2);
  unsigned short* kvbb  = (unsigned short*)alloc((size_t)1024 * 32768 * 2);
  unsigned short* vt    = (unsigned short*)alloc((size_t)16384 * 1024 * 2);
  unsigned short* obuf  = (unsigned short*)alloc((size_t)1024 * 16384 * 2);
  float*          ctab  = (float*)alloc((size_t)S_LEN * 32 * 4);
  float*          stab  = (float*)alloc((size_t)S_LEN * 32 * 4);
  unsigned short* Wukvb = (unsigned short*)alloc((size_t)32768 * 512 * 2);
  // G1 split-K partials alias not-yet-written qcat (34.6 MB < 50.3 MB)
  float* pbufG1 = (float*)qcat;
  // d_ws ~1.8 GB: Wob (bf16 Wo, 235 MB) @ 288 MiB; pbufG4 (4x29.4=117 MB) @ 544 MiB
  unsigned short* Wob    = (unsigned short*)(ws + ((size_t)288 << 20));
  float*          pbufG4 = (float*)(ws + ((size_t)544 << 20));

  auto cvt = [&](const float* in, unsigned short* outp, size_t n) {
    int n8 = (int)(n / 8);
    int blocks = (n8 + 255) / 256;
    if (blocks > 2048) blocks = 2048;
    cvt_bf16_kernel<<<blocks, 256, 0, stream>>>(in, outp, n8);
  };

  // --- conversions for h, W1cat, Wukv ---
  cvt(h,    hb,    (size_t)1024 * 7168);
  cvt(Wdq,  W1cat, (size_t)1536 * 7168);
  cvt(Wdkv, W1cat + (size_t)1536 * 7168, (size_t)512 * 7168);
  cvt(Wrk,  W1cat + (size_t)2048 * 7168, (size_t)64 * 7168);
  cvt(Wukv, Wukvb, (size_t)32768 * 512);
  hipMemsetAsync(W1cat + (size_t)2112 * 7168, 0, (size_t)64 * 7168 * 2, stream);
  hipMemcpyAsync(b1cat,        bdq,  1536 * 4, hipMemcpyDeviceToDevice, stream);
  hipMemcpyAsync(b1cat + 1536, bdkv, 512 * 4,  hipMemcpyDeviceToDevice, stream);
  hipMemcpyAsync(b1cat + 2048, brk,  64 * 4,   hipMemcpyDeviceToDevice, stream);
  hipMemsetAsync(b1cat + 2112, 0, 64 * 4, stream);
  hipMemcpyAsync(b2cat,         buq, 16384 * 4, hipMemcpyDeviceToDevice, stream);
  hipMemcpyAsync(b2cat + 16384, brq, 8192 * 4,  hipMemcpyDeviceToDevice, stream);
  rope_table_kernel<<<(S_LEN * 32 + 255) / 256, 256, 0, stream>>>(ctab, stab);

  const float scale = 0.07216878364870323f;   // 1/sqrt(192)
  const int BIGN = 1 << 30;
  dim3 blk(256);

  // G1 (split-K=4, bf16 W): partials = h @ W1cat^T
  gemm_k<2, 0><<<dim3(24, 8, 4), blk, 0, stream>>>(
      hb, 7168, W1cat, nullptr, nullptr, BIGN, 7168, nullptr,
      pbufG1, 2112, (size_t)1024 * 2112, 2112, 1792, 1.0f);
  reduce_bf16_kernel<<<2112, blk, 0, stream>>>(pbufG1, b1cat, ccat, 2112, 528, 4,
                                               (size_t)1024 * 2112, 1024 * 2112 / 4);
  rope_bf16_kernel<<<(1024 * 32 + 255) / 256, blk, 0, stream>>>(ccat + 2048, 1, 2112, 1024 * 32, ctab, stab);

  // G2 (fp32 W direct, counted-vmcnt pipeline, fused q_r RoPE):
  gemm_k<1, 1, 1><<<dim3(192, 8, 1), blk, 0, stream>>>(
      ccat, 2112, nullptr, Wuq, Wrq, 16384, 1536, b2cat,
      qcat, 24576, 0, 24576, 1536, scale, ctab, stab);

  // G3 (bf16 W via glds): kv = c_kv @ Wukv^T + bukv
  gemm_k<1, 0><<<dim3(256, 8, 1), blk, 0, stream>>>(
      ccat + 1536, 2112, Wukvb, nullptr, nullptr, BIGN, 512, bukv,
      kvbb, 32768, 0, 32768, 512, 1.0f);
  vtrans_kernel<<<dim3(16, 256), blk, 0, stream>>>(kvbb, vt);
  mla_attn_kernel<<<dim3(1024), dim3(512), 0, stream>>>(qcat, kvbb, ccat + 2048, vt, obuf);

  // G4: cvt Wo -> bf16 once, 8-phase 256^2 GEMM (split-K=4), reduce.
  cvt(Wo, Wob, (size_t)7168 * 16384);
  gemm_g4_8ph<<<dim3(28, 4, 4), dim3(512), 0, stream>>>(obuf, Wob, pbufG4);
  reduce_f32_kernel<<<7168, blk, 0, stream>>>(pbufG4, bo, out,
                                              7168, 1792, 4, (size_t)1024 * 7168, 1024 * 7168 / 4);
}

// Round 19
// 936.330 us; speedup vs baseline: 1.3130x; 1.0426x over previous
//
#include <hip/hip_runtime.h>
#include <hip/hip_bf16.h>

#define S_LEN 1024
#define HID 7168
#define NH 128
#define DQ 1536
#define DKV 512
#define DH 128
#define DR 64

typedef __attribute__((ext_vector_type(8))) short bf16x8;
typedef __attribute__((ext_vector_type(4))) float f32x4;
typedef __attribute__((ext_vector_type(4))) float fl4;
typedef __attribute__((ext_vector_type(4))) unsigned short us4;
typedef __attribute__((ext_vector_type(8))) unsigned short us8;
typedef __attribute__((ext_vector_type(4))) unsigned int u32x4;

static __device__ __forceinline__ unsigned short f2bf(float f) {
  union { float f; unsigned int u; } v; v.f = f;
  unsigned int u = v.u;
  return (unsigned short)((u + 0x7fffu + ((u >> 16) & 1u)) >> 16);
}
static __device__ __forceinline__ float bf2f(unsigned short u) {
  union { unsigned int u; float f; } v; v.u = ((unsigned int)u) << 16;
  return v.f;
}
static __device__ __forceinline__ unsigned int cvtpk2(float lo, float hi) {
  unsigned int r;
  asm("v_cvt_pk_bf16_f32 %0, %1, %2" : "=v"(r) : "v"(lo), "v"(hi));
  return r;
}

// ---------------- fp32 -> bf16 conversion -------------------------------------
__global__ __launch_bounds__(256) void cvt_bf16_kernel(
    const float* __restrict__ in, unsigned short* __restrict__ out, int n8) {
  int i = blockIdx.x * 256 + threadIdx.x;
  int stride = gridDim.x * 256;
  for (; i < n8; i += stride) {
    fl4 a = ((const fl4*)in)[2 * i];
    fl4 b = ((const fl4*)in)[2 * i + 1];
    us8 u = { f2bf(a[0]), f2bf(a[1]), f2bf(a[2]), f2bf(a[3]),
              f2bf(b[0]), f2bf(b[1]), f2bf(b[2]), f2bf(b[3]) };
    ((us8*)out)[i] = u;
  }
}

// ---------------- 5-segment cvt (h, Wdq, Wdkv, Wrk, Wukv) ---------------------
__global__ __launch_bounds__(256) void cvt5_kernel(
    const float* __restrict__ h,    const float* __restrict__ wdq,
    const float* __restrict__ wdkv, const float* __restrict__ wrk,
    const float* __restrict__ wukv,
    unsigned short* __restrict__ hb, unsigned short* __restrict__ w1cat,
    unsigned short* __restrict__ wukvb)
{
  // segment boundaries in n8 (8-element) units
  const int s0 = 917504;            // h: 1024*7168/8
  const int s1 = s0 + 1376256;      // Wdq: 1536*7168/8
  const int s2 = s1 + 458752;       // Wdkv: 512*7168/8
  const int s3 = s2 + 57344;        // Wrk: 64*7168/8
  const int s4 = s3 + 2097152;      // Wukv: 32768*512/8
  int i = blockIdx.x * 256 + threadIdx.x;
  int stride = gridDim.x * 256;
  for (; i < s4; i += stride) {
    const float* src;
    unsigned short* dst;
    int j;
    if (i < s0)      { src = h;    dst = hb;                              j = i; }
    else if (i < s1) { src = wdq;  dst = w1cat;                           j = i - s0; }
    else if (i < s2) { src = wdkv; dst = w1cat + (size_t)1536 * 7168;     j = i - s1; }
    else if (i < s3) { src = wrk;  dst = w1cat + (size_t)2048 * 7168;     j = i - s2; }
    else             { src = wukv; dst = wukvb;                           j = i - s3; }
    fl4 a = ((const fl4*)src)[2 * j];
    fl4 b = ((const fl4*)src)[2 * j + 1];
    us8 u = { f2bf(a[0]), f2bf(a[1]), f2bf(a[2]), f2bf(a[3]),
              f2bf(b[0]), f2bf(b[1]), f2bf(b[2]), f2bf(b[3]) };
    ((us8*)dst)[j] = u;
  }
}

// ---------------- bias concat + W1cat pad zero (replaces 8 memcpy/memset) -----
__global__ __launch_bounds__(256) void setup_kernel(
    const float* __restrict__ bdq, const float* __restrict__ bdkv,
    const float* __restrict__ brk, const float* __restrict__ buq,
    const float* __restrict__ brq,
    float* __restrict__ b1cat, float* __restrict__ b2cat,
    unsigned short* __restrict__ w1pad)   // = W1cat + 2112*7168, 64*7168 elems
{
  int i = blockIdx.x * 256 + threadIdx.x;   // grid covers 458752
  if (i < 458752) w1pad[i] = 0;
  if (i < 2176) {
    float v = (i < 1536) ? bdq[i]
            : (i < 2048) ? bdkv[i - 1536]
            : (i < 2112) ? brk[i - 2048] : 0.f;
    b1cat[i] = v;
  }
  if (i < 24576)
    b2cat[i] = (i < 16384) ? buq[i] : brq[i - 16384];
}

// ---------------- bf16 GEMM (m97 structure, counted-vmcnt WFP32) --------------
template <int OUTMODE, int WFP32, int ROPEQ = 0>
__global__ __launch_bounds__(256) void gemm_k(
    const unsigned short* __restrict__ A, int lda,
    const unsigned short* __restrict__ Wb16,
    const float* __restrict__ Wfa, const float* __restrict__ Wfb, int nsplit,
    int ldw,
    const float* __restrict__ bias,
    void* __restrict__ Cv, int ldc, size_t zstride,
    int Ncl, int ksl, float alpha,
    const float* __restrict__ ctab = nullptr,
    const float* __restrict__ stab = nullptr)
{
  const int n0 = blockIdx.x * 128;
  if (n0 >= Ncl) return;

  __shared__ unsigned short As[128 * 64];
  __shared__ unsigned short Ws[128 * 64];
  const int t = threadIdx.x;
  const int l = t & 63, w = t >> 6;
  const int r15 = l & 15, g = l >> 4;
  const int wm = (w >> 1) * 64, wn = (w & 1) * 64;
  const int m0 = blockIdx.y * 128;
  const int kbase = blockIdx.z * ksl;
  const int srow = l >> 3;
  const int scol = (l & 7) * 8;

  f32x4 acc[4][4];
#pragma unroll
  for (int i = 0; i < 4; ++i)
#pragma unroll
    for (int j = 0; j < 4; ++j) acc[i][j] = (f32x4){0.f, 0.f, 0.f, 0.f};

  const unsigned short* Ab = A + (size_t)m0 * lda;
  const unsigned short* Wb = nullptr;
  const float* Wf = nullptr;
  if constexpr (WFP32) {
    Wf = (n0 < nsplit) ? Wfa + (size_t)n0 * ldw : Wfb + (size_t)(n0 - nsplit) * ldw;
  } else {
    Wb = Wb16 + (size_t)n0 * ldw;
  }

  fl4 wx[4], wy[4];
  auto issueW = [&](int k0) {
#pragma unroll
    for (int i = 0; i < 4; ++i) {
      int c = t + 256 * i;
      const float* src = Wf + (size_t)(c >> 3) * ldw + k0 + (c & 7) * 8;
      wx[i] = *(const fl4*)src;
      wy[i] = *(const fl4*)(src + 4);
    }
  };

  if constexpr (WFP32) issueW(kbase);
  const int kend = kbase + ksl;

  for (int k0 = kbase; k0 < kend; k0 += 64) {
    if constexpr (WFP32) {
      __builtin_amdgcn_s_barrier();
      __builtin_amdgcn_sched_barrier(0);
    } else {
      __syncthreads();
    }
#pragma unroll
    for (int i = 0; i < 4; ++i) {
      int chunk = w * 4 + i;
      int row = chunk * 8 + srow;
      __builtin_amdgcn_global_load_lds(
          (const __attribute__((address_space(1))) void*)(Ab + (size_t)row * lda + k0 + scol),
          (__attribute__((address_space(3))) void*)(As + chunk * 512), 16, 0, 0);
      if constexpr (!WFP32) {
        __builtin_amdgcn_global_load_lds(
            (const __attribute__((address_space(1))) void*)(Wb + (size_t)row * ldw + k0 + scol),
            (__attribute__((address_space(3))) void*)(Ws + chunk * 512), 16, 0, 0);
      }
    }
    if constexpr (WFP32) {
      __builtin_amdgcn_sched_barrier(0);
      asm volatile("s_waitcnt vmcnt(4)" ::: "memory");
      __builtin_amdgcn_sched_barrier(0);
#pragma unroll
      for (int i = 0; i < 4; ++i) {
        int c = t + 256 * i;
        u32x4 p = { cvtpk2(wx[i][0], wx[i][1]), cvtpk2(wx[i][2], wx[i][3]),
                    cvtpk2(wy[i][0], wy[i][1]), cvtpk2(wy[i][2], wy[i][3]) };
        ((u32x4*)Ws)[c] = p;
      }
      if (k0 + 64 < kend) {
        issueW(k0 + 64);
        __builtin_amdgcn_sched_barrier(0);
        asm volatile("s_waitcnt vmcnt(8) lgkmcnt(0)" ::: "memory");
      } else {
        asm volatile("s_waitcnt vmcnt(0) lgkmcnt(0)" ::: "memory");
      }
      __builtin_amdgcn_sched_barrier(0);
      __builtin_amdgcn_s_barrier();
    } else {
      __syncthreads();
    }
#pragma unroll
    for (int kk = 0; kk < 2; ++kk) {
      bf16x8 a[4], b[4];
#pragma unroll
      for (int mt = 0; mt < 4; ++mt)
        a[mt] = *reinterpret_cast<const bf16x8*>(&As[(wm + mt * 16 + r15) * 64 + kk * 32 + 8 * g]);
#pragma unroll
      for (int nt = 0; nt < 4; ++nt)
        b[nt] = *reinterpret_cast<const bf16x8*>(&Ws[(wn + nt * 16 + r15) * 64 + kk * 32 + 8 * g]);
#pragma unroll
      for (int mt = 0; mt < 4; ++mt)
#pragma unroll
        for (int nt = 0; nt < 4; ++nt)
          acc[mt][nt] = __builtin_amdgcn_mfma_f32_16x16x32_bf16(a[mt], b[nt], acc[mt][nt], 0, 0, 0);
    }
  }

  if constexpr (OUTMODE == 1) {
    float bv[4];
#pragma unroll
    for (int nt = 0; nt < 4; ++nt) {
      int col = n0 + wn + nt * 16 + r15;
      bv[nt] = (col < Ncl) ? bias[col] : 0.f;
    }
    bool isrope = false;
    if constexpr (ROPEQ) isrope = (n0 + wn) >= 16384;
    if (ROPEQ && isrope) {
#pragma unroll
      for (int mt = 0; mt < 4; ++mt)
#pragma unroll
        for (int r = 0; r < 4; ++r) {
          int row = m0 + wm + mt * 16 + g * 4 + r;
#pragma unroll
          for (int ntp = 0; ntp < 2; ++ntp) {
            int j = ntp * 16 + r15;
            float c = ctab[row * 32 + j];
            float s = stab[row * 32 + j];
            float x1 = acc[mt][ntp][r] + bv[ntp];
            float x2 = acc[mt][ntp + 2][r] + bv[ntp + 2];
            int col1 = n0 + wn + ntp * 16 + r15;
            ((unsigned short*)Cv)[(size_t)row * ldc + col1] =
                f2bf((x1 * c - x2 * s) * alpha);
            ((unsigned short*)Cv)[(size_t)row * ldc + col1 + 32] =
                f2bf((x2 * c + x1 * s) * alpha);
          }
        }
    } else {
#pragma unroll
      for (int mt = 0; mt < 4; ++mt)
#pragma unroll
        for (int nt = 0; nt < 4; ++nt) {
          int col = n0 + wn + nt * 16 + r15;
          if (col < Ncl) {
#pragma unroll
            for (int r = 0; r < 4; ++r) {
              int row = m0 + wm + mt * 16 + g * 4 + r;
              ((unsigned short*)Cv)[(size_t)row * ldc + col] =
                  f2bf((acc[mt][nt][r] + bv[nt]) * alpha);
            }
          }
        }
    }
  } else {
    float* Cp = (float*)Cv + blockIdx.z * zstride;
#pragma unroll
    for (int mt = 0; mt < 4; ++mt)
#pragma unroll
      for (int nt = 0; nt < 4; ++nt) {
        int col = n0 + wn + nt * 16 + r15;
        if (col < Ncl) {
#pragma unroll
          for (int r = 0; r < 4; ++r) {
            int row = m0 + wm + mt * 16 + g * 4 + r;
            Cp[(size_t)row * ldc + col] = acc[mt][nt][r];
          }
        }
      }
  }
}

// ---------------- G4: 8-phase 256x256 template (T2+T3+T4+T5), split-K=2 -------
#define G4_DSREAD_A(buf, mh)                                                  \
  _Pragma("unroll") for (int mf = 0; mf < 4; ++mf)                            \
  _Pragma("unroll") for (int kk = 0; kk < 2; ++kk)                            \
    af[mf][kk] = rdA(buf, mh, mf, kk);

#define G4_DSREAD_B(buf, nh, breg)                                            \
  _Pragma("unroll") for (int nf = 0; nf < 2; ++nf)                            \
  _Pragma("unroll") for (int kk = 0; kk < 2; ++kk)                            \
    breg[nf][kk] = rdB(buf, nh, nf, kk);

#define G4_MFMA(mh, nh, breg)                                                 \
  __builtin_amdgcn_s_setprio(1);                                              \
  _Pragma("unroll") for (int kk = 0; kk < 2; ++kk)                            \
  _Pragma("unroll") for (int mf = 0; mf < 4; ++mf)                            \
  _Pragma("unroll") for (int nf = 0; nf < 2; ++nf)                            \
    acc[mh][nh][mf][nf] = __builtin_amdgcn_mfma_f32_16x16x32_bf16(            \
        af[mf][kk], breg[nf][kk], acc[mh][nh][mf][nf], 0, 0, 0);              \
  __builtin_amdgcn_s_setprio(0);

#define G4_BAR_IN()                                                           \
  __builtin_amdgcn_s_barrier();                                               \
  asm volatile("s_waitcnt lgkmcnt(0)" ::: "memory");                          \
  __builtin_amdgcn_sched_barrier(0);

#define G4_BAR_OUT()                                                          \
  __builtin_amdgcn_sched_barrier(0);                                          \
  __builtin_amdgcn_s_barrier();

__global__ __launch_bounds__(512, 2) void gemm_g4_8ph(
    const unsigned short* __restrict__ A,      // obuf [1024][16384] bf16
    const unsigned short* __restrict__ W,      // Wob [7168][16384] bf16
    float* __restrict__ pbuf)                  // [2][1024][7168] fp32 partials
{
  __shared__ unsigned short S[65536];          // 128 KB
  const int t = threadIdx.x;
  const int l = t & 63, w = t >> 6;            // 8 waves
  const int r15 = l & 15, g = l >> 4;
  const int n0 = blockIdx.x * 256;
  const int m0 = blockIdx.y * 256;
  const int kbase = blockIdx.z * 8192;
  const int NT = 128;

  const int lp = (l & 56) | ((l ^ (l >> 3)) & 7);
  const int srow = lp >> 3;
  const int scol = (lp & 7) * 8;
  const int pr = (w >> 2) * 64;
  const int pc = (w & 3) * 32;

  f32x4 acc[2][2][4][2];
#pragma unroll
  for (int a0 = 0; a0 < 2; ++a0)
#pragma unroll
    for (int a1 = 0; a1 < 2; ++a1)
#pragma unroll
      for (int a2 = 0; a2 < 4; ++a2)
#pragma unroll
        for (int a3 = 0; a3 < 2; ++a3)
          acc[a0][a1][a2][a3] = (f32x4){0.f, 0.f, 0.f, 0.f};

  auto stage = [&](int tile, int which) {
    if (tile >= NT) return;
    const int k0 = kbase + tile * 64;
    const unsigned short* gb = (which < 2)
        ? A + (size_t)(m0 + which * 128) * 16384 + k0
        : W + (size_t)(n0 + (which - 2) * 128) * 16384 + k0;
    unsigned short* dst = S + (tile & 1) * 32768 + which * 8192;
#pragma unroll
    for (int i = 0; i < 2; ++i) {
      __builtin_amdgcn_global_load_lds(
          (const __attribute__((address_space(1))) void*)(gb + (size_t)((w * 2 + i) * 8 + srow) * 16384 + scol),
          (__attribute__((address_space(3))) void*)(dst + (w * 2 + i) * 512 + l * 8), 16, 0, 0);
    }
  };

  auto rdA = [&](int buf, int mh, int mf, int kk) -> bf16x8 {
    int row = pr + mf * 16 + r15;
    int L = row * 128 + kk * 64 + g * 16;
    L ^= ((L >> 7) & 7) << 4;
    return *(const bf16x8*)((const char*)S + buf * 65536 + mh * 16384 + L);
  };
  auto rdB = [&](int buf, int nh, int nf, int kk) -> bf16x8 {
    int row = pc + nf * 16 + r15;
    int L = row * 128 + kk * 64 + g * 16;
    L ^= ((L >> 7) & 7) << 4;
    return *(const bf16x8*)((const char*)S + buf * 65536 + (2 + nh) * 16384 + L);
  };

  bf16x8 af[4][2], bA[2][2], bB[2][2];

  stage(0, 0); stage(0, 1); stage(0, 2); stage(0, 3);
  stage(1, 0); stage(1, 2); stage(1, 3);
  __builtin_amdgcn_sched_barrier(0);
  asm volatile("s_waitcnt vmcnt(6)" ::: "memory");
  __builtin_amdgcn_sched_barrier(0);
  __builtin_amdgcn_s_barrier();

  for (int i = 0; i < 64; ++i) {
    const int tb = 2 * i;
    const bool last = (i == 63);
    // P1: (0,0) of tile tb (buf0)
    G4_DSREAD_A(0, 0)
    G4_DSREAD_B(0, 0, bA)
    stage(tb + 1, 1);
    G4_BAR_IN()
    G4_MFMA(0, 0, bA)
    G4_BAR_OUT()
    // P2: (0,1)
    G4_DSREAD_B(0, 1, bB)
    stage(tb + 2, 0);
    G4_BAR_IN()
    G4_MFMA(0, 1, bB)
    G4_BAR_OUT()
    // P3: (1,1)
    G4_DSREAD_A(0, 1)
    stage(tb + 2, 2);
    G4_BAR_IN()
    G4_MFMA(1, 1, bB)
    G4_BAR_OUT()
    // P4: (1,0)
    stage(tb + 2, 3);
    G4_BAR_IN()
    G4_MFMA(1, 0, bA)
    if (last) { asm volatile("s_waitcnt vmcnt(0)" ::: "memory"); }
    else      { asm volatile("s_waitcnt vmcnt(6)" ::: "memory"); }
    G4_BAR_OUT()
    // P5: (0,0) of tile tb+1 (buf1)
    G4_DSREAD_A(1, 0)
    G4_DSREAD_B(1, 0, bA)
    stage(tb + 2, 1);
    G4_BAR_IN()
    G4_MFMA(0, 0, bA)
    G4_BAR_OUT()
    // P6: (0,1)
    G4_DSREAD_B(1, 1, bB)
    stage(tb + 3, 0);
    G4_BAR_IN()
    G4_MFMA(0, 1, bB)
    G4_BAR_OUT()
    // P7: (1,1)
    G4_DSREAD_A(1, 1)
    stage(tb + 3, 2);
    G4_BAR_IN()
    G4_MFMA(1, 1, bB)
    G4_BAR_OUT()
    // P8: (1,0)
    stage(tb + 3, 3);
    G4_BAR_IN()
    G4_MFMA(1, 0, bA)
    if (last) { asm volatile("s_waitcnt vmcnt(0)" ::: "memory"); }
    else      { asm volatile("s_waitcnt vmcnt(6)" ::: "memory"); }
    G4_BAR_OUT()
  }

  float* Cp = pbuf + (size_t)blockIdx.z * 1024 * 7168;
#pragma unroll
  for (int mh = 0; mh < 2; ++mh)
#pragma unroll
    for (int nh = 0; nh < 2; ++nh)
#pragma unroll
      for (int mf = 0; mf < 4; ++mf)
#pragma unroll
        for (int nf = 0; nf < 2; ++nf) {
          int col = n0 + nh * 128 + pc + nf * 16 + r15;
#pragma unroll
          for (int r = 0; r < 4; ++r) {
            int row = m0 + mh * 128 + pr + mf * 16 + g * 4 + r;
            Cp[(size_t)row * 7168 + col] = acc[mh][nh][mf][nf][r];
          }
        }
}

// ---------------- split-K reductions ------------------------------------------
__global__ __launch_bounds__(256) void reduce_f32_kernel(
    const float* __restrict__ pbuf, const float* __restrict__ bias,
    float* __restrict__ out, int ldo, int rowlen4, int nz, size_t zstride, int total4)
{
  int idx = blockIdx.x * 256 + threadIdx.x;
  if (idx >= total4) return;
  int r = idx / rowlen4, c4 = idx % rowlen4;
  fl4 acc = *(const fl4*)(bias + c4 * 4);
  for (int z = 0; z < nz; ++z)
    acc += *(const fl4*)(pbuf + z * zstride + (size_t)idx * 4);
  *(fl4*)(out + (size_t)r * ldo + c4 * 4) = acc;
}

__global__ __launch_bounds__(256) void reduce_bf16_kernel(
    const float* __restrict__ pbuf, const float* __restrict__ bias,
    unsigned short* __restrict__ out, int ldo, int rowlen4, int nz, size_t zstride, int total4)
{
  int idx = blockIdx.x * 256 + threadIdx.x;
  if (idx >= total4) return;
  int r = idx / rowlen4, c4 = idx % rowlen4;
  fl4 acc = *(const fl4*)(bias + c4 * 4);
  for (int z = 0; z < nz; ++z)
    acc += *(const fl4*)(pbuf + z * zstride + (size_t)idx * 4);
  us4 u = { f2bf(acc[0]), f2bf(acc[1]), f2bf(acc[2]), f2bf(acc[3]) };
  *(us4*)(out + (size_t)r * ldo + c4 * 4) = u;
}

// ---------------- rope tables + table-based rope (k_r only) -------------------
__global__ __launch_bounds__(256) void rope_table_kernel(float* __restrict__ ctab,
                                                         float* __restrict__ stab) {
  int idx = blockIdx.x * 256 + threadIdx.x;
  if (idx >= S_LEN * 32) return;
  int j = idx & 31, s = idx >> 5;
  float invf = expf(-0.28782313662425574f * (float)j);
  float ang = (float)s * invf;
  ctab[idx] = cosf(ang);
  stab[idx] = sinf(ang);
}

__global__ void rope_bf16_kernel(unsigned short* __restrict__ x, int nh, int lda, int total,
                                 const float* __restrict__ ctab,
                                 const float* __restrict__ stab) {
  int idx = blockIdx.x * 256 + threadIdx.x;
  if (idx >= total) return;
  int j = idx & 31;
  int rest = idx >> 5;
  int hh = rest % nh;
  int s = rest / nh;
  float c = ctab[s * 32 + j], sn = stab[s * 32 + j];
  size_t base = (size_t)s * lda + hh * 64;
  float x1 = bf2f(x[base + j]), x2 = bf2f(x[base + j + 32]);
  x[base + j]      = f2bf(x1 * c - x2 * sn);
  x[base + j + 32] = f2bf(x2 * c + x1 * sn);
}

// ---------------- V transpose -------------------------------------------------
__global__ __launch_bounds__(256) void vtrans_kernel(
    const unsigned short* __restrict__ kvb, unsigned short* __restrict__ vt) {
  __shared__ unsigned short tl[64][72];
  const int s0 = blockIdx.x * 64;
  const int c0 = blockIdx.y * 64;
  const int t = threadIdx.x;
  const int rr = t >> 3, cc = (t & 7) * 8;
  const int hbase = (c0 >> 7) * 256 + 128 + (c0 & 127);
#pragma unroll
  for (int i = 0; i < 2; ++i) {
    int r = rr + i * 32;
    *reinterpret_cast<bf16x8*>(&tl[r][cc]) =
        *reinterpret_cast<const bf16x8*>(kvb + (size_t)(s0 + r) * 32768 + hbase + cc);
  }
  __syncthreads();
#pragma unroll
  for (int i = 0; i < 2; ++i) {
    int vc = rr + i * 32;
    unsigned short tmp[8];
#pragma unroll
    for (int j = 0; j < 8; ++j) tmp[j] = tl[cc + j][vc];
    *reinterpret_cast<bf16x8*>(&vt[(size_t)(c0 + vc) * 1024 + s0 + cc]) =
        *reinterpret_cast<bf16x8*>(tmp);
  }
}

// ---------------- flash attention: QBLK=128, 8 waves, T13 defer-max -----------
__global__ __launch_bounds__(512) void mla_attn_kernel(
    const unsigned short* __restrict__ qcat,
    const unsigned short* __restrict__ kvb,
    const unsigned short* __restrict__ kr,
    const unsigned short* __restrict__ vt,
    unsigned short* __restrict__ obuf)
{
  __shared__ unsigned short Klds[64][200];
  __shared__ unsigned short Vlds[128][72];
  __shared__ unsigned short Plds[8][16][72];

  const int t = threadIdx.x;
  const int l = t & 63, w = t >> 6;
  const int r15 = l & 15, g = l >> 4;
  const int bid = blockIdx.x;
  const int orig = (bid & 7) * 128 + (bid >> 3);
  const int h = orig >> 3;
  const int q0 = (orig & 7) * 128;

  bf16x8 qf[6];
  const unsigned short* qrow = qcat + (size_t)(q0 + w * 16 + r15) * 24576;
#pragma unroll
  for (int kk = 0; kk < 4; ++kk)
    qf[kk] = *reinterpret_cast<const bf16x8*>(qrow + h * 128 + kk * 32 + 8 * g);
#pragma unroll
  for (int kk = 4; kk < 6; ++kk)
    qf[kk] = *reinterpret_cast<const bf16x8*>(qrow + 16384 + h * 64 + (kk - 4) * 32 + 8 * g);

  bf16x8 kreg[3], vreg[2];
  auto loadKV = [&](int kk0) {
#pragma unroll
    for (int i = 0; i < 3; ++i) {
      int c = t + 512 * i, row = c / 24, cb = c % 24;
      const unsigned short* src = (cb < 16)
          ? kvb + (size_t)(kk0 + row) * 32768 + h * 256 + cb * 8
          : kr + (size_t)(kk0 + row) * 2112 + (cb - 16) * 8;
      kreg[i] = *reinterpret_cast<const bf16x8*>(src);
    }
#pragma unroll
    for (int i = 0; i < 2; ++i) {
      int c = t + 512 * i, d = c >> 3, kb = c & 7;
      vreg[i] = *reinterpret_cast<const bf16x8*>(vt + ((size_t)h * 128 + d) * 1024 + kk0 + kb * 8);
    }
  };

  float m_r[4], l_r[4];
  f32x4 oacc[8];
#pragma unroll
  for (int r = 0; r < 4; ++r) { m_r[r] = -1e30f; l_r[r] = 0.f; }
#pragma unroll
  for (int d = 0; d < 8; ++d) oacc[d] = (f32x4){0.f, 0.f, 0.f, 0.f};

  loadKV(0);

  for (int kt = 0; kt < 16; ++kt) {
    __syncthreads();
#pragma unroll
    for (int i = 0; i < 3; ++i) {
      int c = t + 512 * i, row = c / 24, cb = c % 24;
      *reinterpret_cast<bf16x8*>(&Klds[row][cb * 8]) = kreg[i];
    }
#pragma unroll
    for (int i = 0; i < 2; ++i) {
      int c = t + 512 * i, d = c >> 3, kb = c & 7;
      *reinterpret_cast<bf16x8*>(&Vlds[d][kb * 8]) = vreg[i];
    }
    __syncthreads();
    if (kt < 15) loadKV((kt + 1) * 64);

    f32x4 sacc[4];
#pragma unroll
    for (int nt = 0; nt < 4; ++nt) sacc[nt] = (f32x4){0.f, 0.f, 0.f, 0.f};
    __builtin_amdgcn_s_setprio(1);
#pragma unroll
    for (int nt = 0; nt < 4; ++nt)
#pragma unroll
      for (int kk = 0; kk < 6; ++kk) {
        bf16x8 b = *reinterpret_cast<const bf16x8*>(&Klds[nt * 16 + r15][kk * 32 + 8 * g]);
        sacc[nt] = __builtin_amdgcn_mfma_f32_16x16x32_bf16(qf[kk], b, sacc[nt], 0, 0, 0);
      }
    __builtin_amdgcn_s_setprio(0);

    // online softmax with T13 defer-max (skip rescale when growth <= 8)
    float mx[4];
#pragma unroll
    for (int r = 0; r < 4; ++r) {
      float m = fmaxf(fmaxf(sacc[0][r], sacc[1][r]), fmaxf(sacc[2][r], sacc[3][r]));
      m = fmaxf(m, __shfl_xor(m, 1));
      m = fmaxf(m, __shfl_xor(m, 2));
      m = fmaxf(m, __shfl_xor(m, 4));
      m = fmaxf(m, __shfl_xor(m, 8));
      mx[r] = m;
    }
    float grow = fmaxf(fmaxf(mx[0] - m_r[0], mx[1] - m_r[1]),
                       fmaxf(mx[2] - m_r[2], mx[3] - m_r[3]));
    if (__any(grow > 8.0f)) {
      float sc[4];
#pragma unroll
      for (int r = 0; r < 4; ++r) {
        float mn = fmaxf(m_r[r], mx[r]);
        sc[r] = __expf(m_r[r] - mn);
        m_r[r] = mn;
        l_r[r] *= sc[r];
      }
#pragma unroll
      for (int d = 0; d < 8; ++d)
#pragma unroll
        for (int r = 0; r < 4; ++r) oacc[d][r] *= sc[r];
    }
    float rsum[4] = {0.f, 0.f, 0.f, 0.f};
#pragma unroll
    for (int nt = 0; nt < 4; ++nt)
#pragma unroll
      for (int r = 0; r < 4; ++r) {
        float p = __expf(sacc[nt][r] - m_r[r]);
        rsum[r] += p;
        Plds[w][g * 4 + r][nt * 16 + r15] = f2bf(p);
      }
#pragma unroll
    for (int r = 0; r < 4; ++r) {
      float s = rsum[r];
      s += __shfl_xor(s, 1);
      s += __shfl_xor(s, 2);
      s += __shfl_xor(s, 4);
      s += __shfl_xor(s, 8);
      l_r[r] += s;
    }

    bf16x8 pa0 = *reinterpret_cast<const bf16x8*>(&Plds[w][r15][8 * g]);
    bf16x8 pa1 = *reinterpret_cast<const bf16x8*>(&Plds[w][r15][32 + 8 * g]);
    __builtin_amdgcn_s_setprio(1);
#pragma unroll
    for (int dt = 0; dt < 8; ++dt) {
      bf16x8 v0 = *reinterpret_cast<const bf16x8*>(&Vlds[dt * 16 + r15][8 * g]);
      bf16x8 v1 = *reinterpret_cast<const bf16x8*>(&Vlds[dt * 16 + r15][32 + 8 * g]);
      oacc[dt] = __builtin_amdgcn_mfma_f32_16x16x32_bf16(pa0, v0, oacc[dt], 0, 0, 0);
      oacc[dt] = __builtin_amdgcn_mfma_f32_16x16x32_bf16(pa1, v1, oacc[dt], 0, 0, 0);
    }
    __builtin_amdgcn_s_setprio(0);
  }

#pragma unroll
  for (int dt = 0; dt < 8; ++dt)
#pragma unroll
    for (int r = 0; r < 4; ++r) {
      int row = q0 + w * 16 + g * 4 + r;
      int col = h * DH + dt * 16 + r15;
      obuf[(size_t)row * 16384 + col] = f2bf(oacc[dt][r] / l_r[r]);
    }
}

// ------------------------------------------------------------------------------
extern "C" void kernel_launch(void* const* d_in, const int* in_sizes, int n_in,
                              void* d_out, int out_size, void* d_ws, size_t ws_size,
                              hipStream_t stream) {
  const float* h    = (const float*)d_in[0];
  const float* Wdq  = (const float*)d_in[1];
  const float* bdq  = (const float*)d_in[2];
  const float* Wdkv = (const float*)d_in[3];
  const float* bdkv = (const float*)d_in[4];
  const float* Wuq  = (const float*)d_in[5];
  const float* buq  = (const float*)d_in[6];
  const float* Wukv = (const float*)d_in[7];
  const float* bukv = (const float*)d_in[8];
  const float* Wrq  = (const float*)d_in[9];
  const float* brq  = (const float*)d_in[10];
  const float* Wrk  = (const float*)d_in[11];
  const float* brk  = (const float*)d_in[12];
  const float* Wo   = (const float*)d_in[13];
  const float* bo   = (const float*)d_in[14];
  float* out = (float*)d_out;

  char* ws = (char*)d_ws;
  size_t off = 0;
  auto alloc = [&](size_t bytes) {
    char* p = ws + off;
    off += (bytes + 255) & ~(size_t)255;
    return p;
  };
  unsigned short* hb    = (unsigned short*)alloc((size_t)1024 * 7168 * 2);
  unsigned short* W1cat = (unsigned short*)alloc((size_t)2176 * 7168 * 2);
  float*          b1cat = (float*)alloc(2176 * 4);
  float*          b2cat = (float*)alloc(24576 * 4);
  unsigned short* ccat  = (unsigned short*)alloc((size_t)1024 * 2112 * 2);
  unsigned short* qcat  = (unsigned short*)alloc((size_t)1024 * 24576 * 2);
  unsigned short* kvbb  = (unsigned short*)alloc((size_t)1024 * 32768 * 2);
  unsigned short* vt    = (unsigned short*)alloc((size_t)16384 * 1024 * 2);
  unsigned short* obuf  = (unsigned short*)alloc((size_t)1024 * 16384 * 2);
  float*          ctab  = (float*)alloc((size_t)S_LEN * 32 * 4);
  float*          stab  = (float*)alloc((size_t)S_LEN * 32 * 4);
  unsigned short* Wukvb = (unsigned short*)alloc((size_t)32768 * 512 * 2);
  // G1 split-K partials alias not-yet-written qcat (34.6 MB < 50.3 MB)
  float* pbufG1 = (float*)qcat;
  // d_ws ~1.8 GB: Wob (bf16 Wo, 235 MB) @ 288 MiB; pbufG4 (2x29.4=59 MB) @ 544 MiB
  unsigned short* Wob    = (unsigned short*)(ws + ((size_t)288 << 20));
  float*          pbufG4 = (float*)(ws + ((size_t)544 << 20));

  const float scale = 0.07216878364870323f;   // 1/sqrt(192)
  const int BIGN = 1 << 30;
  dim3 blk(256);

  // --- fused setup: 5-segment cvt + bias concat + W1cat pad ---
  cvt5_kernel<<<2048, blk, 0, stream>>>(h, Wdq, Wdkv, Wrk, Wukv, hb, W1cat, Wukvb);
  setup_kernel<<<1792, blk, 0, stream>>>(bdq, bdkv, brk, buq, brq,
                                         b1cat, b2cat, W1cat + (size_t)2112 * 7168);
  rope_table_kernel<<<(S_LEN * 32 + 255) / 256, blk, 0, stream>>>(ctab, stab);

  // G1 (split-K=4, bf16 W): partials = h @ W1cat^T
  gemm_k<2, 0><<<dim3(24, 8, 4), blk, 0, stream>>>(
      hb, 7168, W1cat, nullptr, nullptr, BIGN, 7168, nullptr,
      pbufG1, 2112, (size_t)1024 * 2112, 2112, 1792, 1.0f);
  reduce_bf16_kernel<<<2112, blk, 0, stream>>>(pbufG1, b1cat, ccat, 2112, 528, 4,
                                               (size_t)1024 * 2112, 1024 * 2112 / 4);
  rope_bf16_kernel<<<(1024 * 32 + 255) / 256, blk, 0, stream>>>(ccat + 2048, 1, 2112, 1024 * 32, ctab, stab);

  // G2 (fp32 W direct, counted-vmcnt pipeline, fused q_r RoPE):
  gemm_k<1, 1, 1><<<dim3(192, 8, 1), blk, 0, stream>>>(
      ccat, 2112, nullptr, Wuq, Wrq, 16384, 1536, b2cat,
      qcat, 24576, 0, 24576, 1536, scale, ctab, stab);

  // G3 (bf16 W via glds): kv = c_kv @ Wukv^T + bukv
  gemm_k<1, 0><<<dim3(256, 8, 1), blk, 0, stream>>>(
      ccat + 1536, 2112, Wukvb, nullptr, nullptr, BIGN, 512, bukv,
      kvbb, 32768, 0, 32768, 512, 1.0f);
  vtrans_kernel<<<dim3(16, 256), blk, 0, stream>>>(kvbb, vt);
  mla_attn_kernel<<<dim3(1024), dim3(512), 0, stream>>>(qcat, kvbb, ccat + 2048, vt, obuf);

  // G4: cvt Wo -> bf16 once, 8-phase 256^2 GEMM (split-K=2), reduce.
  cvt_bf16_kernel<<<2048, blk, 0, stream>>>(Wo, Wob, (int)((size_t)7168 * 16384 / 8));
  gemm_g4_8ph<<<dim3(28, 4, 2), dim3(512), 0, stream>>>(obuf, Wob, pbufG4);
  reduce_f32_kernel<<<7168, blk, 0, stream>>>(pbufG4, bo, out,
                                              7168, 1792, 2, (size_t)1024 * 7168, 1024 * 7168 / 4);
}

// Round 20
// 931.582 us; speedup vs baseline: 1.3197x; 1.0051x over previous
//
#include <hip/hip_runtime.h>
#include <hip/hip_bf16.h>

#define S_LEN 1024
#define HID 7168
#define NH 128
#define DQ 1536
#define DKV 512
#define DH 128
#define DR 64

typedef __attribute__((ext_vector_type(8))) short bf16x8;
typedef __attribute__((ext_vector_type(4))) float f32x4;
typedef __attribute__((ext_vector_type(4))) float fl4;
typedef __attribute__((ext_vector_type(4))) unsigned short us4;
typedef __attribute__((ext_vector_type(8))) unsigned short us8;
typedef __attribute__((ext_vector_type(4))) unsigned int u32x4;

static __device__ __forceinline__ unsigned short f2bf(float f) {
  union { float f; unsigned int u; } v; v.f = f;
  unsigned int u = v.u;
  return (unsigned short)((u + 0x7fffu + ((u >> 16) & 1u)) >> 16);
}
static __device__ __forceinline__ float bf2f(unsigned short u) {
  union { unsigned int u; float f; } v; v.u = ((unsigned int)u) << 16;
  return v.f;
}
static __device__ __forceinline__ unsigned int cvtpk2(float lo, float hi) {
  unsigned int r;
  asm("v_cvt_pk_bf16_f32 %0, %1, %2" : "=v"(r) : "v"(lo), "v"(hi));
  return r;
}

// ---------------- fp32 -> bf16 conversion -------------------------------------
__global__ __launch_bounds__(256) void cvt_bf16_kernel(
    const float* __restrict__ in, unsigned short* __restrict__ out, int n8) {
  int i = blockIdx.x * 256 + threadIdx.x;
  int stride = gridDim.x * 256;
  for (; i < n8; i += stride) {
    fl4 a = ((const fl4*)in)[2 * i];
    fl4 b = ((const fl4*)in)[2 * i + 1];
    us8 u = { f2bf(a[0]), f2bf(a[1]), f2bf(a[2]), f2bf(a[3]),
              f2bf(b[0]), f2bf(b[1]), f2bf(b[2]), f2bf(b[3]) };
    ((us8*)out)[i] = u;
  }
}

// ---------------- 5-segment cvt (h, Wdq, Wdkv, Wrk, Wukv) ---------------------
__global__ __launch_bounds__(256) void cvt5_kernel(
    const float* __restrict__ h,    const float* __restrict__ wdq,
    const float* __restrict__ wdkv, const float* __restrict__ wrk,
    const float* __restrict__ wukv,
    unsigned short* __restrict__ hb, unsigned short* __restrict__ w1cat,
    unsigned short* __restrict__ wukvb)
{
  const int s0 = 917504;            // h: 1024*7168/8
  const int s1 = s0 + 1376256;      // Wdq
  const int s2 = s1 + 458752;       // Wdkv
  const int s3 = s2 + 57344;        // Wrk
  const int s4 = s3 + 2097152;      // Wukv
  int i = blockIdx.x * 256 + threadIdx.x;
  int stride = gridDim.x * 256;
  for (; i < s4; i += stride) {
    const float* src;
    unsigned short* dst;
    int j;
    if (i < s0)      { src = h;    dst = hb;                              j = i; }
    else if (i < s1) { src = wdq;  dst = w1cat;                           j = i - s0; }
    else if (i < s2) { src = wdkv; dst = w1cat + (size_t)1536 * 7168;     j = i - s1; }
    else if (i < s3) { src = wrk;  dst = w1cat + (size_t)2048 * 7168;     j = i - s2; }
    else             { src = wukv; dst = wukvb;                           j = i - s3; }
    fl4 a = ((const fl4*)src)[2 * j];
    fl4 b = ((const fl4*)src)[2 * j + 1];
    us8 u = { f2bf(a[0]), f2bf(a[1]), f2bf(a[2]), f2bf(a[3]),
              f2bf(b[0]), f2bf(b[1]), f2bf(b[2]), f2bf(b[3]) };
    ((us8*)dst)[j] = u;
  }
}

// ------- setup: bias concat + W1cat pad zero + rope tables (one launch) -------
__global__ __launch_bounds__(256) void setup_kernel(
    const float* __restrict__ bdq, const float* __restrict__ bdkv,
    const float* __restrict__ brk, const float* __restrict__ buq,
    const float* __restrict__ brq,
    float* __restrict__ b1cat, float* __restrict__ b2cat,
    unsigned short* __restrict__ w1pad,   // = W1cat + 2112*7168, 64*7168 elems
    float* __restrict__ ctab, float* __restrict__ stab)
{
  int i = blockIdx.x * 256 + threadIdx.x;   // grid covers 458752
  if (i < 458752) w1pad[i] = 0;
  if (i < 2176) {
    float v = (i < 1536) ? bdq[i]
            : (i < 2048) ? bdkv[i - 1536]
            : (i < 2112) ? brk[i - 2048] : 0.f;
    b1cat[i] = v;
  }
  if (i < 24576)
    b2cat[i] = (i < 16384) ? buq[i] : brq[i - 16384];
  if (i < S_LEN * 32) {
    int j = i & 31, s = i >> 5;
    float invf = expf(-0.28782313662425574f * (float)j);   // 10000^(-j/32)
    float ang = (float)s * invf;
    ctab[i] = cosf(ang);
    stab[i] = sinf(ang);
  }
}

// ---------------- bf16 GEMM (m97 structure, counted-vmcnt WFP32) --------------
template <int OUTMODE, int WFP32, int ROPEQ = 0>
__global__ __launch_bounds__(256) void gemm_k(
    const unsigned short* __restrict__ A, int lda,
    const unsigned short* __restrict__ Wb16,
    const float* __restrict__ Wfa, const float* __restrict__ Wfb, int nsplit,
    int ldw,
    const float* __restrict__ bias,
    void* __restrict__ Cv, int ldc, size_t zstride,
    int Ncl, int ksl, float alpha,
    const float* __restrict__ ctab = nullptr,
    const float* __restrict__ stab = nullptr)
{
  const int n0 = blockIdx.x * 128;
  if (n0 >= Ncl) return;

  __shared__ unsigned short As[128 * 64];
  __shared__ unsigned short Ws[128 * 64];
  const int t = threadIdx.x;
  const int l = t & 63, w = t >> 6;
  const int r15 = l & 15, g = l >> 4;
  const int wm = (w >> 1) * 64, wn = (w & 1) * 64;
  const int m0 = blockIdx.y * 128;
  const int kbase = blockIdx.z * ksl;
  const int srow = l >> 3;
  const int scol = (l & 7) * 8;

  f32x4 acc[4][4];
#pragma unroll
  for (int i = 0; i < 4; ++i)
#pragma unroll
    for (int j = 0; j < 4; ++j) acc[i][j] = (f32x4){0.f, 0.f, 0.f, 0.f};

  const unsigned short* Ab = A + (size_t)m0 * lda;
  const unsigned short* Wb = nullptr;
  const float* Wf = nullptr;
  if constexpr (WFP32) {
    Wf = (n0 < nsplit) ? Wfa + (size_t)n0 * ldw : Wfb + (size_t)(n0 - nsplit) * ldw;
  } else {
    Wb = Wb16 + (size_t)n0 * ldw;
  }

  fl4 wx[4], wy[4];
  auto issueW = [&](int k0) {
#pragma unroll
    for (int i = 0; i < 4; ++i) {
      int c = t + 256 * i;
      const float* src = Wf + (size_t)(c >> 3) * ldw + k0 + (c & 7) * 8;
      wx[i] = *(const fl4*)src;
      wy[i] = *(const fl4*)(src + 4);
    }
  };

  if constexpr (WFP32) issueW(kbase);
  const int kend = kbase + ksl;

  for (int k0 = kbase; k0 < kend; k0 += 64) {
    if constexpr (WFP32) {
      __builtin_amdgcn_s_barrier();
      __builtin_amdgcn_sched_barrier(0);
    } else {
      __syncthreads();
    }
#pragma unroll
    for (int i = 0; i < 4; ++i) {
      int chunk = w * 4 + i;
      int row = chunk * 8 + srow;
      __builtin_amdgcn_global_load_lds(
          (const __attribute__((address_space(1))) void*)(Ab + (size_t)row * lda + k0 + scol),
          (__attribute__((address_space(3))) void*)(As + chunk * 512), 16, 0, 0);
      if constexpr (!WFP32) {
        __builtin_amdgcn_global_load_lds(
            (const __attribute__((address_space(1))) void*)(Wb + (size_t)row * ldw + k0 + scol),
            (__attribute__((address_space(3))) void*)(Ws + chunk * 512), 16, 0, 0);
      }
    }
    if constexpr (WFP32) {
      __builtin_amdgcn_sched_barrier(0);
      asm volatile("s_waitcnt vmcnt(4)" ::: "memory");
      __builtin_amdgcn_sched_barrier(0);
#pragma unroll
      for (int i = 0; i < 4; ++i) {
        int c = t + 256 * i;
        u32x4 p = { cvtpk2(wx[i][0], wx[i][1]), cvtpk2(wx[i][2], wx[i][3]),
                    cvtpk2(wy[i][0], wy[i][1]), cvtpk2(wy[i][2], wy[i][3]) };
        ((u32x4*)Ws)[c] = p;
      }
      if (k0 + 64 < kend) {
        issueW(k0 + 64);
        __builtin_amdgcn_sched_barrier(0);
        asm volatile("s_waitcnt vmcnt(8) lgkmcnt(0)" ::: "memory");
      } else {
        asm volatile("s_waitcnt vmcnt(0) lgkmcnt(0)" ::: "memory");
      }
      __builtin_amdgcn_sched_barrier(0);
      __builtin_amdgcn_s_barrier();
    } else {
      __syncthreads();
    }
#pragma unroll
    for (int kk = 0; kk < 2; ++kk) {
      bf16x8 a[4], b[4];
#pragma unroll
      for (int mt = 0; mt < 4; ++mt)
        a[mt] = *reinterpret_cast<const bf16x8*>(&As[(wm + mt * 16 + r15) * 64 + kk * 32 + 8 * g]);
#pragma unroll
      for (int nt = 0; nt < 4; ++nt)
        b[nt] = *reinterpret_cast<const bf16x8*>(&Ws[(wn + nt * 16 + r15) * 64 + kk * 32 + 8 * g]);
#pragma unroll
      for (int mt = 0; mt < 4; ++mt)
#pragma unroll
        for (int nt = 0; nt < 4; ++nt)
          acc[mt][nt] = __builtin_amdgcn_mfma_f32_16x16x32_bf16(a[mt], b[nt], acc[mt][nt], 0, 0, 0);
    }
  }

  if constexpr (OUTMODE == 1) {
    float bv[4];
#pragma unroll
    for (int nt = 0; nt < 4; ++nt) {
      int col = n0 + wn + nt * 16 + r15;
      bv[nt] = (col < Ncl) ? bias[col] : 0.f;
    }
    bool isrope = false;
    if constexpr (ROPEQ) isrope = (n0 + wn) >= 16384;
    if (ROPEQ && isrope) {
#pragma unroll
      for (int mt = 0; mt < 4; ++mt)
#pragma unroll
        for (int r = 0; r < 4; ++r) {
          int row = m0 + wm + mt * 16 + g * 4 + r;
#pragma unroll
          for (int ntp = 0; ntp < 2; ++ntp) {
            int j = ntp * 16 + r15;
            float c = ctab[row * 32 + j];
            float s = stab[row * 32 + j];
            float x1 = acc[mt][ntp][r] + bv[ntp];
            float x2 = acc[mt][ntp + 2][r] + bv[ntp + 2];
            int col1 = n0 + wn + ntp * 16 + r15;
            ((unsigned short*)Cv)[(size_t)row * ldc + col1] =
                f2bf((x1 * c - x2 * s) * alpha);
            ((unsigned short*)Cv)[(size_t)row * ldc + col1 + 32] =
                f2bf((x2 * c + x1 * s) * alpha);
          }
        }
    } else {
#pragma unroll
      for (int mt = 0; mt < 4; ++mt)
#pragma unroll
        for (int nt = 0; nt < 4; ++nt) {
          int col = n0 + wn + nt * 16 + r15;
          if (col < Ncl) {
#pragma unroll
            for (int r = 0; r < 4; ++r) {
              int row = m0 + wm + mt * 16 + g * 4 + r;
              ((unsigned short*)Cv)[(size_t)row * ldc + col] =
                  f2bf((acc[mt][nt][r] + bv[nt]) * alpha);
            }
          }
        }
    }
  } else {
    float* Cp = (float*)Cv + blockIdx.z * zstride;
#pragma unroll
    for (int mt = 0; mt < 4; ++mt)
#pragma unroll
      for (int nt = 0; nt < 4; ++nt) {
        int col = n0 + wn + nt * 16 + r15;
        if (col < Ncl) {
#pragma unroll
          for (int r = 0; r < 4; ++r) {
            int row = m0 + wm + mt * 16 + g * 4 + r;
            Cp[(size_t)row * ldc + col] = acc[mt][nt][r];
          }
        }
      }
  }
}

// ---------------- G4: 8-phase 256x256 template (T2+T3+T4+T5), split-K=2 -------
#define G4_DSREAD_A(buf, mh)                                                  \
  _Pragma("unroll") for (int mf = 0; mf < 4; ++mf)                            \
  _Pragma("unroll") for (int kk = 0; kk < 2; ++kk)                            \
    af[mf][kk] = rdA(buf, mh, mf, kk);

#define G4_DSREAD_B(buf, nh, breg)                                           \
  _Pragma("unroll") for (int nf = 0; nf < 2; ++nf)                            \
  _Pragma("unroll") for (int kk = 0; kk < 2; ++kk)                            \
    breg[nf][kk] = rdB(buf, nh, nf, kk);

#define G4_MFMA(mh, nh, breg)                                                 \
  __builtin_amdgcn_s_setprio(1);                                              \
  _Pragma("unroll") for (int kk = 0; kk < 2; ++kk)                            \
  _Pragma("unroll") for (int mf = 0; mf < 4; ++mf)                            \
  _Pragma("unroll") for (int nf = 0; nf < 2; ++nf)                            \
    acc[mh][nh][mf][nf] = __builtin_amdgcn_mfma_f32_16x16x32_bf16(            \
        af[mf][kk], breg[nf][kk], acc[mh][nh][mf][nf], 0, 0, 0);              \
  __builtin_amdgcn_s_setprio(0);

#define G4_BAR_IN()                                                           \
  __builtin_amdgcn_s_barrier();                                               \
  asm volatile("s_waitcnt lgkmcnt(0)" ::: "memory");                          \
  __builtin_amdgcn_sched_barrier(0);

#define G4_BAR_OUT()                                                          \
  __builtin_amdgcn_sched_barrier(0);                                          \
  __builtin_amdgcn_s_barrier();

__global__ __launch_bounds__(512, 2) void gemm_g4_8ph(
    const unsigned short* __restrict__ A,      // obuf [1024][16384] bf16
    const unsigned short* __restrict__ W,      // Wob [7168][16384] bf16
    float* __restrict__ pbuf)                  // [2][1024][7168] fp32 partials
{
  __shared__ unsigned short S[65536];          // 128 KB
  const int t = threadIdx.x;
  const int l = t & 63, w = t >> 6;            // 8 waves
  const int r15 = l & 15, g = l >> 4;
  const int n0 = blockIdx.x * 256;
  const int m0 = blockIdx.y * 256;
  const int kbase = blockIdx.z * 8192;
  const int NT = 128;

  const int lp = (l & 56) | ((l ^ (l >> 3)) & 7);
  const int srow = lp >> 3;
  const int scol = (lp & 7) * 8;
  const int pr = (w >> 2) * 64;
  const int pc = (w & 3) * 32;

  f32x4 acc[2][2][4][2];
#pragma unroll
  for (int a0 = 0; a0 < 2; ++a0)
#pragma unroll
    for (int a1 = 0; a1 < 2; ++a1)
#pragma unroll
      for (int a2 = 0; a2 < 4; ++a2)
#pragma unroll
        for (int a3 = 0; a3 < 2; ++a3)
          acc[a0][a1][a2][a3] = (f32x4){0.f, 0.f, 0.f, 0.f};

  auto stage = [&](int tile, int which) {
    if (tile >= NT) return;
    const int k0 = kbase + tile * 64;
    const unsigned short* gb = (which < 2)
        ? A + (size_t)(m0 + which * 128) * 16384 + k0
        : W + (size_t)(n0 + (which - 2) * 128) * 16384 + k0;
    unsigned short* dst = S + (tile & 1) * 32768 + which * 8192;
#pragma unroll
    for (int i = 0; i < 2; ++i) {
      __builtin_amdgcn_global_load_lds(
          (const __attribute__((address_space(1))) void*)(gb + (size_t)((w * 2 + i) * 8 + srow) * 16384 + scol),
          (__attribute__((address_space(3))) void*)(dst + (w * 2 + i) * 512 + l * 8), 16, 0, 0);
    }
  };

  auto rdA = [&](int buf, int mh, int mf, int kk) -> bf16x8 {
    int row = pr + mf * 16 + r15;
    int L = row * 128 + kk * 64 + g * 16;
    L ^= ((L >> 7) & 7) << 4;
    return *(const bf16x8*)((const char*)S + buf * 65536 + mh * 16384 + L);
  };
  auto rdB = [&](int buf, int nh, int nf, int kk) -> bf16x8 {
    int row = pc + nf * 16 + r15;
    int L = row * 128 + kk * 64 + g * 16;
    L ^= ((L >> 7) & 7) << 4;
    return *(const bf16x8*)((const char*)S + buf * 65536 + (2 + nh) * 16384 + L);
  };

  bf16x8 af[4][2], bA[2][2], bB[2][2];

  stage(0, 0); stage(0, 1); stage(0, 2); stage(0, 3);
  stage(1, 0); stage(1, 2); stage(1, 3);
  __builtin_amdgcn_sched_barrier(0);
  asm volatile("s_waitcnt vmcnt(6)" ::: "memory");
  __builtin_amdgcn_sched_barrier(0);
  __builtin_amdgcn_s_barrier();

  for (int i = 0; i < 64; ++i) {
    const int tb = 2 * i;
    const bool last = (i == 63);
    // P1: (0,0) of tile tb (buf0)
    G4_DSREAD_A(0, 0)
    G4_DSREAD_B(0, 0, bA)
    stage(tb + 1, 1);
    G4_BAR_IN()
    G4_MFMA(0, 0, bA)
    G4_BAR_OUT()
    // P2: (0,1)
    G4_DSREAD_B(0, 1, bB)
    stage(tb + 2, 0);
    G4_BAR_IN()
    G4_MFMA(0, 1, bB)
    G4_BAR_OUT()
    // P3: (1,1)
    G4_DSREAD_A(0, 1)
    stage(tb + 2, 2);
    G4_BAR_IN()
    G4_MFMA(1, 1, bB)
    G4_BAR_OUT()
    // P4: (1,0)
    stage(tb + 2, 3);
    G4_BAR_IN()
    G4_MFMA(1, 0, bA)
    if (last) { asm volatile("s_waitcnt vmcnt(0)" ::: "memory"); }
    else      { asm volatile("s_waitcnt vmcnt(6)" ::: "memory"); }
    G4_BAR_OUT()
    // P5: (0,0) of tile tb+1 (buf1)
    G4_DSREAD_A(1, 0)
    G4_DSREAD_B(1, 0, bA)
    stage(tb + 2, 1);
    G4_BAR_IN()
    G4_MFMA(0, 0, bA)
    G4_BAR_OUT()
    // P6: (0,1)
    G4_DSREAD_B(1, 1, bB)
    stage(tb + 3, 0);
    G4_BAR_IN()
    G4_MFMA(0, 1, bB)
    G4_BAR_OUT()
    // P7: (1,1)
    G4_DSREAD_A(1, 1)
    stage(tb + 3, 2);
    G4_BAR_IN()
    G4_MFMA(1, 1, bB)
    G4_BAR_OUT()
    // P8: (1,0)
    stage(tb + 3, 3);
    G4_BAR_IN()
    G4_MFMA(1, 0, bA)
    if (last) { asm volatile("s_waitcnt vmcnt(0)" ::: "memory"); }
    else      { asm volatile("s_waitcnt vmcnt(6)" ::: "memory"); }
    G4_BAR_OUT()
  }

  float* Cp = pbuf + (size_t)blockIdx.z * 1024 * 7168;
#pragma unroll
  for (int mh = 0; mh < 2; ++mh)
#pragma unroll
    for (int nh = 0; nh < 2; ++nh)
#pragma unroll
      for (int mf = 0; mf < 4; ++mf)
#pragma unroll
        for (int nf = 0; nf < 2; ++nf) {
          int col = n0 + nh * 128 + pc + nf * 16 + r15;
#pragma unroll
          for (int r = 0; r < 4; ++r) {
            int row = m0 + mh * 128 + pr + mf * 16 + g * 4 + r;
            Cp[(size_t)row * 7168 + col] = acc[mh][nh][mf][nf][r];
          }
        }
}

// ---------------- split-K reductions ------------------------------------------
__global__ __launch_bounds__(256) void reduce_f32_kernel(
    const float* __restrict__ pbuf, const float* __restrict__ bias,
    float* __restrict__ out, int ldo, int rowlen4, int nz, size_t zstride, int total4)
{
  int idx = blockIdx.x * 256 + threadIdx.x;
  if (idx >= total4) return;
  int r = idx / rowlen4, c4 = idx % rowlen4;
  fl4 acc = *(const fl4*)(bias + c4 * 4);
  for (int z = 0; z < nz; ++z)
    acc += *(const fl4*)(pbuf + z * zstride + (size_t)idx * 4);
  *(fl4*)(out + (size_t)r * ldo + c4 * 4) = acc;
}

__global__ __launch_bounds__(256) void reduce_bf16_kernel(
    const float* __restrict__ pbuf, const float* __restrict__ bias,
    unsigned short* __restrict__ out, int ldo, int rowlen4, int nz, size_t zstride, int total4)
{
  int idx = blockIdx.x * 256 + threadIdx.x;
  if (idx >= total4) return;
  int r = idx / rowlen4, c4 = idx % rowlen4;
  fl4 acc = *(const fl4*)(bias + c4 * 4);
  for (int z = 0; z < nz; ++z)
    acc += *(const fl4*)(pbuf + z * zstride + (size_t)idx * 4);
  us4 u = { f2bf(acc[0]), f2bf(acc[1]), f2bf(acc[2]), f2bf(acc[3]) };
  *(us4*)(out + (size_t)r * ldo + c4 * 4) = u;
}

// ---------------- rope (k_r only) ---------------------------------------------
__global__ void rope_bf16_kernel(unsigned short* __restrict__ x, int nh, int lda, int total,
                                 const float* __restrict__ ctab,
                                 const float* __restrict__ stab) {
  int idx = blockIdx.x * 256 + threadIdx.x;
  if (idx >= total) return;
  int j = idx & 31;
  int rest = idx >> 5;
  int hh = rest % nh;
  int s = rest / nh;
  float c = ctab[s * 32 + j], sn = stab[s * 32 + j];
  size_t base = (size_t)s * lda + hh * 64;
  float x1 = bf2f(x[base + j]), x2 = bf2f(x[base + j + 32]);
  x[base + j]      = f2bf(x1 * c - x2 * sn);
  x[base + j + 32] = f2bf(x2 * c + x1 * sn);
}

// ---------------- V transpose -------------------------------------------------
__global__ __launch_bounds__(256) void vtrans_kernel(
    const unsigned short* __restrict__ kvb, unsigned short* __restrict__ vt) {
  __shared__ unsigned short tl[64][72];
  const int s0 = blockIdx.x * 64;
  const int c0 = blockIdx.y * 64;
  const int t = threadIdx.x;
  const int rr = t >> 3, cc = (t & 7) * 8;
  const int hbase = (c0 >> 7) * 256 + 128 + (c0 & 127);
#pragma unroll
  for (int i = 0; i < 2; ++i) {
    int r = rr + i * 32;
    *reinterpret_cast<bf16x8*>(&tl[r][cc]) =
        *reinterpret_cast<const bf16x8*>(kvb + (size_t)(s0 + r) * 32768 + hbase + cc);
  }
  __syncthreads();
#pragma unroll
  for (int i = 0; i < 2; ++i) {
    int vc = rr + i * 32;
    unsigned short tmp[8];
#pragma unroll
    for (int j = 0; j < 8; ++j) tmp[j] = tl[cc + j][vc];
    *reinterpret_cast<bf16x8*>(&vt[(size_t)(c0 + vc) * 1024 + s0 + cc]) =
        *reinterpret_cast<bf16x8*>(tmp);
  }
}

// ---------------- flash attention: QBLK=128, 8 waves, T13 defer-max -----------
__global__ __launch_bounds__(512) void mla_attn_kernel(
    const unsigned short* __restrict__ qcat,
    const unsigned short* __restrict__ kvb,
    const unsigned short* __restrict__ kr,
    const unsigned short* __restrict__ vt,
    unsigned short* __restrict__ obuf)
{
  __shared__ unsigned short Klds[64][200];
  __shared__ unsigned short Vlds[128][72];
  __shared__ unsigned short Plds[8][16][72];

  const int t = threadIdx.x;
  const int l = t & 63, w = t >> 6;
  const int r15 = l & 15, g = l >> 4;
  const int bid = blockIdx.x;
  const int orig = (bid & 7) * 128 + (bid >> 3);
  const int h = orig >> 3;
  const int q0 = (orig & 7) * 128;

  bf16x8 qf[6];
  const unsigned short* qrow = qcat + (size_t)(q0 + w * 16 + r15) * 24576;
#pragma unroll
  for (int kk = 0; kk < 4; ++kk)
    qf[kk] = *reinterpret_cast<const bf16x8*>(qrow + h * 128 + kk * 32 + 8 * g);
#pragma unroll
  for (int kk = 4; kk < 6; ++kk)
    qf[kk] = *reinterpret_cast<const bf16x8*>(qrow + 16384 + h * 64 + (kk - 4) * 32 + 8 * g);

  bf16x8 kreg[3], vreg[2];
  auto loadKV = [&](int kk0) {
#pragma unroll
    for (int i = 0; i < 3; ++i) {
      int c = t + 512 * i, row = c / 24, cb = c % 24;
      const unsigned short* src = (cb < 16)
          ? kvb + (size_t)(kk0 + row) * 32768 + h * 256 + cb * 8
          : kr + (size_t)(kk0 + row) * 2112 + (cb - 16) * 8;
      kreg[i] = *reinterpret_cast<const bf16x8*>(src);
    }
#pragma unroll
    for (int i = 0; i < 2; ++i) {
      int c = t + 512 * i, d = c >> 3, kb = c & 7;
      vreg[i] = *reinterpret_cast<const bf16x8*>(vt + ((size_t)h * 128 + d) * 1024 + kk0 + kb * 8);
    }
  };

  float m_r[4], l_r[4];
  f32x4 oacc[8];
#pragma unroll
  for (int r = 0; r < 4; ++r) { m_r[r] = -1e30f; l_r[r] = 0.f; }
#pragma unroll
  for (int d = 0; d < 8; ++d) oacc[d] = (f32x4){0.f, 0.f, 0.f, 0.f};

  loadKV(0);

  for (int kt = 0; kt < 16; ++kt) {
    __syncthreads();
#pragma unroll
    for (int i = 0; i < 3; ++i) {
      int c = t + 512 * i, row = c / 24, cb = c % 24;
      *reinterpret_cast<bf16x8*>(&Klds[row][cb * 8]) = kreg[i];
    }
#pragma unroll
    for (int i = 0; i < 2; ++i) {
      int c = t + 512 * i, d = c >> 3, kb = c & 7;
      *reinterpret_cast<bf16x8*>(&Vlds[d][kb * 8]) = vreg[i];
    }
    __syncthreads();
    if (kt < 15) loadKV((kt + 1) * 64);

    f32x4 sacc[4];
#pragma unroll
    for (int nt = 0; nt < 4; ++nt) sacc[nt] = (f32x4){0.f, 0.f, 0.f, 0.f};
    __builtin_amdgcn_s_setprio(1);
#pragma unroll
    for (int nt = 0; nt < 4; ++nt)
#pragma unroll
      for (int kk = 0; kk < 6; ++kk) {
        bf16x8 b = *reinterpret_cast<const bf16x8*>(&Klds[nt * 16 + r15][kk * 32 + 8 * g]);
        sacc[nt] = __builtin_amdgcn_mfma_f32_16x16x32_bf16(qf[kk], b, sacc[nt], 0, 0, 0);
      }
    __builtin_amdgcn_s_setprio(0);

    // online softmax with T13 defer-max
    float mx[4];
#pragma unroll
    for (int r = 0; r < 4; ++r) {
      float m = fmaxf(fmaxf(sacc[0][r], sacc[1][r]), fmaxf(sacc[2][r], sacc[3][r]));
      m = fmaxf(m, __shfl_xor(m, 1));
      m = fmaxf(m, __shfl_xor(m, 2));
      m = fmaxf(m, __shfl_xor(m, 4));
      m = fmaxf(m, __shfl_xor(m, 8));
      mx[r] = m;
    }
    float grow = fmaxf(fmaxf(mx[0] - m_r[0], mx[1] - m_r[1]),
                       fmaxf(mx[2] - m_r[2], mx[3] - m_r[3]));
    if (__any(grow > 8.0f)) {
      float sc[4];
#pragma unroll
      for (int r = 0; r < 4; ++r) {
        float mn = fmaxf(m_r[r], mx[r]);
        sc[r] = __expf(m_r[r] - mn);
        m_r[r] = mn;
        l_r[r] *= sc[r];
      }
#pragma unroll
      for (int d = 0; d < 8; ++d)
#pragma unroll
        for (int r = 0; r < 4; ++r) oacc[d][r] *= sc[r];
    }
    float rsum[4] = {0.f, 0.f, 0.f, 0.f};
#pragma unroll
    for (int nt = 0; nt < 4; ++nt)
#pragma unroll
      for (int r = 0; r < 4; ++r) {
        float p = __expf(sacc[nt][r] - m_r[r]);
        rsum[r] += p;
        Plds[w][g * 4 + r][nt * 16 + r15] = f2bf(p);
      }
#pragma unroll
    for (int r = 0; r < 4; ++r) {
      float s = rsum[r];
      s += __shfl_xor(s, 1);
      s += __shfl_xor(s, 2);
      s += __shfl_xor(s, 4);
      s += __shfl_xor(s, 8);
      l_r[r] += s;
    }

    bf16x8 pa0 = *reinterpret_cast<const bf16x8*>(&Plds[w][r15][8 * g]);
    bf16x8 pa1 = *reinterpret_cast<const bf16x8*>(&Plds[w][r15][32 + 8 * g]);
    __builtin_amdgcn_s_setprio(1);
#pragma unroll
    for (int dt = 0; dt < 8; ++dt) {
      bf16x8 v0 = *reinterpret_cast<const bf16x8*>(&Vlds[dt * 16 + r15][8 * g]);
      bf16x8 v1 = *reinterpret_cast<const bf16x8*>(&Vlds[dt * 16 + r15][32 + 8 * g]);
      oacc[dt] = __builtin_amdgcn_mfma_f32_16x16x32_bf16(pa0, v0, oacc[dt], 0, 0, 0);
      oacc[dt] = __builtin_amdgcn_mfma_f32_16x16x32_bf16(pa1, v1, oacc[dt], 0, 0, 0);
    }
    __builtin_amdgcn_s_setprio(0);
  }

#pragma unroll
  for (int dt = 0; dt < 8; ++dt)
#pragma unroll
    for (int r = 0; r < 4; ++r) {
      int row = q0 + w * 16 + g * 4 + r;
      int col = h * DH + dt * 16 + r15;
      obuf[(size_t)row * 16384 + col] = f2bf(oacc[dt][r] / l_r[r]);
    }
}

// ------------------------------------------------------------------------------
extern "C" void kernel_launch(void* const* d_in, const int* in_sizes, int n_in,
                              void* d_out, int out_size, void* d_ws, size_t ws_size,
                              hipStream_t stream) {
  const float* h    = (const float*)d_in[0];
  const float* Wdq  = (const float*)d_in[1];
  const float* bdq  = (const float*)d_in[2];
  const float* Wdkv = (const float*)d_in[3];
  const float* bdkv = (const float*)d_in[4];
  const float* Wuq  = (const float*)d_in[5];
  const float* buq  = (const float*)d_in[6];
  const float* Wukv = (const float*)d_in[7];
  const float* bukv = (const float*)d_in[8];
  const float* Wrq  = (const float*)d_in[9];
  const float* brq  = (const float*)d_in[10];
  const float* Wrk  = (const float*)d_in[11];
  const float* brk  = (const float*)d_in[12];
  const float* Wo   = (const float*)d_in[13];
  const float* bo   = (const float*)d_in[14];
  float* out = (float*)d_out;

  char* ws = (char*)d_ws;
  size_t off = 0;
  auto alloc = [&](size_t bytes) {
    char* p = ws + off;
    off += (bytes + 255) & ~(size_t)255;
    return p;
  };
  unsigned short* hb    = (unsigned short*)alloc((size_t)1024 * 7168 * 2);
  unsigned short* W1cat = (unsigned short*)alloc((size_t)2176 * 7168 * 2);
  float*          b1cat = (float*)alloc(2176 * 4);
  float*          b2cat = (float*)alloc(24576 * 4);
  unsigned short* ccat  = (unsigned short*)alloc((size_t)1024 * 2112 * 2);
  unsigned short* qcat  = (unsigned short*)alloc((size_t)1024 * 24576 * 2);
  unsigned short* kvbb  = (unsigned short*)alloc((size_t)1024 * 32768 * 2);
  unsigned short* vt    = (unsigned short*)alloc((size_t)16384 * 1024 * 2);
  unsigned short* obuf  = (unsigned short*)alloc((size_t)1024 * 16384 * 2);
  float*          ctab  = (float*)alloc((size_t)S_LEN * 32 * 4);
  float*          stab  = (float*)alloc((size_t)S_LEN * 32 * 4);
  unsigned short* Wukvb = (unsigned short*)alloc((size_t)32768 * 512 * 2);
  // G1 split-K partials (2 x 1024 x 2112 fp32 = 17.3 MB) alias not-yet-written qcat
  float* pbufG1 = (float*)qcat;
  // d_ws ~1.8 GB: Wob (bf16 Wo, 235 MB) @ 288 MiB; pbufG4 (2x29.4=59 MB) @ 544 MiB
  unsigned short* Wob    = (unsigned short*)(ws + ((size_t)288 << 20));
  float*          pbufG4 = (float*)(ws + ((size_t)544 << 20));

  const float scale = 0.07216878364870323f;   // 1/sqrt(192)
  const int BIGN = 1 << 30;
  dim3 blk(256);

  // --- fused setup: 5-segment cvt + {bias concat, W1 pad, rope tables} ---
  cvt5_kernel<<<2048, blk, 0, stream>>>(h, Wdq, Wdkv, Wrk, Wukv, hb, W1cat, Wukvb);
  setup_kernel<<<1792, blk, 0, stream>>>(bdq, bdkv, brk, buq, brq,
                                         b1cat, b2cat, W1cat + (size_t)2112 * 7168,
                                         ctab, stab);

  // G1 (split-K=2, bf16 W): partials = h @ W1cat^T
  gemm_k<2, 0><<<dim3(24, 8, 2), blk, 0, stream>>>(
      hb, 7168, W1cat, nullptr, nullptr, BIGN, 7168, nullptr,
      pbufG1, 2112, (size_t)1024 * 2112, 2112, 3584, 1.0f);
  reduce_bf16_kernel<<<2112, blk, 0, stream>>>(pbufG1, b1cat, ccat, 2112, 528, 2,
                                               (size_t)1024 * 2112, 1024 * 2112 / 4);
  rope_bf16_kernel<<<(1024 * 32 + 255) / 256, blk, 0, stream>>>(ccat + 2048, 1, 2112, 1024 * 32, ctab, stab);

  // G2 (fp32 W direct, counted-vmcnt pipeline, fused q_r RoPE):
  gemm_k<1, 1, 1><<<dim3(192, 8, 1), blk, 0, stream>>>(
      ccat, 2112, nullptr, Wuq, Wrq, 16384, 1536, b2cat,
      qcat, 24576, 0, 24576, 1536, scale, ctab, stab);

  // G3 (bf16 W via glds): kv = c_kv @ Wukv^T + bukv
  gemm_k<1, 0><<<dim3(256, 8, 1), blk, 0, stream>>>(
      ccat + 1536, 2112, Wukvb, nullptr, nullptr, BIGN, 512, bukv,
      kvbb, 32768, 0, 32768, 512, 1.0f);
  vtrans_kernel<<<dim3(16, 256), blk, 0, stream>>>(kvbb, vt);
  mla_attn_kernel<<<dim3(1024), dim3(512), 0, stream>>>(qcat, kvbb, ccat + 2048, vt, obuf);

  // G4: cvt Wo -> bf16 once, 8-phase 256^2 GEMM (split-K=2), reduce.
  cvt_bf16_kernel<<<2048, blk, 0, stream>>>(Wo, Wob, (int)((size_t)7168 * 16384 / 8));
  gemm_g4_8ph<<<dim3(28, 4, 2), dim3(512), 0, stream>>>(obuf, Wob, pbufG4);
  reduce_f32_kernel<<<7168, blk, 0, stream>>>(pbufG4, bo, out,
                                              7168, 1792, 2, (size_t)1024 * 7168, 1024 * 7168 / 4);
}